// Round 18
// baseline (504.603 us; speedup 1.0000x reference)
//
#include <hip/hip_runtime.h>
#include <hip/hip_bf16.h>
#include <math.h>

#define T_ 2048
#define H_ 1024
#define HQ_ 16
#define HK_ 4
#define D_ 64
#define NE_ 8
#define II_ 2048

typedef __attribute__((ext_vector_type(8))) short bf16x8;
typedef __attribute__((ext_vector_type(8))) unsigned short u16x8;
typedef __attribute__((ext_vector_type(4))) float f32x4;

// async global->LDS DMA: 16B per lane, dest = wave-uniform base + lane*16
#define GLOAD16(g, l)                                                                   \
  __builtin_amdgcn_global_load_lds((const __attribute__((address_space(1))) unsigned int*)(g), \
                                   (__attribute__((address_space(3))) unsigned int*)(l), 16, 0, 0)

__device__ __forceinline__ unsigned short f2bf(float f) {
  unsigned int u = __float_as_uint(f);
  return (unsigned short)((u + 0x7fffu + ((u >> 16) & 1u)) >> 16);
}
__device__ __forceinline__ float bf2f(unsigned short h) {
  return __uint_as_float((unsigned int)h << 16);
}

// ---------------- rmsnorm (fp32 in, fp32 out + optional bf16 out) ----------------
__global__ __launch_bounds__(256) void k_rmsnorm(const float* __restrict__ x, const float* __restrict__ w,
                                                 float* __restrict__ outf, unsigned short* __restrict__ outb) {
  int row = blockIdx.x;
  int tid = threadIdx.x;
  float4 v = ((const float4*)(x + (size_t)row * H_))[tid];
  float ss = v.x * v.x + v.y * v.y + v.z * v.z + v.w * v.w;
#pragma unroll
  for (int off = 32; off; off >>= 1) ss += __shfl_xor(ss, off, 64);
  __shared__ float red[4];
  int lane = tid & 63, wid = tid >> 6;
  if (lane == 0) red[wid] = ss;
  __syncthreads();
  float tot = red[0] + red[1] + red[2] + red[3];
  float inv = rsqrtf(tot * (1.0f / H_) + 1e-5f);
  float4 wv = ((const float4*)w)[tid];
  float4 o;
  o.x = v.x * inv * wv.x; o.y = v.y * inv * wv.y; o.z = v.z * inv * wv.z; o.w = v.w * inv * wv.w;
  ((float4*)(outf + (size_t)row * H_))[tid] = o;
  if (outb) {
    ushort4 b; b.x = f2bf(o.x); b.y = f2bf(o.y); b.z = f2bf(o.z); b.w = f2bf(o.w);
    ((ushort4*)(outb + (size_t)row * H_))[tid] = b;
  }
}

// ---------------- rmsnorm writing expanded bf16x3 A' = [hi|hi|lo] along K'=3H ----------------
__global__ __launch_bounds__(256) void k_rmsnorm_split(const float* __restrict__ x, const float* __restrict__ w,
                                                       unsigned short* __restrict__ Aq) {
  int row = blockIdx.x;
  int tid = threadIdx.x;
  float4 v = ((const float4*)(x + (size_t)row * H_))[tid];
  float ss = v.x * v.x + v.y * v.y + v.z * v.z + v.w * v.w;
#pragma unroll
  for (int off = 32; off; off >>= 1) ss += __shfl_xor(ss, off, 64);
  __shared__ float red[4];
  int lane = tid & 63, wid = tid >> 6;
  if (lane == 0) red[wid] = ss;
  __syncthreads();
  float tot = red[0] + red[1] + red[2] + red[3];
  float inv = rsqrtf(tot * (1.0f / H_) + 1e-5f);
  float4 wv = ((const float4*)w)[tid];
  float4 o;
  o.x = v.x * inv * wv.x; o.y = v.y * inv * wv.y; o.z = v.z * inv * wv.z; o.w = v.w * inv * wv.w;
  ushort4 hi, lo;
  hi.x = f2bf(o.x); hi.y = f2bf(o.y); hi.z = f2bf(o.z); hi.w = f2bf(o.w);
  lo.x = f2bf(o.x - bf2f(hi.x)); lo.y = f2bf(o.y - bf2f(hi.y));
  lo.z = f2bf(o.z - bf2f(hi.z)); lo.w = f2bf(o.w - bf2f(hi.w));
  size_t base = (size_t)row * (3 * H_) + tid * 4;
  *(ushort4*)(Aq + base) = hi;
  *(ushort4*)(Aq + base + H_) = hi;
  *(ushort4*)(Aq + base + 2 * H_) = lo;
}

// ---------------- weight split: W[N][K] fp32 -> W'[N][3K] bf16 = [hi|lo|hi] ----------------
__global__ __launch_bounds__(256) void k_wsplit(const float* __restrict__ in, unsigned short* __restrict__ out,
                                                int K, int n8total) {
  int stride = gridDim.x * 256;
  int kc8 = K >> 3;
  for (int i = blockIdx.x * 256 + threadIdx.x; i < n8total; i += stride) {
    int n = i / kc8, kc = (i - n * kc8) * 8;
    const float4* p = (const float4*)(in + (size_t)n * K + kc);
    float4 a = p[0], b = p[1];
    u16x8 hi, lo;
    hi[0] = f2bf(a.x); hi[1] = f2bf(a.y); hi[2] = f2bf(a.z); hi[3] = f2bf(a.w);
    hi[4] = f2bf(b.x); hi[5] = f2bf(b.y); hi[6] = f2bf(b.z); hi[7] = f2bf(b.w);
    lo[0] = f2bf(a.x - bf2f(hi[0])); lo[1] = f2bf(a.y - bf2f(hi[1]));
    lo[2] = f2bf(a.z - bf2f(hi[2])); lo[3] = f2bf(a.w - bf2f(hi[3]));
    lo[4] = f2bf(b.x - bf2f(hi[4])); lo[5] = f2bf(b.y - bf2f(hi[5]));
    lo[6] = f2bf(b.z - bf2f(hi[6])); lo[7] = f2bf(b.w - bf2f(hi[7]));
    size_t ob = (size_t)n * 3 * K + kc;
    *(u16x8*)(out + ob) = hi;
    *(u16x8*)(out + ob + K) = lo;
    *(u16x8*)(out + ob + 2 * K) = hi;
  }
}

// ---------------- bf16 GEMM (expanded-K bf16x3), m97-style gload_lds + dbuf ----------------
template <int ADD>
__global__ __launch_bounds__(256) void k_hgemm(const unsigned short* __restrict__ A, const unsigned short* __restrict__ B,
                                               float* __restrict__ C, const float* __restrict__ addsrc,
                                               int N, int K3) {
  int m0 = blockIdx.y * 128, n0 = blockIdx.x * 64;
  __shared__ unsigned short As[2][128 * 32];
  __shared__ unsigned short Bs[2][64 * 32];
  int tid = threadIdx.x, lane = tid & 63, w = tid >> 6;
  int wr = w >> 1, wc = w & 1;
  int l15 = lane & 15, lg = lane >> 4;
  int srow = lane >> 2, schunk = lane & 3;

  const unsigned short* ga0 = A + (size_t)(m0 + w * 32 + srow) * K3 + schunk * 8;
  const unsigned short* ga1 = A + (size_t)(m0 + w * 32 + 16 + srow) * K3 + schunk * 8;
  const unsigned short* gb = B + (size_t)(n0 + w * 16 + srow) * K3 + schunk * 8;

  f32x4 acc[4][2];
  f32x4 z = {0.f, 0.f, 0.f, 0.f};
#pragma unroll
  for (int a = 0; a < 4; a++)
#pragma unroll
    for (int b = 0; b < 2; b++) acc[a][b] = z;

  GLOAD16(ga0, &As[0][(w * 32) * 32]);
  GLOAD16(ga1, &As[0][(w * 32 + 16) * 32]);
  GLOAD16(gb, &Bs[0][(w * 16) * 32]);
  __syncthreads();

  int nt = K3 / 32;
  for (int t = 0; t < nt; ++t) {
    int cur = t & 1;
    if (t + 1 < nt) {
      int ko = (t + 1) * 32;
      GLOAD16(ga0 + ko, &As[cur ^ 1][(w * 32) * 32]);
      GLOAD16(ga1 + ko, &As[cur ^ 1][(w * 32 + 16) * 32]);
      GLOAD16(gb + ko, &Bs[cur ^ 1][(w * 16) * 32]);
    }
    bf16x8 af[4], bw2[2];
#pragma unroll
    for (int fa = 0; fa < 4; fa++)
      af[fa] = *(const bf16x8*)&As[cur][(wr * 64 + fa * 16 + l15) * 32 + lg * 8];
#pragma unroll
    for (int fb = 0; fb < 2; fb++)
      bw2[fb] = *(const bf16x8*)&Bs[cur][(wc * 32 + fb * 16 + l15) * 32 + lg * 8];
#pragma unroll
    for (int fa = 0; fa < 4; fa++)
#pragma unroll
      for (int fb = 0; fb < 2; fb++)
        acc[fa][fb] = __builtin_amdgcn_mfma_f32_16x16x32_bf16(af[fa], bw2[fb], acc[fa][fb], 0, 0, 0);
    __syncthreads();
  }
#pragma unroll
  for (int fa = 0; fa < 4; fa++)
#pragma unroll
    for (int r = 0; r < 4; r++) {
      int row = m0 + wr * 64 + fa * 16 + lg * 4 + r;
#pragma unroll
      for (int fb = 0; fb < 2; fb++) {
        int col = n0 + wc * 32 + fb * 16 + l15;
        float v = acc[fa][fb][r];
        if (ADD) v += addsrc[(size_t)row * N + col];
        C[(size_t)row * N + col] = v;
      }
    }
}

// ---------------- RoPE cos/sin table ----------------
__global__ __launch_bounds__(256) void k_rope_table(const int* __restrict__ pos, float* __restrict__ ct,
                                                    float* __restrict__ st) {
  int idx = blockIdx.x * 256 + threadIdx.x;  // T*32
  int t = idx >> 5, i = idx & 31;
  float p = (float)pow(10000.0, (double)i / 32.0);
  float freq = 1.0f / p;
  float ang = (float)pos[t] * freq;
  ct[idx] = cosf(ang);
  st[idx] = sinf(ang);
}

// ---------------- RoPE apply + bf16 hi/lo split ----------------
__global__ __launch_bounds__(256) void k_rope_prep(const float* __restrict__ qkv, const float* __restrict__ ct,
                                                   const float* __restrict__ st, unsigned short* __restrict__ Qhi,
                                                   unsigned short* __restrict__ Qlo, unsigned short* __restrict__ Khi,
                                                   unsigned short* __restrict__ Klo) {
  int t = blockIdx.x, tid = threadIdx.x;
  const float* row = qkv + (size_t)t * 1536;
#pragma unroll 2
  for (int it = tid; it < 512; it += 256) {
    int h = it >> 5, i = it & 31;
    float c = ct[t * 32 + i], s = st[t * 32 + i];
    float x1 = row[h * 64 + i], x2 = row[h * 64 + i + 32];
    float a = (x1 * c - x2 * s) * 0.125f;
    float b = (x2 * c + x1 * s) * 0.125f;
    size_t base = ((size_t)h * T_ + t) * 64 + i;
    unsigned short ah = f2bf(a), bh = f2bf(b);
    Qhi[base] = ah; Qhi[base + 32] = bh;
    Qlo[base] = f2bf(a - bf2f(ah));
    Qlo[base + 32] = f2bf(b - bf2f(bh));
  }
  if (tid < 128) {
    int h = tid >> 5, i = tid & 31;
    float c = ct[t * 32 + i], s = st[t * 32 + i];
    float x1 = row[1024 + h * 64 + i], x2 = row[1024 + h * 64 + i + 32];
    float a = x1 * c - x2 * s;
    float b = x2 * c + x1 * s;
    size_t base = ((size_t)h * T_ + t) * 64 + i;
    unsigned short ah = f2bf(a), bh = f2bf(b);
    Khi[base] = ah; Khi[base + 32] = bh;
    Klo[base] = f2bf(a - bf2f(ah));
    Klo[base + 32] = f2bf(b - bf2f(bh));
  }
}

// ---------------- V transpose + split: Vthi/Vtlo [kvh][d][t] ----------------
__global__ __launch_bounds__(256) void k_vtrans(const float* __restrict__ qkv, unsigned short* __restrict__ Vthi,
                                                unsigned short* __restrict__ Vtlo) {
  int t0 = blockIdx.x * 64, h = blockIdx.y;
  __shared__ float tile[64][65];
  int tid = threadIdx.x;
  int c = tid & 63, w = tid >> 6;
  for (int r = w; r < 64; r += 4)
    tile[r][c] = qkv[(size_t)(t0 + r) * 1536 + 1280 + h * 64 + c];
  __syncthreads();
  for (int d = w; d < 64; d += 4) {
    float v = tile[c][d];
    unsigned short hi = f2bf(v);
    size_t idx = ((size_t)h * 64 + d) * T_ + t0 + c;
    Vthi[idx] = hi;
    Vtlo[idx] = f2bf(v - bf2f(hi));
  }
}

// ---------------- flash attention, bf16x3; 32-row q-tiles, 128 threads (2 waves), Ps aliases Ks ----------------
// 1024 blocks x 4 blocks/CU (36.9KB LDS). Same per-wave math as the 64-row version; K/V staged per block.
__global__ __launch_bounds__(128) void k_attn_mfma(const unsigned short* __restrict__ Qhi,
                                                   const unsigned short* __restrict__ Qlo,
                                                   const unsigned short* __restrict__ Khi,
                                                   const unsigned short* __restrict__ Klo,
                                                   const unsigned short* __restrict__ Vthi,
                                                   const unsigned short* __restrict__ Vtlo,
                                                   unsigned short* __restrict__ Ao) {
  int bid = blockIdx.x;
  int head = bid & 15;
  int q32 = 63 - (bid >> 4);  // heavy-first: large q dispatch first
  int qb = q32 * 32;          // first of this block's 32 q-rows
  int kvh = head >> 2;
  int tid = threadIdx.x, lane = tid & 63, w = tid >> 6;  // w in {0,1}
  int l15 = lane & 15, lg = lane >> 4;

  // 4 x (64*72) shorts = 36.9 KB. Ps aliases Ks (Ks dead after QK^T; barrier-protected).
  __shared__ unsigned short S[4 * 64 * 72];
  unsigned short* KsH = S;
  unsigned short* KsL = S + 4608;
  unsigned short* VsH = S + 9216;
  unsigned short* VsL = S + 13824;
  unsigned short* PsH = KsH;
  unsigned short* PsL = KsL;

  bf16x8 qh[2], ql[2];
  {
    size_t qbase = ((size_t)head * T_ + qb + w * 16 + l15) * 64 + lg * 8;
    qh[0] = *(const bf16x8*)(Qhi + qbase);
    qh[1] = *(const bf16x8*)(Qhi + qbase + 32);
    ql[0] = *(const bf16x8*)(Qlo + qbase);
    ql[1] = *(const bf16x8*)(Qlo + qbase + 32);
  }
  f32x4 z = {0.f, 0.f, 0.f, 0.f};
  f32x4 Oa[4];
  float mrow[4], lrow[4];
#pragma unroll
  for (int r = 0; r < 4; r++) { mrow[r] = -1e30f; lrow[r] = 0.f; }
#pragma unroll
  for (int dg = 0; dg < 4; dg++) Oa[dg] = z;

  int ntiles = (qb + 32 + 63) >> 6;  // kv-tiles covering rows [0, qb+32)
  for (int jbt = 0; jbt < ntiles; ++jbt) {
    int jb = jbt * 64;
    // staging: 128 threads x 4 iters of 16B per buffer
    for (int c = tid; c < 512; c += 128) {
      int r = c >> 3, g = (c & 7) * 8;
      size_t kgl = ((size_t)kvh * T_ + jb + r) * 64 + g;
      size_t vgl = ((size_t)kvh * 64 + r) * T_ + jb + g;
      *(uint4*)&KsH[r * 72 + g] = *(const uint4*)(Khi + kgl);
      *(uint4*)&KsL[r * 72 + g] = *(const uint4*)(Klo + kgl);
      *(uint4*)&VsH[r * 72 + g] = *(const uint4*)(Vthi + vgl);
      *(uint4*)&VsL[r * 72 + g] = *(const uint4*)(Vtlo + vgl);
    }
    __syncthreads();

    f32x4 sc[4];
    sc[0] = z; sc[1] = z; sc[2] = z; sc[3] = z;
#pragma unroll
    for (int kg = 0; kg < 4; kg++) {
      int ba = (kg * 16 + l15) * 72 + lg * 8;
      bf16x8 bh0 = *(const bf16x8*)&KsH[ba];
      bf16x8 bh1 = *(const bf16x8*)&KsH[ba + 32];
      bf16x8 bl0 = *(const bf16x8*)&KsL[ba];
      bf16x8 bl1 = *(const bf16x8*)&KsL[ba + 32];
      sc[kg] = __builtin_amdgcn_mfma_f32_16x16x32_bf16(qh[0], bh0, sc[kg], 0, 0, 0);
      sc[kg] = __builtin_amdgcn_mfma_f32_16x16x32_bf16(qh[1], bh1, sc[kg], 0, 0, 0);
      sc[kg] = __builtin_amdgcn_mfma_f32_16x16x32_bf16(qh[0], bl0, sc[kg], 0, 0, 0);
      sc[kg] = __builtin_amdgcn_mfma_f32_16x16x32_bf16(qh[1], bl1, sc[kg], 0, 0, 0);
      sc[kg] = __builtin_amdgcn_mfma_f32_16x16x32_bf16(ql[0], bh0, sc[kg], 0, 0, 0);
      sc[kg] = __builtin_amdgcn_mfma_f32_16x16x32_bf16(ql[1], bh1, sc[kg], 0, 0, 0);
    }
    if (jbt == ntiles - 1) {
      // absolute-index causal mask (covers half-masked and fully-masked columns)
      int rowa = qb + w * 16 + lg * 4;
#pragma unroll
      for (int kg = 0; kg < 4; kg++) {
        int cola = jb + kg * 16 + l15;
#pragma unroll
        for (int r = 0; r < 4; r++)
          if (cola > rowa + r) sc[kg][r] = -1e30f;
      }
    }
#pragma unroll
    for (int r = 0; r < 4; r++) {
      float mt = fmaxf(fmaxf(sc[0][r], sc[1][r]), fmaxf(sc[2][r], sc[3][r]));
      mt = fmaxf(mt, __shfl_xor(mt, 1, 64));
      mt = fmaxf(mt, __shfl_xor(mt, 2, 64));
      mt = fmaxf(mt, __shfl_xor(mt, 4, 64));
      mt = fmaxf(mt, __shfl_xor(mt, 8, 64));
      float mnew = fmaxf(mrow[r], mt);
      float corr = __expf(mrow[r] - mnew);
      mrow[r] = mnew;
      float s = 0.f;
#pragma unroll
      for (int kg = 0; kg < 4; kg++) {
        float p = __expf(sc[kg][r] - mnew);
        sc[kg][r] = p;
        s += p;
      }
      s += __shfl_xor(s, 1, 64);
      s += __shfl_xor(s, 2, 64);
      s += __shfl_xor(s, 4, 64);
      s += __shfl_xor(s, 8, 64);
      lrow[r] = lrow[r] * corr + s;
      // per-ROW rescale (Oa[dg] components are 4 different rows)
#pragma unroll
      for (int dg = 0; dg < 4; dg++) Oa[dg][r] *= corr;
    }
    __syncthreads();  // both waves' QK reads of Ks done before Ps (alias) overwrite
    {
      int rb = w * 16 + lg * 4;
#pragma unroll
      for (int kg = 0; kg < 4; kg++) {
        int col = kg * 16 + l15;
#pragma unroll
        for (int r = 0; r < 4; r++) {
          float p = sc[kg][r];
          unsigned short ph = f2bf(p);
          PsH[(rb + r) * 72 + col] = ph;
          PsL[(rb + r) * 72 + col] = f2bf(p - bf2f(ph));
        }
      }
    }
    {
      // PV: A-frag rows w*16..w*16+15 == rows this wave just wrote (same-wave, no barrier)
      int ab = (w * 16 + l15) * 72 + lg * 8;
      bf16x8 ph0 = *(const bf16x8*)&PsH[ab];
      bf16x8 ph1 = *(const bf16x8*)&PsH[ab + 32];
      bf16x8 pl0 = *(const bf16x8*)&PsL[ab];
      bf16x8 pl1 = *(const bf16x8*)&PsL[ab + 32];
#pragma unroll
      for (int dg = 0; dg < 4; dg++) {
        int vb = (dg * 16 + l15) * 72 + lg * 8;
        bf16x8 vh0 = *(const bf16x8*)&VsH[vb];
        bf16x8 vh1 = *(const bf16x8*)&VsH[vb + 32];
        bf16x8 vl0 = *(const bf16x8*)&VsL[vb];
        bf16x8 vl1 = *(const bf16x8*)&VsL[vb + 32];
        Oa[dg] = __builtin_amdgcn_mfma_f32_16x16x32_bf16(ph0, vh0, Oa[dg], 0, 0, 0);
        Oa[dg] = __builtin_amdgcn_mfma_f32_16x16x32_bf16(ph1, vh1, Oa[dg], 0, 0, 0);
        Oa[dg] = __builtin_amdgcn_mfma_f32_16x16x32_bf16(ph0, vl0, Oa[dg], 0, 0, 0);
        Oa[dg] = __builtin_amdgcn_mfma_f32_16x16x32_bf16(ph1, vl1, Oa[dg], 0, 0, 0);
        Oa[dg] = __builtin_amdgcn_mfma_f32_16x16x32_bf16(pl0, vh0, Oa[dg], 0, 0, 0);
        Oa[dg] = __builtin_amdgcn_mfma_f32_16x16x32_bf16(pl1, vh1, Oa[dg], 0, 0, 0);
      }
    }
    __syncthreads();  // Ps/Vs reads done before next tile's staging writes
  }
#pragma unroll
  for (int r = 0; r < 4; r++) {
    float inv = 1.0f / lrow[r];
    size_t rb2 = (size_t)(qb + w * 16 + lg * 4 + r) * 3072 + head * 64;
#pragma unroll
    for (int dg = 0; dg < 4; dg++) {
      float v = Oa[dg][r] * inv;
      unsigned short hi2 = f2bf(v);
      unsigned short lo2 = f2bf(v - bf2f(hi2));
      Ao[rb2 + dg * 16 + l15] = hi2;
      Ao[rb2 + 1024 + dg * 16 + l15] = hi2;
      Ao[rb2 + 2048 + dg * 16 + l15] = lo2;
    }
  }
}

// ---------------- router ----------------
__global__ __launch_bounds__(256) void k_router(const float* __restrict__ h2, const float* __restrict__ gw,
                                                int* __restrict__ topi, float* __restrict__ topw,
                                                int* __restrict__ counts) {
  int wid = threadIdx.x >> 6, lane = threadIdx.x & 63;
  int t = blockIdx.x * 4 + wid;
  const float* hr = h2 + (size_t)t * H_;
  float hv[16];
#pragma unroll
  for (int i = 0; i < 16; i++) hv[i] = hr[lane + 64 * i];
  float le[8];
#pragma unroll
  for (int e = 0; e < 8; e++) {
    const float* g = gw + (size_t)e * H_;
    float acc = 0.f;
#pragma unroll
    for (int i = 0; i < 16; i++) acc += hv[i] * g[lane + 64 * i];
#pragma unroll
    for (int off = 32; off; off >>= 1) acc += __shfl_xor(acc, off, 64);
    le[e] = acc;
  }
  if (lane == 0) {
    int i0 = 0;
#pragma unroll
    for (int e = 1; e < 8; e++)
      if (le[e] > le[i0]) i0 = e;
    int i1 = (i0 == 0) ? 1 : 0;
#pragma unroll
    for (int e = 0; e < 8; e++) {
      if (e == i0) continue;
      if (le[e] > le[i1]) i1 = e;
    }
    float w1r = expf(le[i1] - le[i0]);
    float denom = 1.0f + w1r;
    topi[t * 2 + 0] = i0;
    topi[t * 2 + 1] = i1;
    topw[t * 2 + 0] = 1.0f / denom;
    topw[t * 2 + 1] = w1r / denom;
    atomicAdd(&counts[i0], 1);
    atomicAdd(&counts[i1], 1);
  }
}

__global__ void k_scan(const int* __restrict__ counts, int* __restrict__ offsets) {
  if (threadIdx.x == 0 && blockIdx.x == 0) {
    int off = 0;
    for (int e = 0; e < NE_; e++) { offsets[e] = off; off += counts[e]; }
  }
}

__global__ __launch_bounds__(256) void k_build(const int* __restrict__ topi, const float* __restrict__ topw,
                                               const int* __restrict__ offsets, int* __restrict__ counts2,
                                               int* __restrict__ pairs_ts, float* __restrict__ pairs_w) {
  int t = blockIdx.x * 256 + threadIdx.x;
#pragma unroll
  for (int s = 0; s < 2; s++) {
    int e = topi[t * 2 + s];
    int slot = atomicAdd(&counts2[e], 1);
    int p = offsets[e] + slot;
    pairs_ts[p] = t * 2 + s;
    pairs_w[p] = topw[t * 2 + s];
  }
}

// ---------------- fp32 -> bf16 bulk convert, all three MoE weights in one launch ----------------
__global__ __launch_bounds__(256) void k_conv3(const float* __restrict__ w1, const float* __restrict__ w3,
                                               const float* __restrict__ w2, unsigned short* __restrict__ W1b,
                                               unsigned short* __restrict__ W3b, unsigned short* __restrict__ W2b,
                                               int n8each) {
  int stride = gridDim.x * 256;
  int total = 3 * n8each;
  for (int i = blockIdx.x * 256 + threadIdx.x; i < total; i += stride) {
    int sel = i / n8each;
    int j = i - sel * n8each;
    const float* in = (sel == 0) ? w1 : (sel == 1) ? w3 : w2;
    unsigned short* out = (sel == 0) ? W1b : (sel == 1) ? W3b : W2b;
    const float4* p = (const float4*)in + (size_t)j * 2;
    float4 a = p[0], b = p[1];
    u16x8 t;
    t[0] = f2bf(a.x); t[1] = f2bf(a.y); t[2] = f2bf(a.z); t[3] = f2bf(a.w);
    t[4] = f2bf(b.x); t[5] = f2bf(b.y); t[6] = f2bf(b.z); t[7] = f2bf(b.w);
    *((u16x8*)out + j) = t;
  }
}

// ---------------- MoE up: 128x64 tile, BK=32, gload_lds dbuf, silu epilogue ----------------
__global__ __launch_bounds__(256) void k_moe_up(const unsigned short* __restrict__ h2b, const unsigned short* __restrict__ W1b,
                                                const unsigned short* __restrict__ W3b, const int* __restrict__ pairs_ts,
                                                const int* __restrict__ offsets, const int* __restrict__ counts,
                                                unsigned short* __restrict__ G) {
  int e = blockIdx.z;
  int ne = counts[e];
  int row0 = blockIdx.y * 128;
  if (row0 >= ne) return;
  int col0 = blockIdx.x * 64;
  int pbase = offsets[e];
  __shared__ unsigned short As[2][128 * 32];
  __shared__ unsigned short B1s[2][64 * 32];
  __shared__ unsigned short B2s[2][64 * 32];
  int tid = threadIdx.x, lane = tid & 63, w = tid >> 6;
  int wr = w >> 1, wc = w & 1;
  int l15 = lane & 15, lg = lane >> 4;
  int srow = lane >> 2, schunk = lane & 3;

  int gr0 = row0 + w * 32 + srow, gr1 = gr0 + 16;
  int tok0 = (gr0 < ne) ? (pairs_ts[pbase + gr0] >> 1) : 0;
  int tok1 = (gr1 < ne) ? (pairs_ts[pbase + gr1] >> 1) : 0;
  const unsigned short* ga0 = h2b + (size_t)tok0 * H_ + schunk * 8;
  const unsigned short* ga1 = h2b + (size_t)tok1 * H_ + schunk * 8;
  const unsigned short* gb1 = W1b + ((size_t)e * II_ + col0 + w * 16 + srow) * H_ + schunk * 8;
  const unsigned short* gb3 = W3b + ((size_t)e * II_ + col0 + w * 16 + srow) * H_ + schunk * 8;

  f32x4 acc1[4][2], acc2[4][2];
  f32x4 z = {0.f, 0.f, 0.f, 0.f};
#pragma unroll
  for (int a = 0; a < 4; a++)
#pragma unroll
    for (int b = 0; b < 2; b++) { acc1[a][b] = z; acc2[a][b] = z; }

  GLOAD16(ga0, &As[0][(w * 32) * 32]);
  GLOAD16(ga1, &As[0][(w * 32 + 16) * 32]);
  GLOAD16(gb1, &B1s[0][(w * 16) * 32]);
  GLOAD16(gb3, &B2s[0][(w * 16) * 32]);
  __syncthreads();

  for (int t = 0; t < H_ / 32; ++t) {
    int cur = t & 1;
    if (t + 1 < H_ / 32) {
      int ko = (t + 1) * 32;
      GLOAD16(ga0 + ko, &As[cur ^ 1][(w * 32) * 32]);
      GLOAD16(ga1 + ko, &As[cur ^ 1][(w * 32 + 16) * 32]);
      GLOAD16(gb1 + ko, &B1s[cur ^ 1][(w * 16) * 32]);
      GLOAD16(gb3 + ko, &B2s[cur ^ 1][(w * 16) * 32]);
    }
    bf16x8 af[4], b1f[2], b2f[2];
#pragma unroll
    for (int fa = 0; fa < 4; fa++)
      af[fa] = *(const bf16x8*)&As[cur][(wr * 64 + fa * 16 + l15) * 32 + lg * 8];
#pragma unroll
    for (int fb = 0; fb < 2; fb++) {
      b1f[fb] = *(const bf16x8*)&B1s[cur][(wc * 32 + fb * 16 + l15) * 32 + lg * 8];
      b2f[fb] = *(const bf16x8*)&B2s[cur][(wc * 32 + fb * 16 + l15) * 32 + lg * 8];
    }
#pragma unroll
    for (int fa = 0; fa < 4; fa++)
#pragma unroll
      for (int fb = 0; fb < 2; fb++) {
        acc1[fa][fb] = __builtin_amdgcn_mfma_f32_16x16x32_bf16(af[fa], b1f[fb], acc1[fa][fb], 0, 0, 0);
        acc2[fa][fb] = __builtin_amdgcn_mfma_f32_16x16x32_bf16(af[fa], b2f[fb], acc2[fa][fb], 0, 0, 0);
      }
    __syncthreads();
  }
#pragma unroll
  for (int fa = 0; fa < 4; fa++)
#pragma unroll
    for (int r = 0; r < 4; r++) {
      int prow = row0 + wr * 64 + fa * 16 + lg * 4 + r;
      if (prow < ne) {
#pragma unroll
        for (int fb = 0; fb < 2; fb++) {
          int icol = col0 + wc * 32 + fb * 16 + l15;
          float h1 = acc1[fa][fb][r], h3 = acc2[fa][fb][r];
          float g = h1 / (1.0f + __expf(-h1)) * h3;
          G[(size_t)(pbase + prow) * II_ + icol] = f2bf(g);
        }
      }
    }
}

// ---------------- MoE down: 128x64 tile, BK=32, gload_lds dbuf, weighted store ----------------
__global__ __launch_bounds__(256) void k_moe_down(const unsigned short* __restrict__ G, const unsigned short* __restrict__ W2b,
                                                  const int* __restrict__ pairs_ts, const float* __restrict__ pairs_w,
                                                  const int* __restrict__ offsets, const int* __restrict__ counts,
                                                  float* __restrict__ Pbuf) {
  int e = blockIdx.z;
  int ne = counts[e];
  int row0 = blockIdx.y * 128;
  if (row0 >= ne) return;
  int col0 = blockIdx.x * 64;
  int pbase = offsets[e];
  __shared__ unsigned short As[2][128 * 32];
  __shared__ unsigned short Bs[2][64 * 32];
  int tid = threadIdx.x, lane = tid & 63, w = tid >> 6;
  int wr = w >> 1, wc = w & 1;
  int l15 = lane & 15, lg = lane >> 4;
  int srow = lane >> 2, schunk = lane & 3;

  int gr0 = row0 + w * 32 + srow, gr1 = gr0 + 16;
  int p0 = pbase + ((gr0 < ne) ? gr0 : 0);
  int p1 = pbase + ((gr1 < ne) ? gr1 : 0);
  const unsigned short* ga0 = G + (size_t)p0 * II_ + schunk * 8;
  const unsigned short* ga1 = G + (size_t)p1 * II_ + schunk * 8;
  const unsigned short* gb = W2b + ((size_t)e * H_ + col0 + w * 16 + srow) * II_ + schunk * 8;

  f32x4 acc[4][2];
  f32x4 z = {0.f, 0.f, 0.f, 0.f};
#pragma unroll
  for (int a = 0; a < 4; a++)
#pragma unroll
    for (int b = 0; b < 2; b++) acc[a][b] = z;

  GLOAD16(ga0, &As[0][(w * 32) * 32]);
  GLOAD16(ga1, &As[0][(w * 32 + 16) * 32]);
  GLOAD16(gb, &Bs[0][(w * 16) * 32]);
  __syncthreads();

  for (int t = 0; t < II_ / 32; ++t) {
    int cur = t & 1;
    if (t + 1 < II_ / 32) {
      int ko = (t + 1) * 32;
      GLOAD16(ga0 + ko, &As[cur ^ 1][(w * 32) * 32]);
      GLOAD16(ga1 + ko, &As[cur ^ 1][(w * 32 + 16) * 32]);
      GLOAD16(gb + ko, &Bs[cur ^ 1][(w * 16) * 32]);
    }
    bf16x8 af[4], bw2[2];
#pragma unroll
    for (int fa = 0; fa < 4; fa++)
      af[fa] = *(const bf16x8*)&As[cur][(wr * 64 + fa * 16 + l15) * 32 + lg * 8];
#pragma unroll
    for (int fb = 0; fb < 2; fb++)
      bw2[fb] = *(const bf16x8*)&Bs[cur][(wc * 32 + fb * 16 + l15) * 32 + lg * 8];
#pragma unroll
    for (int fa = 0; fa < 4; fa++)
#pragma unroll
      for (int fb = 0; fb < 2; fb++)
        acc[fa][fb] = __builtin_amdgcn_mfma_f32_16x16x32_bf16(af[fa], bw2[fb], acc[fa][fb], 0, 0, 0);
    __syncthreads();
  }
#pragma unroll
  for (int fa = 0; fa < 4; fa++)
#pragma unroll
    for (int r = 0; r < 4; r++) {
      int prow = row0 + wr * 64 + fa * 16 + lg * 4 + r;
      if (prow < ne) {
        int p = pbase + prow;
        int ts = pairs_ts[p];
        float wgt = pairs_w[p];
#pragma unroll
        for (int fb = 0; fb < 2; fb++) {
          int col = col0 + wc * 32 + fb * 16 + l15;
          Pbuf[(size_t)ts * H_ + col] = wgt * acc[fa][fb][r];
        }
      }
    }
}

// ---------------- final: out = rmsnorm(resid + P0 + P1) ----------------
__global__ __launch_bounds__(256) void k_final(const float* __restrict__ resid, const float* __restrict__ Pbuf,
                                               const float* __restrict__ w, float* __restrict__ out) {
  int row = blockIdx.x;
  int tid = threadIdx.x;
  float4 a = ((const float4*)(resid + (size_t)row * H_))[tid];
  float4 p0 = ((const float4*)(Pbuf + (size_t)(2 * row) * H_))[tid];
  float4 p1 = ((const float4*)(Pbuf + (size_t)(2 * row + 1) * H_))[tid];
  float4 v;
  v.x = a.x + p0.x + p1.x; v.y = a.y + p0.y + p1.y; v.z = a.z + p0.z + p1.z; v.w = a.w + p0.w + p1.w;
  float ss = v.x * v.x + v.y * v.y + v.z * v.z + v.w * v.w;
#pragma unroll
  for (int off = 32; off; off >>= 1) ss += __shfl_xor(ss, off, 64);
  __shared__ float red[4];
  int lane = tid & 63, wid = tid >> 6;
  if (lane == 0) red[wid] = ss;
  __syncthreads();
  float tot = red[0] + red[1] + red[2] + red[3];
  float inv = rsqrtf(tot * (1.0f / H_) + 1e-5f);
  float4 wv = ((const float4*)w)[tid];
  float4 o;
  o.x = v.x * inv * wv.x; o.y = v.y * inv * wv.y; o.z = v.z * inv * wv.z; o.w = v.w * inv * wv.w;
  ((float4*)(out + (size_t)row * H_))[tid] = o;
}

extern "C" void kernel_launch(void* const* d_in, const int* in_sizes, int n_in,
                              void* d_out, int out_size, void* d_ws, size_t ws_size,
                              hipStream_t stream) {
  const float* x = (const float*)d_in[0];
  const int* pos = (const int*)d_in[1];
  const float* qkv_w = (const float*)d_in[2];
  const float* o_w = (const float*)d_in[3];
  const float* nin_w = (const float*)d_in[4];
  const float* npost_w = (const float*)d_in[5];
  const float* nnext_w = (const float*)d_in[6];
  const float* gate_w = (const float*)d_in[7];
  const float* w1 = (const float*)d_in[8];
  const float* w3 = (const float*)d_in[9];
  const float* w2 = (const float*)d_in[10];
  float* out = (float*)d_out;

  // ---- persistent region ----
  float* resid = (float*)d_ws;                       // T*H
  float* h2 = resid + (size_t)T_ * H_;               // T*H
  float* Pbuf = h2 + (size_t)T_ * H_;                // 2*T*H
  float* topw = Pbuf + (size_t)2 * T_ * H_;          // 2T
  float* pairsw = topw + T_ * 2;                     // 4096
  unsigned short* h2b = (unsigned short*)(pairsw + 4096);  // T*H
  unsigned short* G = h2b + (size_t)T_ * H_;         // 2*T*II
  int* topi = (int*)(G + (size_t)2 * T_ * II_);      // 2T
  int* ctrl = topi + T_ * 2;
  int* counts = ctrl;
  int* counts2 = ctrl + 8;
  int* offsets = ctrl + 16;
  int* pairs_ts = ctrl + 24;                         // 4096
  char* trans = (char*)(pairs_ts + 4096);
  trans = (char*)(((uintptr_t)trans + 255) & ~(uintptr_t)255);

  // ---- transient: attention phase ----
  unsigned short* Aq = (unsigned short*)trans;       // T*3072
  unsigned short* Bq = Aq + (size_t)T_ * 3072;       // 1536*3072
  unsigned short* Bo = Bq + (size_t)1536 * 3072;     // 1024*3072
  unsigned short* Ao = Bo + (size_t)1024 * 3072;     // T*3072
  float* qkvb = (float*)(Ao + (size_t)T_ * 3072);    // T*1536
  float* ct = qkvb + (size_t)T_ * 1536;              // T*32
  float* st = ct + (size_t)T_ * 32;                  // T*32
  unsigned short* uu = (unsigned short*)(st + (size_t)T_ * 32);
  unsigned short* Qhi = uu;  uu += (size_t)HQ_ * T_ * D_;
  unsigned short* Qlo = uu;  uu += (size_t)HQ_ * T_ * D_;
  unsigned short* Khi = uu;  uu += (size_t)HK_ * T_ * D_;
  unsigned short* Klo = uu;  uu += (size_t)HK_ * T_ * D_;
  unsigned short* Vthi = uu; uu += (size_t)HK_ * D_ * T_;
  unsigned short* Vtlo = uu; uu += (size_t)HK_ * D_ * T_;

  // ---- transient: MoE phase (aliases attention transients; conv runs after router) ----
  unsigned short* W1b = (unsigned short*)trans;      // E*I*H
  unsigned short* W3b = W1b + (size_t)NE_ * II_ * H_;
  unsigned short* W2b = W3b + (size_t)NE_ * II_ * H_;

  const int WCNT8 = (NE_ * II_ * H_) / 8;

  hipMemsetAsync(ctrl, 0, 64, stream);  // counts + counts2
  k_rmsnorm_split<<<T_, 256, 0, stream>>>(x, nin_w, Aq);
  k_wsplit<<<2048, 256, 0, stream>>>(qkv_w, Bq, H_, 1536 * H_ / 8);
  k_wsplit<<<2048, 256, 0, stream>>>(o_w, Bo, HQ_ * D_, H_ * HQ_ * D_ / 8);
  k_hgemm<0><<<dim3(1536 / 64, T_ / 128), 256, 0, stream>>>(Aq, Bq, qkvb, nullptr, 1536, 3 * H_);
  k_rope_table<<<T_ * 32 / 256, 256, 0, stream>>>(pos, ct, st);
  k_rope_prep<<<T_, 256, 0, stream>>>(qkvb, ct, st, Qhi, Qlo, Khi, Klo);
  k_vtrans<<<dim3(T_ / 64, HK_), 256, 0, stream>>>(qkvb, Vthi, Vtlo);
  k_attn_mfma<<<dim3(1024), 128, 0, stream>>>(Qhi, Qlo, Khi, Klo, Vthi, Vtlo, Ao);
  k_hgemm<1><<<dim3(H_ / 64, T_ / 128), 256, 0, stream>>>(Ao, Bo, resid, x, H_, 3 * HQ_ * D_);
  k_rmsnorm<<<T_, 256, 0, stream>>>(resid, npost_w, h2, h2b);
  k_router<<<T_ / 4, 256, 0, stream>>>(h2, gate_w, topi, topw, counts);
  k_scan<<<1, 64, 0, stream>>>(counts, offsets);
  k_build<<<T_ / 256, 256, 0, stream>>>(topi, topw, offsets, counts2, pairs_ts, pairsw);
  // weight pre-conversion (attention transients are dead now) — single fused launch
  k_conv3<<<4096, 256, 0, stream>>>(w1, w3, w2, W1b, W3b, W2b, WCNT8);
  k_moe_up<<<dim3(II_ / 64, T_ / 128, NE_), 256, 0, stream>>>(h2b, W1b, W3b, pairs_ts, offsets, counts, G);
  k_moe_down<<<dim3(H_ / 64, T_ / 128, NE_), 256, 0, stream>>>(G, W2b, pairs_ts, pairsw, offsets, counts, Pbuf);
  k_final<<<T_, 256, 0, stream>>>(resid, Pbuf, nnext_w, out);
}

// Round 19
// 485.866 us; speedup vs baseline: 1.0386x; 1.0386x over previous
//
#include <hip/hip_runtime.h>
#include <hip/hip_bf16.h>
#include <math.h>

#define T_ 2048
#define H_ 1024
#define HQ_ 16
#define HK_ 4
#define D_ 64
#define NE_ 8
#define II_ 2048

typedef __attribute__((ext_vector_type(8))) short bf16x8;
typedef __attribute__((ext_vector_type(8))) unsigned short u16x8;
typedef __attribute__((ext_vector_type(4))) float f32x4;

// async global->LDS DMA: 16B per lane, dest = wave-uniform base + lane*16
#define GLOAD16(g, l)                                                                   \
  __builtin_amdgcn_global_load_lds((const __attribute__((address_space(1))) unsigned int*)(g), \
                                   (__attribute__((address_space(3))) unsigned int*)(l), 16, 0, 0)

__device__ __forceinline__ unsigned short f2bf(float f) {
  unsigned int u = __float_as_uint(f);
  return (unsigned short)((u + 0x7fffu + ((u >> 16) & 1u)) >> 16);
}
__device__ __forceinline__ float bf2f(unsigned short h) {
  return __uint_as_float((unsigned int)h << 16);
}

// ---------------- rmsnorm (fp32 in, fp32 out + optional bf16 out) ----------------
__global__ __launch_bounds__(256) void k_rmsnorm(const float* __restrict__ x, const float* __restrict__ w,
                                                 float* __restrict__ outf, unsigned short* __restrict__ outb) {
  int row = blockIdx.x;
  int tid = threadIdx.x;
  float4 v = ((const float4*)(x + (size_t)row * H_))[tid];
  float ss = v.x * v.x + v.y * v.y + v.z * v.z + v.w * v.w;
#pragma unroll
  for (int off = 32; off; off >>= 1) ss += __shfl_xor(ss, off, 64);
  __shared__ float red[4];
  int lane = tid & 63, wid = tid >> 6;
  if (lane == 0) red[wid] = ss;
  __syncthreads();
  float tot = red[0] + red[1] + red[2] + red[3];
  float inv = rsqrtf(tot * (1.0f / H_) + 1e-5f);
  float4 wv = ((const float4*)w)[tid];
  float4 o;
  o.x = v.x * inv * wv.x; o.y = v.y * inv * wv.y; o.z = v.z * inv * wv.z; o.w = v.w * inv * wv.w;
  ((float4*)(outf + (size_t)row * H_))[tid] = o;
  if (outb) {
    ushort4 b; b.x = f2bf(o.x); b.y = f2bf(o.y); b.z = f2bf(o.z); b.w = f2bf(o.w);
    ((ushort4*)(outb + (size_t)row * H_))[tid] = b;
  }
}

// ---------------- rmsnorm writing expanded bf16x3 A' = [hi|hi|lo] along K'=3H ----------------
__global__ __launch_bounds__(256) void k_rmsnorm_split(const float* __restrict__ x, const float* __restrict__ w,
                                                       unsigned short* __restrict__ Aq) {
  int row = blockIdx.x;
  int tid = threadIdx.x;
  float4 v = ((const float4*)(x + (size_t)row * H_))[tid];
  float ss = v.x * v.x + v.y * v.y + v.z * v.z + v.w * v.w;
#pragma unroll
  for (int off = 32; off; off >>= 1) ss += __shfl_xor(ss, off, 64);
  __shared__ float red[4];
  int lane = tid & 63, wid = tid >> 6;
  if (lane == 0) red[wid] = ss;
  __syncthreads();
  float tot = red[0] + red[1] + red[2] + red[3];
  float inv = rsqrtf(tot * (1.0f / H_) + 1e-5f);
  float4 wv = ((const float4*)w)[tid];
  float4 o;
  o.x = v.x * inv * wv.x; o.y = v.y * inv * wv.y; o.z = v.z * inv * wv.z; o.w = v.w * inv * wv.w;
  ushort4 hi, lo;
  hi.x = f2bf(o.x); hi.y = f2bf(o.y); hi.z = f2bf(o.z); hi.w = f2bf(o.w);
  lo.x = f2bf(o.x - bf2f(hi.x)); lo.y = f2bf(o.y - bf2f(hi.y));
  lo.z = f2bf(o.z - bf2f(hi.z)); lo.w = f2bf(o.w - bf2f(hi.w));
  size_t base = (size_t)row * (3 * H_) + tid * 4;
  *(ushort4*)(Aq + base) = hi;
  *(ushort4*)(Aq + base + H_) = hi;
  *(ushort4*)(Aq + base + 2 * H_) = lo;
}

// ---------------- weight split: W[N][K] fp32 -> W'[N][3K] bf16 = [hi|lo|hi] ----------------
__global__ __launch_bounds__(256) void k_wsplit(const float* __restrict__ in, unsigned short* __restrict__ out,
                                                int K, int n8total) {
  int stride = gridDim.x * 256;
  int kc8 = K >> 3;
  for (int i = blockIdx.x * 256 + threadIdx.x; i < n8total; i += stride) {
    int n = i / kc8, kc = (i - n * kc8) * 8;
    const float4* p = (const float4*)(in + (size_t)n * K + kc);
    float4 a = p[0], b = p[1];
    u16x8 hi, lo;
    hi[0] = f2bf(a.x); hi[1] = f2bf(a.y); hi[2] = f2bf(a.z); hi[3] = f2bf(a.w);
    hi[4] = f2bf(b.x); hi[5] = f2bf(b.y); hi[6] = f2bf(b.z); hi[7] = f2bf(b.w);
    lo[0] = f2bf(a.x - bf2f(hi[0])); lo[1] = f2bf(a.y - bf2f(hi[1]));
    lo[2] = f2bf(a.z - bf2f(hi[2])); lo[3] = f2bf(a.w - bf2f(hi[3]));
    lo[4] = f2bf(b.x - bf2f(hi[4])); lo[5] = f2bf(b.y - bf2f(hi[5]));
    lo[6] = f2bf(b.z - bf2f(hi[6])); lo[7] = f2bf(b.w - bf2f(hi[7]));
    size_t ob = (size_t)n * 3 * K + kc;
    *(u16x8*)(out + ob) = hi;
    *(u16x8*)(out + ob + K) = lo;
    *(u16x8*)(out + ob + 2 * K) = hi;
  }
}

// ---------------- bf16 GEMM (expanded-K bf16x3), m97-style gload_lds + dbuf ----------------
template <int ADD>
__global__ __launch_bounds__(256) void k_hgemm(const unsigned short* __restrict__ A, const unsigned short* __restrict__ B,
                                               float* __restrict__ C, const float* __restrict__ addsrc,
                                               int N, int K3) {
  int m0 = blockIdx.y * 128, n0 = blockIdx.x * 64;
  __shared__ unsigned short As[2][128 * 32];
  __shared__ unsigned short Bs[2][64 * 32];
  int tid = threadIdx.x, lane = tid & 63, w = tid >> 6;
  int wr = w >> 1, wc = w & 1;
  int l15 = lane & 15, lg = lane >> 4;
  int srow = lane >> 2, schunk = lane & 3;

  const unsigned short* ga0 = A + (size_t)(m0 + w * 32 + srow) * K3 + schunk * 8;
  const unsigned short* ga1 = A + (size_t)(m0 + w * 32 + 16 + srow) * K3 + schunk * 8;
  const unsigned short* gb = B + (size_t)(n0 + w * 16 + srow) * K3 + schunk * 8;

  f32x4 acc[4][2];
  f32x4 z = {0.f, 0.f, 0.f, 0.f};
#pragma unroll
  for (int a = 0; a < 4; a++)
#pragma unroll
    for (int b = 0; b < 2; b++) acc[a][b] = z;

  GLOAD16(ga0, &As[0][(w * 32) * 32]);
  GLOAD16(ga1, &As[0][(w * 32 + 16) * 32]);
  GLOAD16(gb, &Bs[0][(w * 16) * 32]);
  __syncthreads();

  int nt = K3 / 32;
  for (int t = 0; t < nt; ++t) {
    int cur = t & 1;
    if (t + 1 < nt) {
      int ko = (t + 1) * 32;
      GLOAD16(ga0 + ko, &As[cur ^ 1][(w * 32) * 32]);
      GLOAD16(ga1 + ko, &As[cur ^ 1][(w * 32 + 16) * 32]);
      GLOAD16(gb + ko, &Bs[cur ^ 1][(w * 16) * 32]);
    }
    bf16x8 af[4], bw2[2];
#pragma unroll
    for (int fa = 0; fa < 4; fa++)
      af[fa] = *(const bf16x8*)&As[cur][(wr * 64 + fa * 16 + l15) * 32 + lg * 8];
#pragma unroll
    for (int fb = 0; fb < 2; fb++)
      bw2[fb] = *(const bf16x8*)&Bs[cur][(wc * 32 + fb * 16 + l15) * 32 + lg * 8];
#pragma unroll
    for (int fa = 0; fa < 4; fa++)
#pragma unroll
      for (int fb = 0; fb < 2; fb++)
        acc[fa][fb] = __builtin_amdgcn_mfma_f32_16x16x32_bf16(af[fa], bw2[fb], acc[fa][fb], 0, 0, 0);
    __syncthreads();
  }
#pragma unroll
  for (int fa = 0; fa < 4; fa++)
#pragma unroll
    for (int r = 0; r < 4; r++) {
      int row = m0 + wr * 64 + fa * 16 + lg * 4 + r;
#pragma unroll
      for (int fb = 0; fb < 2; fb++) {
        int col = n0 + wc * 32 + fb * 16 + l15;
        float v = acc[fa][fb][r];
        if (ADD) v += addsrc[(size_t)row * N + col];
        C[(size_t)row * N + col] = v;
      }
    }
}

// ---------------- RoPE cos/sin table ----------------
__global__ __launch_bounds__(256) void k_rope_table(const int* __restrict__ pos, float* __restrict__ ct,
                                                    float* __restrict__ st) {
  int idx = blockIdx.x * 256 + threadIdx.x;  // T*32
  int t = idx >> 5, i = idx & 31;
  float p = (float)pow(10000.0, (double)i / 32.0);
  float freq = 1.0f / p;
  float ang = (float)pos[t] * freq;
  ct[idx] = cosf(ang);
  st[idx] = sinf(ang);
}

// ---------------- RoPE apply + bf16 hi/lo split ----------------
__global__ __launch_bounds__(256) void k_rope_prep(const float* __restrict__ qkv, const float* __restrict__ ct,
                                                   const float* __restrict__ st, unsigned short* __restrict__ Qhi,
                                                   unsigned short* __restrict__ Qlo, unsigned short* __restrict__ Khi,
                                                   unsigned short* __restrict__ Klo) {
  int t = blockIdx.x, tid = threadIdx.x;
  const float* row = qkv + (size_t)t * 1536;
#pragma unroll 2
  for (int it = tid; it < 512; it += 256) {
    int h = it >> 5, i = it & 31;
    float c = ct[t * 32 + i], s = st[t * 32 + i];
    float x1 = row[h * 64 + i], x2 = row[h * 64 + i + 32];
    float a = (x1 * c - x2 * s) * 0.125f;
    float b = (x2 * c + x1 * s) * 0.125f;
    size_t base = ((size_t)h * T_ + t) * 64 + i;
    unsigned short ah = f2bf(a), bh = f2bf(b);
    Qhi[base] = ah; Qhi[base + 32] = bh;
    Qlo[base] = f2bf(a - bf2f(ah));
    Qlo[base + 32] = f2bf(b - bf2f(bh));
  }
  if (tid < 128) {
    int h = tid >> 5, i = tid & 31;
    float c = ct[t * 32 + i], s = st[t * 32 + i];
    float x1 = row[1024 + h * 64 + i], x2 = row[1024 + h * 64 + i + 32];
    float a = x1 * c - x2 * s;
    float b = x2 * c + x1 * s;
    size_t base = ((size_t)h * T_ + t) * 64 + i;
    unsigned short ah = f2bf(a), bh = f2bf(b);
    Khi[base] = ah; Khi[base + 32] = bh;
    Klo[base] = f2bf(a - bf2f(ah));
    Klo[base + 32] = f2bf(b - bf2f(bh));
  }
}

// ---------------- V transpose + split: Vthi/Vtlo [kvh][d][t] ----------------
__global__ __launch_bounds__(256) void k_vtrans(const float* __restrict__ qkv, unsigned short* __restrict__ Vthi,
                                                unsigned short* __restrict__ Vtlo) {
  int t0 = blockIdx.x * 64, h = blockIdx.y;
  __shared__ float tile[64][65];
  int tid = threadIdx.x;
  int c = tid & 63, w = tid >> 6;
  for (int r = w; r < 64; r += 4)
    tile[r][c] = qkv[(size_t)(t0 + r) * 1536 + 1280 + h * 64 + c];
  __syncthreads();
  for (int d = w; d < 64; d += 4) {
    float v = tile[c][d];
    unsigned short hi = f2bf(v);
    size_t idx = ((size_t)h * 64 + d) * T_ + t0 + c;
    Vthi[idx] = hi;
    Vtlo[idx] = f2bf(v - bf2f(hi));
  }
}

// ---------------- flash attention, bf16x3; Ps aliases Ks (36.9KB LDS -> 4 blk/CU), direct staging ----------------
__global__ __launch_bounds__(256) void k_attn_mfma(const unsigned short* __restrict__ Qhi,
                                                   const unsigned short* __restrict__ Qlo,
                                                   const unsigned short* __restrict__ Khi,
                                                   const unsigned short* __restrict__ Klo,
                                                   const unsigned short* __restrict__ Vthi,
                                                   const unsigned short* __restrict__ Vtlo,
                                                   unsigned short* __restrict__ Ao) {
  int bid = blockIdx.x;
  int kk = bid >> 4;
  int head = bid & 15;
  // heavy-first: qidx 31..16 dispatch first, then 0..15
  int qidx = (kk < 16) ? (31 - kk) : (kk - 16);
  int qb = qidx * 64;
  int kvh = head >> 2;
  int tid = threadIdx.x, lane = tid & 63, w = tid >> 6;
  int l15 = lane & 15, lg = lane >> 4;

  // 4 x (64*72) shorts = 36.9 KB. Ps aliases Ks (Ks dead after QK^T; barrier-protected).
  __shared__ unsigned short S[4 * 64 * 72];
  unsigned short* KsH = S;
  unsigned short* KsL = S + 4608;
  unsigned short* VsH = S + 9216;
  unsigned short* VsL = S + 13824;
  unsigned short* PsH = KsH;
  unsigned short* PsL = KsL;

  bf16x8 qh[2], ql[2];
  {
    size_t qbase = ((size_t)head * T_ + qb + w * 16 + l15) * 64 + lg * 8;
    qh[0] = *(const bf16x8*)(Qhi + qbase);
    qh[1] = *(const bf16x8*)(Qhi + qbase + 32);
    ql[0] = *(const bf16x8*)(Qlo + qbase);
    ql[1] = *(const bf16x8*)(Qlo + qbase + 32);
  }
  f32x4 z = {0.f, 0.f, 0.f, 0.f};
  f32x4 Oa[4];
  float mrow[4], lrow[4];
#pragma unroll
  for (int r = 0; r < 4; r++) { mrow[r] = -1e30f; lrow[r] = 0.f; }
#pragma unroll
  for (int dg = 0; dg < 4; dg++) Oa[dg] = z;

  for (int jb = 0; jb <= qb; jb += 64) {
    // direct staging (short register liveness; previous tile's LDS reads protected by tile-end barrier)
    for (int c = tid; c < 512; c += 256) {
      int r = c >> 3, g = (c & 7) * 8;
      size_t kgl = ((size_t)kvh * T_ + jb + r) * 64 + g;
      size_t vgl = ((size_t)kvh * 64 + r) * T_ + jb + g;
      *(uint4*)&KsH[r * 72 + g] = *(const uint4*)(Khi + kgl);
      *(uint4*)&KsL[r * 72 + g] = *(const uint4*)(Klo + kgl);
      *(uint4*)&VsH[r * 72 + g] = *(const uint4*)(Vthi + vgl);
      *(uint4*)&VsL[r * 72 + g] = *(const uint4*)(Vtlo + vgl);
    }
    __syncthreads();

    f32x4 sc[4];
    sc[0] = z; sc[1] = z; sc[2] = z; sc[3] = z;
#pragma unroll
    for (int kg = 0; kg < 4; kg++) {
      int ba = (kg * 16 + l15) * 72 + lg * 8;
      bf16x8 bh0 = *(const bf16x8*)&KsH[ba];
      bf16x8 bh1 = *(const bf16x8*)&KsH[ba + 32];
      bf16x8 bl0 = *(const bf16x8*)&KsL[ba];
      bf16x8 bl1 = *(const bf16x8*)&KsL[ba + 32];
      sc[kg] = __builtin_amdgcn_mfma_f32_16x16x32_bf16(qh[0], bh0, sc[kg], 0, 0, 0);
      sc[kg] = __builtin_amdgcn_mfma_f32_16x16x32_bf16(qh[1], bh1, sc[kg], 0, 0, 0);
      sc[kg] = __builtin_amdgcn_mfma_f32_16x16x32_bf16(qh[0], bl0, sc[kg], 0, 0, 0);
      sc[kg] = __builtin_amdgcn_mfma_f32_16x16x32_bf16(qh[1], bl1, sc[kg], 0, 0, 0);
      sc[kg] = __builtin_amdgcn_mfma_f32_16x16x32_bf16(ql[0], bh0, sc[kg], 0, 0, 0);
      sc[kg] = __builtin_amdgcn_mfma_f32_16x16x32_bf16(ql[1], bh1, sc[kg], 0, 0, 0);
    }
    if (jb == qb) {
      int rb = w * 16 + lg * 4;
#pragma unroll
      for (int kg = 0; kg < 4; kg++) {
        int col = kg * 16 + l15;
#pragma unroll
        for (int r = 0; r < 4; r++)
          if (col > rb + r) sc[kg][r] = -1e30f;
      }
    }
#pragma unroll
    for (int r = 0; r < 4; r++) {
      float mt = fmaxf(fmaxf(sc[0][r], sc[1][r]), fmaxf(sc[2][r], sc[3][r]));
      mt = fmaxf(mt, __shfl_xor(mt, 1, 64));
      mt = fmaxf(mt, __shfl_xor(mt, 2, 64));
      mt = fmaxf(mt, __shfl_xor(mt, 4, 64));
      mt = fmaxf(mt, __shfl_xor(mt, 8, 64));
      float mnew = fmaxf(mrow[r], mt);
      float corr = __expf(mrow[r] - mnew);
      mrow[r] = mnew;
      float s = 0.f;
#pragma unroll
      for (int kg = 0; kg < 4; kg++) {
        float p = __expf(sc[kg][r] - mnew);
        sc[kg][r] = p;
        s += p;
      }
      s += __shfl_xor(s, 1, 64);
      s += __shfl_xor(s, 2, 64);
      s += __shfl_xor(s, 4, 64);
      s += __shfl_xor(s, 8, 64);
      lrow[r] = lrow[r] * corr + s;
      // per-ROW rescale (Oa[dg] components are 4 different rows)
#pragma unroll
      for (int dg = 0; dg < 4; dg++) Oa[dg][r] *= corr;
    }
    __syncthreads();  // all waves' QK reads of Ks done before Ps (alias) overwrite
    {
      int rb = w * 16 + lg * 4;
#pragma unroll
      for (int kg = 0; kg < 4; kg++) {
        int col = kg * 16 + l15;
#pragma unroll
        for (int r = 0; r < 4; r++) {
          float p = sc[kg][r];
          unsigned short ph = f2bf(p);
          PsH[(rb + r) * 72 + col] = ph;
          PsL[(rb + r) * 72 + col] = f2bf(p - bf2f(ph));
        }
      }
    }
    {
      // PV: A-frag rows w*16..w*16+15 == rows this wave just wrote (same-wave, no barrier)
      int ab = (w * 16 + l15) * 72 + lg * 8;
      bf16x8 ph0 = *(const bf16x8*)&PsH[ab];
      bf16x8 ph1 = *(const bf16x8*)&PsH[ab + 32];
      bf16x8 pl0 = *(const bf16x8*)&PsL[ab];
      bf16x8 pl1 = *(const bf16x8*)&PsL[ab + 32];
#pragma unroll
      for (int dg = 0; dg < 4; dg++) {
        int vb = (dg * 16 + l15) * 72 + lg * 8;
        bf16x8 vh0 = *(const bf16x8*)&VsH[vb];
        bf16x8 vh1 = *(const bf16x8*)&VsH[vb + 32];
        bf16x8 vl0 = *(const bf16x8*)&VsL[vb];
        bf16x8 vl1 = *(const bf16x8*)&VsL[vb + 32];
        Oa[dg] = __builtin_amdgcn_mfma_f32_16x16x32_bf16(ph0, vh0, Oa[dg], 0, 0, 0);
        Oa[dg] = __builtin_amdgcn_mfma_f32_16x16x32_bf16(ph1, vh1, Oa[dg], 0, 0, 0);
        Oa[dg] = __builtin_amdgcn_mfma_f32_16x16x32_bf16(ph0, vl0, Oa[dg], 0, 0, 0);
        Oa[dg] = __builtin_amdgcn_mfma_f32_16x16x32_bf16(ph1, vl1, Oa[dg], 0, 0, 0);
        Oa[dg] = __builtin_amdgcn_mfma_f32_16x16x32_bf16(pl0, vh0, Oa[dg], 0, 0, 0);
        Oa[dg] = __builtin_amdgcn_mfma_f32_16x16x32_bf16(pl1, vh1, Oa[dg], 0, 0, 0);
      }
    }
    __syncthreads();  // Ps/Vs reads done before next tile's staging writes
  }
#pragma unroll
  for (int r = 0; r < 4; r++) {
    float inv = 1.0f / lrow[r];
    size_t rb2 = (size_t)(qb + w * 16 + lg * 4 + r) * 3072 + head * 64;
#pragma unroll
    for (int dg = 0; dg < 4; dg++) {
      float v = Oa[dg][r] * inv;
      unsigned short hi2 = f2bf(v);
      unsigned short lo2 = f2bf(v - bf2f(hi2));
      Ao[rb2 + dg * 16 + l15] = hi2;
      Ao[rb2 + 1024 + dg * 16 + l15] = hi2;
      Ao[rb2 + 2048 + dg * 16 + l15] = lo2;
    }
  }
}

// ---------------- router ----------------
__global__ __launch_bounds__(256) void k_router(const float* __restrict__ h2, const float* __restrict__ gw,
                                                int* __restrict__ topi, float* __restrict__ topw,
                                                int* __restrict__ counts) {
  int wid = threadIdx.x >> 6, lane = threadIdx.x & 63;
  int t = blockIdx.x * 4 + wid;
  const float* hr = h2 + (size_t)t * H_;
  float hv[16];
#pragma unroll
  for (int i = 0; i < 16; i++) hv[i] = hr[lane + 64 * i];
  float le[8];
#pragma unroll
  for (int e = 0; e < 8; e++) {
    const float* g = gw + (size_t)e * H_;
    float acc = 0.f;
#pragma unroll
    for (int i = 0; i < 16; i++) acc += hv[i] * g[lane + 64 * i];
#pragma unroll
    for (int off = 32; off; off >>= 1) acc += __shfl_xor(acc, off, 64);
    le[e] = acc;
  }
  if (lane == 0) {
    int i0 = 0;
#pragma unroll
    for (int e = 1; e < 8; e++)
      if (le[e] > le[i0]) i0 = e;
    int i1 = (i0 == 0) ? 1 : 0;
#pragma unroll
    for (int e = 0; e < 8; e++) {
      if (e == i0) continue;
      if (le[e] > le[i1]) i1 = e;
    }
    float w1r = expf(le[i1] - le[i0]);
    float denom = 1.0f + w1r;
    topi[t * 2 + 0] = i0;
    topi[t * 2 + 1] = i1;
    topw[t * 2 + 0] = 1.0f / denom;
    topw[t * 2 + 1] = w1r / denom;
    atomicAdd(&counts[i0], 1);
    atomicAdd(&counts[i1], 1);
  }
}

__global__ void k_scan(const int* __restrict__ counts, int* __restrict__ offsets) {
  if (threadIdx.x == 0 && blockIdx.x == 0) {
    int off = 0;
    for (int e = 0; e < NE_; e++) { offsets[e] = off; off += counts[e]; }
  }
}

__global__ __launch_bounds__(256) void k_build(const int* __restrict__ topi, const float* __restrict__ topw,
                                               const int* __restrict__ offsets, int* __restrict__ counts2,
                                               int* __restrict__ pairs_ts, float* __restrict__ pairs_w) {
  int t = blockIdx.x * 256 + threadIdx.x;
#pragma unroll
  for (int s = 0; s < 2; s++) {
    int e = topi[t * 2 + s];
    int slot = atomicAdd(&counts2[e], 1);
    int p = offsets[e] + slot;
    pairs_ts[p] = t * 2 + s;
    pairs_w[p] = topw[t * 2 + s];
  }
}

// ---------------- fp32 -> bf16 bulk convert, all three MoE weights in one launch ----------------
__global__ __launch_bounds__(256) void k_conv3(const float* __restrict__ w1, const float* __restrict__ w3,
                                               const float* __restrict__ w2, unsigned short* __restrict__ W1b,
                                               unsigned short* __restrict__ W3b, unsigned short* __restrict__ W2b,
                                               int n8each) {
  int stride = gridDim.x * 256;
  int total = 3 * n8each;
  for (int i = blockIdx.x * 256 + threadIdx.x; i < total; i += stride) {
    int sel = i / n8each;
    int j = i - sel * n8each;
    const float* in = (sel == 0) ? w1 : (sel == 1) ? w3 : w2;
    unsigned short* out = (sel == 0) ? W1b : (sel == 1) ? W3b : W2b;
    const float4* p = (const float4*)in + (size_t)j * 2;
    float4 a = p[0], b = p[1];
    u16x8 t;
    t[0] = f2bf(a.x); t[1] = f2bf(a.y); t[2] = f2bf(a.z); t[3] = f2bf(a.w);
    t[4] = f2bf(b.x); t[5] = f2bf(b.y); t[6] = f2bf(b.z); t[7] = f2bf(b.w);
    *((u16x8*)out + j) = t;
  }
}

// ---------------- MoE up: 128x64 tile, BK=32, gload_lds dbuf, silu epilogue ----------------
__global__ __launch_bounds__(256) void k_moe_up(const unsigned short* __restrict__ h2b, const unsigned short* __restrict__ W1b,
                                                const unsigned short* __restrict__ W3b, const int* __restrict__ pairs_ts,
                                                const int* __restrict__ offsets, const int* __restrict__ counts,
                                                unsigned short* __restrict__ G) {
  int e = blockIdx.z;
  int ne = counts[e];
  int row0 = blockIdx.y * 128;
  if (row0 >= ne) return;
  int col0 = blockIdx.x * 64;
  int pbase = offsets[e];
  __shared__ unsigned short As[2][128 * 32];
  __shared__ unsigned short B1s[2][64 * 32];
  __shared__ unsigned short B2s[2][64 * 32];
  int tid = threadIdx.x, lane = tid & 63, w = tid >> 6;
  int wr = w >> 1, wc = w & 1;
  int l15 = lane & 15, lg = lane >> 4;
  int srow = lane >> 2, schunk = lane & 3;

  int gr0 = row0 + w * 32 + srow, gr1 = gr0 + 16;
  int tok0 = (gr0 < ne) ? (pairs_ts[pbase + gr0] >> 1) : 0;
  int tok1 = (gr1 < ne) ? (pairs_ts[pbase + gr1] >> 1) : 0;
  const unsigned short* ga0 = h2b + (size_t)tok0 * H_ + schunk * 8;
  const unsigned short* ga1 = h2b + (size_t)tok1 * H_ + schunk * 8;
  const unsigned short* gb1 = W1b + ((size_t)e * II_ + col0 + w * 16 + srow) * H_ + schunk * 8;
  const unsigned short* gb3 = W3b + ((size_t)e * II_ + col0 + w * 16 + srow) * H_ + schunk * 8;

  f32x4 acc1[4][2], acc2[4][2];
  f32x4 z = {0.f, 0.f, 0.f, 0.f};
#pragma unroll
  for (int a = 0; a < 4; a++)
#pragma unroll
    for (int b = 0; b < 2; b++) { acc1[a][b] = z; acc2[a][b] = z; }

  GLOAD16(ga0, &As[0][(w * 32) * 32]);
  GLOAD16(ga1, &As[0][(w * 32 + 16) * 32]);
  GLOAD16(gb1, &B1s[0][(w * 16) * 32]);
  GLOAD16(gb3, &B2s[0][(w * 16) * 32]);
  __syncthreads();

  for (int t = 0; t < H_ / 32; ++t) {
    int cur = t & 1;
    if (t + 1 < H_ / 32) {
      int ko = (t + 1) * 32;
      GLOAD16(ga0 + ko, &As[cur ^ 1][(w * 32) * 32]);
      GLOAD16(ga1 + ko, &As[cur ^ 1][(w * 32 + 16) * 32]);
      GLOAD16(gb1 + ko, &B1s[cur ^ 1][(w * 16) * 32]);
      GLOAD16(gb3 + ko, &B2s[cur ^ 1][(w * 16) * 32]);
    }
    bf16x8 af[4], b1f[2], b2f[2];
#pragma unroll
    for (int fa = 0; fa < 4; fa++)
      af[fa] = *(const bf16x8*)&As[cur][(wr * 64 + fa * 16 + l15) * 32 + lg * 8];
#pragma unroll
    for (int fb = 0; fb < 2; fb++) {
      b1f[fb] = *(const bf16x8*)&B1s[cur][(wc * 32 + fb * 16 + l15) * 32 + lg * 8];
      b2f[fb] = *(const bf16x8*)&B2s[cur][(wc * 32 + fb * 16 + l15) * 32 + lg * 8];
    }
#pragma unroll
    for (int fa = 0; fa < 4; fa++)
#pragma unroll
      for (int fb = 0; fb < 2; fb++) {
        acc1[fa][fb] = __builtin_amdgcn_mfma_f32_16x16x32_bf16(af[fa], b1f[fb], acc1[fa][fb], 0, 0, 0);
        acc2[fa][fb] = __builtin_amdgcn_mfma_f32_16x16x32_bf16(af[fa], b2f[fb], acc2[fa][fb], 0, 0, 0);
      }
    __syncthreads();
  }
#pragma unroll
  for (int fa = 0; fa < 4; fa++)
#pragma unroll
    for (int r = 0; r < 4; r++) {
      int prow = row0 + wr * 64 + fa * 16 + lg * 4 + r;
      if (prow < ne) {
#pragma unroll
        for (int fb = 0; fb < 2; fb++) {
          int icol = col0 + wc * 32 + fb * 16 + l15;
          float h1 = acc1[fa][fb][r], h3 = acc2[fa][fb][r];
          float g = h1 / (1.0f + __expf(-h1)) * h3;
          G[(size_t)(pbase + prow) * II_ + icol] = f2bf(g);
        }
      }
    }
}

// ---------------- MoE down: 128x64 tile, BK=32, gload_lds dbuf, weighted store ----------------
__global__ __launch_bounds__(256) void k_moe_down(const unsigned short* __restrict__ G, const unsigned short* __restrict__ W2b,
                                                  const int* __restrict__ pairs_ts, const float* __restrict__ pairs_w,
                                                  const int* __restrict__ offsets, const int* __restrict__ counts,
                                                  float* __restrict__ Pbuf) {
  int e = blockIdx.z;
  int ne = counts[e];
  int row0 = blockIdx.y * 128;
  if (row0 >= ne) return;
  int col0 = blockIdx.x * 64;
  int pbase = offsets[e];
  __shared__ unsigned short As[2][128 * 32];
  __shared__ unsigned short Bs[2][64 * 32];
  int tid = threadIdx.x, lane = tid & 63, w = tid >> 6;
  int wr = w >> 1, wc = w & 1;
  int l15 = lane & 15, lg = lane >> 4;
  int srow = lane >> 2, schunk = lane & 3;

  int gr0 = row0 + w * 32 + srow, gr1 = gr0 + 16;
  int p0 = pbase + ((gr0 < ne) ? gr0 : 0);
  int p1 = pbase + ((gr1 < ne) ? gr1 : 0);
  const unsigned short* ga0 = G + (size_t)p0 * II_ + schunk * 8;
  const unsigned short* ga1 = G + (size_t)p1 * II_ + schunk * 8;
  const unsigned short* gb = W2b + ((size_t)e * H_ + col0 + w * 16 + srow) * II_ + schunk * 8;

  f32x4 acc[4][2];
  f32x4 z = {0.f, 0.f, 0.f, 0.f};
#pragma unroll
  for (int a = 0; a < 4; a++)
#pragma unroll
    for (int b = 0; b < 2; b++) acc[a][b] = z;

  GLOAD16(ga0, &As[0][(w * 32) * 32]);
  GLOAD16(ga1, &As[0][(w * 32 + 16) * 32]);
  GLOAD16(gb, &Bs[0][(w * 16) * 32]);
  __syncthreads();

  for (int t = 0; t < II_ / 32; ++t) {
    int cur = t & 1;
    if (t + 1 < II_ / 32) {
      int ko = (t + 1) * 32;
      GLOAD16(ga0 + ko, &As[cur ^ 1][(w * 32) * 32]);
      GLOAD16(ga1 + ko, &As[cur ^ 1][(w * 32 + 16) * 32]);
      GLOAD16(gb + ko, &Bs[cur ^ 1][(w * 16) * 32]);
    }
    bf16x8 af[4], bw2[2];
#pragma unroll
    for (int fa = 0; fa < 4; fa++)
      af[fa] = *(const bf16x8*)&As[cur][(wr * 64 + fa * 16 + l15) * 32 + lg * 8];
#pragma unroll
    for (int fb = 0; fb < 2; fb++)
      bw2[fb] = *(const bf16x8*)&Bs[cur][(wc * 32 + fb * 16 + l15) * 32 + lg * 8];
#pragma unroll
    for (int fa = 0; fa < 4; fa++)
#pragma unroll
      for (int fb = 0; fb < 2; fb++)
        acc[fa][fb] = __builtin_amdgcn_mfma_f32_16x16x32_bf16(af[fa], bw2[fb], acc[fa][fb], 0, 0, 0);
    __syncthreads();
  }
#pragma unroll
  for (int fa = 0; fa < 4; fa++)
#pragma unroll
    for (int r = 0; r < 4; r++) {
      int prow = row0 + wr * 64 + fa * 16 + lg * 4 + r;
      if (prow < ne) {
        int p = pbase + prow;
        int ts = pairs_ts[p];
        float wgt = pairs_w[p];
#pragma unroll
        for (int fb = 0; fb < 2; fb++) {
          int col = col0 + wc * 32 + fb * 16 + l15;
          Pbuf[(size_t)ts * H_ + col] = wgt * acc[fa][fb][r];
        }
      }
    }
}

// ---------------- final: out = rmsnorm(resid + P0 + P1) ----------------
__global__ __launch_bounds__(256) void k_final(const float* __restrict__ resid, const float* __restrict__ Pbuf,
                                               const float* __restrict__ w, float* __restrict__ out) {
  int row = blockIdx.x;
  int tid = threadIdx.x;
  float4 a = ((const float4*)(resid + (size_t)row * H_))[tid];
  float4 p0 = ((const float4*)(Pbuf + (size_t)(2 * row) * H_))[tid];
  float4 p1 = ((const float4*)(Pbuf + (size_t)(2 * row + 1) * H_))[tid];
  float4 v;
  v.x = a.x + p0.x + p1.x; v.y = a.y + p0.y + p1.y; v.z = a.z + p0.z + p1.z; v.w = a.w + p0.w + p1.w;
  float ss = v.x * v.x + v.y * v.y + v.z * v.z + v.w * v.w;
#pragma unroll
  for (int off = 32; off; off >>= 1) ss += __shfl_xor(ss, off, 64);
  __shared__ float red[4];
  int lane = tid & 63, wid = tid >> 6;
  if (lane == 0) red[wid] = ss;
  __syncthreads();
  float tot = red[0] + red[1] + red[2] + red[3];
  float inv = rsqrtf(tot * (1.0f / H_) + 1e-5f);
  float4 wv = ((const float4*)w)[tid];
  float4 o;
  o.x = v.x * inv * wv.x; o.y = v.y * inv * wv.y; o.z = v.z * inv * wv.z; o.w = v.w * inv * wv.w;
  ((float4*)(out + (size_t)row * H_))[tid] = o;
}

extern "C" void kernel_launch(void* const* d_in, const int* in_sizes, int n_in,
                              void* d_out, int out_size, void* d_ws, size_t ws_size,
                              hipStream_t stream) {
  const float* x = (const float*)d_in[0];
  const int* pos = (const int*)d_in[1];
  const float* qkv_w = (const float*)d_in[2];
  const float* o_w = (const float*)d_in[3];
  const float* nin_w = (const float*)d_in[4];
  const float* npost_w = (const float*)d_in[5];
  const float* nnext_w = (const float*)d_in[6];
  const float* gate_w = (const float*)d_in[7];
  const float* w1 = (const float*)d_in[8];
  const float* w3 = (const float*)d_in[9];
  const float* w2 = (const float*)d_in[10];
  float* out = (float*)d_out;

  // ---- persistent region ----
  float* resid = (float*)d_ws;                       // T*H
  float* h2 = resid + (size_t)T_ * H_;               // T*H
  float* Pbuf = h2 + (size_t)T_ * H_;                // 2*T*H
  float* topw = Pbuf + (size_t)2 * T_ * H_;          // 2T
  float* pairsw = topw + T_ * 2;                     // 4096
  unsigned short* h2b = (unsigned short*)(pairsw + 4096);  // T*H
  unsigned short* G = h2b + (size_t)T_ * H_;         // 2*T*II
  int* topi = (int*)(G + (size_t)2 * T_ * II_);      // 2T
  int* ctrl = topi + T_ * 2;
  int* counts = ctrl;
  int* counts2 = ctrl + 8;
  int* offsets = ctrl + 16;
  int* pairs_ts = ctrl + 24;                         // 4096
  char* trans = (char*)(pairs_ts + 4096);
  trans = (char*)(((uintptr_t)trans + 255) & ~(uintptr_t)255);

  // ---- transient: attention phase ----
  unsigned short* Aq = (unsigned short*)trans;       // T*3072
  unsigned short* Bq = Aq + (size_t)T_ * 3072;       // 1536*3072
  unsigned short* Bo = Bq + (size_t)1536 * 3072;     // 1024*3072
  unsigned short* Ao = Bo + (size_t)1024 * 3072;     // T*3072
  float* qkvb = (float*)(Ao + (size_t)T_ * 3072);    // T*1536
  float* ct = qkvb + (size_t)T_ * 1536;              // T*32
  float* st = ct + (size_t)T_ * 32;                  // T*32
  unsigned short* uu = (unsigned short*)(st + (size_t)T_ * 32);
  unsigned short* Qhi = uu;  uu += (size_t)HQ_ * T_ * D_;
  unsigned short* Qlo = uu;  uu += (size_t)HQ_ * T_ * D_;
  unsigned short* Khi = uu;  uu += (size_t)HK_ * T_ * D_;
  unsigned short* Klo = uu;  uu += (size_t)HK_ * T_ * D_;
  unsigned short* Vthi = uu; uu += (size_t)HK_ * D_ * T_;
  unsigned short* Vtlo = uu; uu += (size_t)HK_ * D_ * T_;

  // ---- transient: MoE phase (aliases attention transients; conv runs after router) ----
  unsigned short* W1b = (unsigned short*)trans;      // E*I*H
  unsigned short* W3b = W1b + (size_t)NE_ * II_ * H_;
  unsigned short* W2b = W3b + (size_t)NE_ * II_ * H_;

  const int WCNT8 = (NE_ * II_ * H_) / 8;

  hipMemsetAsync(ctrl, 0, 64, stream);  // counts + counts2
  k_rmsnorm_split<<<T_, 256, 0, stream>>>(x, nin_w, Aq);
  k_wsplit<<<2048, 256, 0, stream>>>(qkv_w, Bq, H_, 1536 * H_ / 8);
  k_wsplit<<<2048, 256, 0, stream>>>(o_w, Bo, HQ_ * D_, H_ * HQ_ * D_ / 8);
  k_hgemm<0><<<dim3(1536 / 64, T_ / 128), 256, 0, stream>>>(Aq, Bq, qkvb, nullptr, 1536, 3 * H_);
  k_rope_table<<<T_ * 32 / 256, 256, 0, stream>>>(pos, ct, st);
  k_rope_prep<<<T_, 256, 0, stream>>>(qkvb, ct, st, Qhi, Qlo, Khi, Klo);
  k_vtrans<<<dim3(T_ / 64, HK_), 256, 0, stream>>>(qkvb, Vthi, Vtlo);
  k_attn_mfma<<<dim3(512), 256, 0, stream>>>(Qhi, Qlo, Khi, Klo, Vthi, Vtlo, Ao);
  k_hgemm<1><<<dim3(H_ / 64, T_ / 128), 256, 0, stream>>>(Ao, Bo, resid, x, H_, 3 * HQ_ * D_);
  k_rmsnorm<<<T_, 256, 0, stream>>>(resid, npost_w, h2, h2b);
  k_router<<<T_ / 4, 256, 0, stream>>>(h2, gate_w, topi, topw, counts);
  k_scan<<<1, 64, 0, stream>>>(counts, offsets);
  k_build<<<T_ / 256, 256, 0, stream>>>(topi, topw, offsets, counts2, pairs_ts, pairsw);
  // weight pre-conversion (attention transients are dead now) — single fused launch
  k_conv3<<<4096, 256, 0, stream>>>(w1, w3, w2, W1b, W3b, W2b, WCNT8);
  k_moe_up<<<dim3(II_ / 64, T_ / 128, NE_), 256, 0, stream>>>(h2b, W1b, W3b, pairs_ts, offsets, counts, G);
  k_moe_down<<<dim3(H_ / 64, T_ / 128, NE_), 256, 0, stream>>>(G, W2b, pairs_ts, pairsw, offsets, counts, Pbuf);
  k_final<<<T_, 256, 0, stream>>>(resid, Pbuf, nnext_w, out);
}

// Round 20
// 481.565 us; speedup vs baseline: 1.0478x; 1.0089x over previous
//
#include <hip/hip_runtime.h>
#include <hip/hip_bf16.h>
#include <math.h>

#define T_ 2048
#define H_ 1024
#define HQ_ 16
#define HK_ 4
#define D_ 64
#define NE_ 8
#define II_ 2048

typedef __attribute__((ext_vector_type(8))) short bf16x8;
typedef __attribute__((ext_vector_type(8))) unsigned short u16x8;
typedef __attribute__((ext_vector_type(4))) float f32x4;

// async global->LDS DMA: 16B per lane, dest = wave-uniform base + lane*16
#define GLOAD16(g, l)                                                                   \
  __builtin_amdgcn_global_load_lds((const __attribute__((address_space(1))) unsigned int*)(g), \
                                   (__attribute__((address_space(3))) unsigned int*)(l), 16, 0, 0)

__device__ __forceinline__ unsigned short f2bf(float f) {
  unsigned int u = __float_as_uint(f);
  return (unsigned short)((u + 0x7fffu + ((u >> 16) & 1u)) >> 16);
}
__device__ __forceinline__ float bf2f(unsigned short h) {
  return __uint_as_float((unsigned int)h << 16);
}

// ---------------- rmsnorm writing expanded bf16x3 A' = [hi|hi|lo] along K'=3H ----------------
__global__ __launch_bounds__(256) void k_rmsnorm_split(const float* __restrict__ x, const float* __restrict__ w,
                                                       unsigned short* __restrict__ Aq) {
  int row = blockIdx.x;
  int tid = threadIdx.x;
  float4 v = ((const float4*)(x + (size_t)row * H_))[tid];
  float ss = v.x * v.x + v.y * v.y + v.z * v.z + v.w * v.w;
#pragma unroll
  for (int off = 32; off; off >>= 1) ss += __shfl_xor(ss, off, 64);
  __shared__ float red[4];
  int lane = tid & 63, wid = tid >> 6;
  if (lane == 0) red[wid] = ss;
  __syncthreads();
  float tot = red[0] + red[1] + red[2] + red[3];
  float inv = rsqrtf(tot * (1.0f / H_) + 1e-5f);
  float4 wv = ((const float4*)w)[tid];
  float4 o;
  o.x = v.x * inv * wv.x; o.y = v.y * inv * wv.y; o.z = v.z * inv * wv.z; o.w = v.w * inv * wv.w;
  ushort4 hi, lo;
  hi.x = f2bf(o.x); hi.y = f2bf(o.y); hi.z = f2bf(o.z); hi.w = f2bf(o.w);
  lo.x = f2bf(o.x - bf2f(hi.x)); lo.y = f2bf(o.y - bf2f(hi.y));
  lo.z = f2bf(o.z - bf2f(hi.z)); lo.w = f2bf(o.w - bf2f(hi.w));
  size_t base = (size_t)row * (3 * H_) + tid * 4;
  *(ushort4*)(Aq + base) = hi;
  *(ushort4*)(Aq + base + H_) = hi;
  *(ushort4*)(Aq + base + 2 * H_) = lo;
}

// ---------------- weight split: W[N][K] fp32 -> W'[N][3K] bf16 = [hi|lo|hi] ----------------
__global__ __launch_bounds__(256) void k_wsplit(const float* __restrict__ in, unsigned short* __restrict__ out,
                                                int K, int n8total) {
  int stride = gridDim.x * 256;
  int kc8 = K >> 3;
  for (int i = blockIdx.x * 256 + threadIdx.x; i < n8total; i += stride) {
    int n = i / kc8, kc = (i - n * kc8) * 8;
    const float4* p = (const float4*)(in + (size_t)n * K + kc);
    float4 a = p[0], b = p[1];
    u16x8 hi, lo;
    hi[0] = f2bf(a.x); hi[1] = f2bf(a.y); hi[2] = f2bf(a.z); hi[3] = f2bf(a.w);
    hi[4] = f2bf(b.x); hi[5] = f2bf(b.y); hi[6] = f2bf(b.z); hi[7] = f2bf(b.w);
    lo[0] = f2bf(a.x - bf2f(hi[0])); lo[1] = f2bf(a.y - bf2f(hi[1]));
    lo[2] = f2bf(a.z - bf2f(hi[2])); lo[3] = f2bf(a.w - bf2f(hi[3]));
    lo[4] = f2bf(b.x - bf2f(hi[4])); lo[5] = f2bf(b.y - bf2f(hi[5]));
    lo[6] = f2bf(b.z - bf2f(hi[6])); lo[7] = f2bf(b.w - bf2f(hi[7]));
    size_t ob = (size_t)n * 3 * K + kc;
    *(u16x8*)(out + ob) = hi;
    *(u16x8*)(out + ob + K) = lo;
    *(u16x8*)(out + ob + 2 * K) = hi;
  }
}

// ---------------- bf16 GEMM (expanded-K bf16x3), m97-style gload_lds + dbuf ----------------
template <int ADD>
__global__ __launch_bounds__(256) void k_hgemm(const unsigned short* __restrict__ A, const unsigned short* __restrict__ B,
                                               float* __restrict__ C, const float* __restrict__ addsrc,
                                               int N, int K3) {
  int m0 = blockIdx.y * 128, n0 = blockIdx.x * 64;
  __shared__ unsigned short As[2][128 * 32];
  __shared__ unsigned short Bs[2][64 * 32];
  int tid = threadIdx.x, lane = tid & 63, w = tid >> 6;
  int wr = w >> 1, wc = w & 1;
  int l15 = lane & 15, lg = lane >> 4;
  int srow = lane >> 2, schunk = lane & 3;

  const unsigned short* ga0 = A + (size_t)(m0 + w * 32 + srow) * K3 + schunk * 8;
  const unsigned short* ga1 = A + (size_t)(m0 + w * 32 + 16 + srow) * K3 + schunk * 8;
  const unsigned short* gb = B + (size_t)(n0 + w * 16 + srow) * K3 + schunk * 8;

  f32x4 acc[4][2];
  f32x4 z = {0.f, 0.f, 0.f, 0.f};
#pragma unroll
  for (int a = 0; a < 4; a++)
#pragma unroll
    for (int b = 0; b < 2; b++) acc[a][b] = z;

  GLOAD16(ga0, &As[0][(w * 32) * 32]);
  GLOAD16(ga1, &As[0][(w * 32 + 16) * 32]);
  GLOAD16(gb, &Bs[0][(w * 16) * 32]);
  __syncthreads();

  int nt = K3 / 32;
  for (int t = 0; t < nt; ++t) {
    int cur = t & 1;
    if (t + 1 < nt) {
      int ko = (t + 1) * 32;
      GLOAD16(ga0 + ko, &As[cur ^ 1][(w * 32) * 32]);
      GLOAD16(ga1 + ko, &As[cur ^ 1][(w * 32 + 16) * 32]);
      GLOAD16(gb + ko, &Bs[cur ^ 1][(w * 16) * 32]);
    }
    bf16x8 af[4], bw2[2];
#pragma unroll
    for (int fa = 0; fa < 4; fa++)
      af[fa] = *(const bf16x8*)&As[cur][(wr * 64 + fa * 16 + l15) * 32 + lg * 8];
#pragma unroll
    for (int fb = 0; fb < 2; fb++)
      bw2[fb] = *(const bf16x8*)&Bs[cur][(wc * 32 + fb * 16 + l15) * 32 + lg * 8];
#pragma unroll
    for (int fa = 0; fa < 4; fa++)
#pragma unroll
      for (int fb = 0; fb < 2; fb++)
        acc[fa][fb] = __builtin_amdgcn_mfma_f32_16x16x32_bf16(af[fa], bw2[fb], acc[fa][fb], 0, 0, 0);
    __syncthreads();
  }
#pragma unroll
  for (int fa = 0; fa < 4; fa++)
#pragma unroll
    for (int r = 0; r < 4; r++) {
      int row = m0 + wr * 64 + fa * 16 + lg * 4 + r;
#pragma unroll
      for (int fb = 0; fb < 2; fb++) {
        int col = n0 + wc * 32 + fb * 16 + l15;
        float v = acc[fa][fb][r];
        if (ADD) v += addsrc[(size_t)row * N + col];
        C[(size_t)row * N + col] = v;
      }
    }
}

// ---------------- RoPE apply + bf16 hi/lo split (cos/sin table computed in-block) ----------------
__global__ __launch_bounds__(256) void k_rope_prep(const float* __restrict__ qkv, const int* __restrict__ pos,
                                                   unsigned short* __restrict__ Qhi, unsigned short* __restrict__ Qlo,
                                                   unsigned short* __restrict__ Khi, unsigned short* __restrict__ Klo) {
  int t = blockIdx.x, tid = threadIdx.x;
  __shared__ float cs[32], sn[32];
  if (tid < 32) {
    float p = (float)pow(10000.0, (double)tid / 32.0);
    float freq = 1.0f / p;
    float ang = (float)pos[t] * freq;
    cs[tid] = cosf(ang);
    sn[tid] = sinf(ang);
  }
  __syncthreads();
  const float* row = qkv + (size_t)t * 1536;
#pragma unroll 2
  for (int it = tid; it < 512; it += 256) {
    int h = it >> 5, i = it & 31;
    float c = cs[i], s = sn[i];
    float x1 = row[h * 64 + i], x2 = row[h * 64 + i + 32];
    float a = (x1 * c - x2 * s) * 0.125f;
    float b = (x2 * c + x1 * s) * 0.125f;
    size_t base = ((size_t)h * T_ + t) * 64 + i;
    unsigned short ah = f2bf(a), bh = f2bf(b);
    Qhi[base] = ah; Qhi[base + 32] = bh;
    Qlo[base] = f2bf(a - bf2f(ah));
    Qlo[base + 32] = f2bf(b - bf2f(bh));
  }
  if (tid < 128) {
    int h = tid >> 5, i = tid & 31;
    float c = cs[i], s = sn[i];
    float x1 = row[1024 + h * 64 + i], x2 = row[1024 + h * 64 + i + 32];
    float a = x1 * c - x2 * s;
    float b = x2 * c + x1 * s;
    size_t base = ((size_t)h * T_ + t) * 64 + i;
    unsigned short ah = f2bf(a), bh = f2bf(b);
    Khi[base] = ah; Khi[base + 32] = bh;
    Klo[base] = f2bf(a - bf2f(ah));
    Klo[base + 32] = f2bf(b - bf2f(bh));
  }
}

// ---------------- V transpose + split: Vthi/Vtlo [kvh][d][t] ----------------
__global__ __launch_bounds__(256) void k_vtrans(const float* __restrict__ qkv, unsigned short* __restrict__ Vthi,
                                                unsigned short* __restrict__ Vtlo) {
  int t0 = blockIdx.x * 64, h = blockIdx.y;
  __shared__ float tile[64][65];
  int tid = threadIdx.x;
  int c = tid & 63, w = tid >> 6;
  for (int r = w; r < 64; r += 4)
    tile[r][c] = qkv[(size_t)(t0 + r) * 1536 + 1280 + h * 64 + c];
  __syncthreads();
  for (int d = w; d < 64; d += 4) {
    float v = tile[c][d];
    unsigned short hi = f2bf(v);
    size_t idx = ((size_t)h * 64 + d) * T_ + t0 + c;
    Vthi[idx] = hi;
    Vtlo[idx] = f2bf(v - bf2f(hi));
  }
}

// ---------------- flash attention, bf16x3; Ps aliases Ks (36.9KB LDS -> 4 blk/CU), direct staging ----------------
__global__ __launch_bounds__(256) void k_attn_mfma(const unsigned short* __restrict__ Qhi,
                                                   const unsigned short* __restrict__ Qlo,
                                                   const unsigned short* __restrict__ Khi,
                                                   const unsigned short* __restrict__ Klo,
                                                   const unsigned short* __restrict__ Vthi,
                                                   const unsigned short* __restrict__ Vtlo,
                                                   unsigned short* __restrict__ Ao) {
  int bid = blockIdx.x;
  int kk = bid >> 4;
  int head = bid & 15;
  // heavy-first: qidx 31..16 dispatch first, then 0..15
  int qidx = (kk < 16) ? (31 - kk) : (kk - 16);
  int qb = qidx * 64;
  int kvh = head >> 2;
  int tid = threadIdx.x, lane = tid & 63, w = tid >> 6;
  int l15 = lane & 15, lg = lane >> 4;

  // 4 x (64*72) shorts = 36.9 KB. Ps aliases Ks (Ks dead after QK^T; barrier-protected).
  __shared__ unsigned short S[4 * 64 * 72];
  unsigned short* KsH = S;
  unsigned short* KsL = S + 4608;
  unsigned short* VsH = S + 9216;
  unsigned short* VsL = S + 13824;
  unsigned short* PsH = KsH;
  unsigned short* PsL = KsL;

  bf16x8 qh[2], ql[2];
  {
    size_t qbase = ((size_t)head * T_ + qb + w * 16 + l15) * 64 + lg * 8;
    qh[0] = *(const bf16x8*)(Qhi + qbase);
    qh[1] = *(const bf16x8*)(Qhi + qbase + 32);
    ql[0] = *(const bf16x8*)(Qlo + qbase);
    ql[1] = *(const bf16x8*)(Qlo + qbase + 32);
  }
  f32x4 z = {0.f, 0.f, 0.f, 0.f};
  f32x4 Oa[4];
  float mrow[4], lrow[4];
#pragma unroll
  for (int r = 0; r < 4; r++) { mrow[r] = -1e30f; lrow[r] = 0.f; }
#pragma unroll
  for (int dg = 0; dg < 4; dg++) Oa[dg] = z;

  for (int jb = 0; jb <= qb; jb += 64) {
    // direct staging (short register liveness; previous tile's LDS reads protected by tile-end barrier)
    for (int c = tid; c < 512; c += 256) {
      int r = c >> 3, g = (c & 7) * 8;
      size_t kgl = ((size_t)kvh * T_ + jb + r) * 64 + g;
      size_t vgl = ((size_t)kvh * 64 + r) * T_ + jb + g;
      *(uint4*)&KsH[r * 72 + g] = *(const uint4*)(Khi + kgl);
      *(uint4*)&KsL[r * 72 + g] = *(const uint4*)(Klo + kgl);
      *(uint4*)&VsH[r * 72 + g] = *(const uint4*)(Vthi + vgl);
      *(uint4*)&VsL[r * 72 + g] = *(const uint4*)(Vtlo + vgl);
    }
    __syncthreads();

    f32x4 sc[4];
    sc[0] = z; sc[1] = z; sc[2] = z; sc[3] = z;
#pragma unroll
    for (int kg = 0; kg < 4; kg++) {
      int ba = (kg * 16 + l15) * 72 + lg * 8;
      bf16x8 bh0 = *(const bf16x8*)&KsH[ba];
      bf16x8 bh1 = *(const bf16x8*)&KsH[ba + 32];
      bf16x8 bl0 = *(const bf16x8*)&KsL[ba];
      bf16x8 bl1 = *(const bf16x8*)&KsL[ba + 32];
      sc[kg] = __builtin_amdgcn_mfma_f32_16x16x32_bf16(qh[0], bh0, sc[kg], 0, 0, 0);
      sc[kg] = __builtin_amdgcn_mfma_f32_16x16x32_bf16(qh[1], bh1, sc[kg], 0, 0, 0);
      sc[kg] = __builtin_amdgcn_mfma_f32_16x16x32_bf16(qh[0], bl0, sc[kg], 0, 0, 0);
      sc[kg] = __builtin_amdgcn_mfma_f32_16x16x32_bf16(qh[1], bl1, sc[kg], 0, 0, 0);
      sc[kg] = __builtin_amdgcn_mfma_f32_16x16x32_bf16(ql[0], bh0, sc[kg], 0, 0, 0);
      sc[kg] = __builtin_amdgcn_mfma_f32_16x16x32_bf16(ql[1], bh1, sc[kg], 0, 0, 0);
    }
    if (jb == qb) {
      int rb = w * 16 + lg * 4;
#pragma unroll
      for (int kg = 0; kg < 4; kg++) {
        int col = kg * 16 + l15;
#pragma unroll
        for (int r = 0; r < 4; r++)
          if (col > rb + r) sc[kg][r] = -1e30f;
      }
    }
#pragma unroll
    for (int r = 0; r < 4; r++) {
      float mt = fmaxf(fmaxf(sc[0][r], sc[1][r]), fmaxf(sc[2][r], sc[3][r]));
      mt = fmaxf(mt, __shfl_xor(mt, 1, 64));
      mt = fmaxf(mt, __shfl_xor(mt, 2, 64));
      mt = fmaxf(mt, __shfl_xor(mt, 4, 64));
      mt = fmaxf(mt, __shfl_xor(mt, 8, 64));
      float mnew = fmaxf(mrow[r], mt);
      float corr = __expf(mrow[r] - mnew);
      mrow[r] = mnew;
      float s = 0.f;
#pragma unroll
      for (int kg = 0; kg < 4; kg++) {
        float p = __expf(sc[kg][r] - mnew);
        sc[kg][r] = p;
        s += p;
      }
      s += __shfl_xor(s, 1, 64);
      s += __shfl_xor(s, 2, 64);
      s += __shfl_xor(s, 4, 64);
      s += __shfl_xor(s, 8, 64);
      lrow[r] = lrow[r] * corr + s;
      // per-ROW rescale (Oa[dg] components are 4 different rows)
#pragma unroll
      for (int dg = 0; dg < 4; dg++) Oa[dg][r] *= corr;
    }
    __syncthreads();  // all waves' QK reads of Ks done before Ps (alias) overwrite
    {
      int rb = w * 16 + lg * 4;
#pragma unroll
      for (int kg = 0; kg < 4; kg++) {
        int col = kg * 16 + l15;
#pragma unroll
        for (int r = 0; r < 4; r++) {
          float p = sc[kg][r];
          unsigned short ph = f2bf(p);
          PsH[(rb + r) * 72 + col] = ph;
          PsL[(rb + r) * 72 + col] = f2bf(p - bf2f(ph));
        }
      }
    }
    {
      // PV: A-frag rows w*16..w*16+15 == rows this wave just wrote (same-wave, no barrier)
      int ab = (w * 16 + l15) * 72 + lg * 8;
      bf16x8 ph0 = *(const bf16x8*)&PsH[ab];
      bf16x8 ph1 = *(const bf16x8*)&PsH[ab + 32];
      bf16x8 pl0 = *(const bf16x8*)&PsL[ab];
      bf16x8 pl1 = *(const bf16x8*)&PsL[ab + 32];
#pragma unroll
      for (int dg = 0; dg < 4; dg++) {
        int vb = (dg * 16 + l15) * 72 + lg * 8;
        bf16x8 vh0 = *(const bf16x8*)&VsH[vb];
        bf16x8 vh1 = *(const bf16x8*)&VsH[vb + 32];
        bf16x8 vl0 = *(const bf16x8*)&VsL[vb];
        bf16x8 vl1 = *(const bf16x8*)&VsL[vb + 32];
        Oa[dg] = __builtin_amdgcn_mfma_f32_16x16x32_bf16(ph0, vh0, Oa[dg], 0, 0, 0);
        Oa[dg] = __builtin_amdgcn_mfma_f32_16x16x32_bf16(ph1, vh1, Oa[dg], 0, 0, 0);
        Oa[dg] = __builtin_amdgcn_mfma_f32_16x16x32_bf16(ph0, vl0, Oa[dg], 0, 0, 0);
        Oa[dg] = __builtin_amdgcn_mfma_f32_16x16x32_bf16(ph1, vl1, Oa[dg], 0, 0, 0);
        Oa[dg] = __builtin_amdgcn_mfma_f32_16x16x32_bf16(pl0, vh0, Oa[dg], 0, 0, 0);
        Oa[dg] = __builtin_amdgcn_mfma_f32_16x16x32_bf16(pl1, vh1, Oa[dg], 0, 0, 0);
      }
    }
    __syncthreads();  // Ps/Vs reads done before next tile's staging writes
  }
#pragma unroll
  for (int r = 0; r < 4; r++) {
    float inv = 1.0f / lrow[r];
    size_t rb2 = (size_t)(qb + w * 16 + lg * 4 + r) * 3072 + head * 64;
#pragma unroll
    for (int dg = 0; dg < 4; dg++) {
      float v = Oa[dg][r] * inv;
      unsigned short hi2 = f2bf(v);
      unsigned short lo2 = f2bf(v - bf2f(hi2));
      Ao[rb2 + dg * 16 + l15] = hi2;
      Ao[rb2 + 1024 + dg * 16 + l15] = hi2;
      Ao[rb2 + 2048 + dg * 16 + l15] = lo2;
    }
  }
}

// ---------------- fused rmsnorm(post) + router: one wave per token ----------------
__global__ __launch_bounds__(256) void k_rmsrouter(const float* __restrict__ resid, const float* __restrict__ w,
                                                   const float* __restrict__ gw, unsigned short* __restrict__ h2b,
                                                   int* __restrict__ topi, float* __restrict__ topw,
                                                   int* __restrict__ counts) {
  int wid = threadIdx.x >> 6, lane = threadIdx.x & 63;
  int t = blockIdx.x * 4 + wid;
  const float* hr = resid + (size_t)t * H_;
  float hv[16];
#pragma unroll
  for (int i = 0; i < 16; i++) hv[i] = hr[lane + 64 * i];
  float ss = 0.f;
#pragma unroll
  for (int i = 0; i < 16; i++) ss += hv[i] * hv[i];
#pragma unroll
  for (int off = 32; off; off >>= 1) ss += __shfl_xor(ss, off, 64);
  float inv = rsqrtf(ss * (1.0f / H_) + 1e-5f);
#pragma unroll
  for (int i = 0; i < 16; i++) {
    hv[i] = hv[i] * inv * w[lane + 64 * i];
    h2b[(size_t)t * H_ + lane + 64 * i] = f2bf(hv[i]);
  }
  float le[8];
#pragma unroll
  for (int e = 0; e < 8; e++) {
    const float* g = gw + (size_t)e * H_;
    float acc = 0.f;
#pragma unroll
    for (int i = 0; i < 16; i++) acc += hv[i] * g[lane + 64 * i];
#pragma unroll
    for (int off = 32; off; off >>= 1) acc += __shfl_xor(acc, off, 64);
    le[e] = acc;
  }
  if (lane == 0) {
    int i0 = 0;
#pragma unroll
    for (int e = 1; e < 8; e++)
      if (le[e] > le[i0]) i0 = e;
    int i1 = (i0 == 0) ? 1 : 0;
#pragma unroll
    for (int e = 0; e < 8; e++) {
      if (e == i0) continue;
      if (le[e] > le[i1]) i1 = e;
    }
    float w1r = expf(le[i1] - le[i0]);
    float denom = 1.0f + w1r;
    topi[t * 2 + 0] = i0;
    topi[t * 2 + 1] = i1;
    topw[t * 2 + 0] = 1.0f / denom;
    topw[t * 2 + 1] = w1r / denom;
    atomicAdd(&counts[i0], 1);
    atomicAdd(&counts[i1], 1);
  }
}

__global__ void k_scan(const int* __restrict__ counts, int* __restrict__ offsets) {
  if (threadIdx.x == 0 && blockIdx.x == 0) {
    int off = 0;
    for (int e = 0; e < NE_; e++) { offsets[e] = off; off += counts[e]; }
  }
}

__global__ __launch_bounds__(256) void k_build(const int* __restrict__ topi, const float* __restrict__ topw,
                                               const int* __restrict__ offsets, int* __restrict__ counts2,
                                               int* __restrict__ pairs_ts, float* __restrict__ pairs_w) {
  int t = blockIdx.x * 256 + threadIdx.x;
#pragma unroll
  for (int s = 0; s < 2; s++) {
    int e = topi[t * 2 + s];
    int slot = atomicAdd(&counts2[e], 1);
    int p = offsets[e] + slot;
    pairs_ts[p] = t * 2 + s;
    pairs_w[p] = topw[t * 2 + s];
  }
}

// ---------------- fp32 -> bf16 bulk convert, all three MoE weights in one launch ----------------
__global__ __launch_bounds__(256) void k_conv3(const float* __restrict__ w1, const float* __restrict__ w3,
                                               const float* __restrict__ w2, unsigned short* __restrict__ W1b,
                                               unsigned short* __restrict__ W3b, unsigned short* __restrict__ W2b,
                                               int n8each) {
  int stride = gridDim.x * 256;
  int total = 3 * n8each;
  for (int i = blockIdx.x * 256 + threadIdx.x; i < total; i += stride) {
    int sel = i / n8each;
    int j = i - sel * n8each;
    const float* in = (sel == 0) ? w1 : (sel == 1) ? w3 : w2;
    unsigned short* out = (sel == 0) ? W1b : (sel == 1) ? W3b : W2b;
    const float4* p = (const float4*)in + (size_t)j * 2;
    float4 a = p[0], b = p[1];
    u16x8 t;
    t[0] = f2bf(a.x); t[1] = f2bf(a.y); t[2] = f2bf(a.z); t[3] = f2bf(a.w);
    t[4] = f2bf(b.x); t[5] = f2bf(b.y); t[6] = f2bf(b.z); t[7] = f2bf(b.w);
    *((u16x8*)out + j) = t;
  }
}

// ---------------- MoE up: 128x64 tile, BK=32, gload_lds dbuf, silu epilogue ----------------
__global__ __launch_bounds__(256) void k_moe_up(const unsigned short* __restrict__ h2b, const unsigned short* __restrict__ W1b,
                                                const unsigned short* __restrict__ W3b, const int* __restrict__ pairs_ts,
                                                const int* __restrict__ offsets, const int* __restrict__ counts,
                                                unsigned short* __restrict__ G) {
  int e = blockIdx.z;
  int ne = counts[e];
  int row0 = blockIdx.y * 128;
  if (row0 >= ne) return;
  int col0 = blockIdx.x * 64;
  int pbase = offsets[e];
  __shared__ unsigned short As[2][128 * 32];
  __shared__ unsigned short B1s[2][64 * 32];
  __shared__ unsigned short B2s[2][64 * 32];
  int tid = threadIdx.x, lane = tid & 63, w = tid >> 6;
  int wr = w >> 1, wc = w & 1;
  int l15 = lane & 15, lg = lane >> 4;
  int srow = lane >> 2, schunk = lane & 3;

  int gr0 = row0 + w * 32 + srow, gr1 = gr0 + 16;
  int tok0 = (gr0 < ne) ? (pairs_ts[pbase + gr0] >> 1) : 0;
  int tok1 = (gr1 < ne) ? (pairs_ts[pbase + gr1] >> 1) : 0;
  const unsigned short* ga0 = h2b + (size_t)tok0 * H_ + schunk * 8;
  const unsigned short* ga1 = h2b + (size_t)tok1 * H_ + schunk * 8;
  const unsigned short* gb1 = W1b + ((size_t)e * II_ + col0 + w * 16 + srow) * H_ + schunk * 8;
  const unsigned short* gb3 = W3b + ((size_t)e * II_ + col0 + w * 16 + srow) * H_ + schunk * 8;

  f32x4 acc1[4][2], acc2[4][2];
  f32x4 z = {0.f, 0.f, 0.f, 0.f};
#pragma unroll
  for (int a = 0; a < 4; a++)
#pragma unroll
    for (int b = 0; b < 2; b++) { acc1[a][b] = z; acc2[a][b] = z; }

  GLOAD16(ga0, &As[0][(w * 32) * 32]);
  GLOAD16(ga1, &As[0][(w * 32 + 16) * 32]);
  GLOAD16(gb1, &B1s[0][(w * 16) * 32]);
  GLOAD16(gb3, &B2s[0][(w * 16) * 32]);
  __syncthreads();

  for (int t = 0; t < H_ / 32; ++t) {
    int cur = t & 1;
    if (t + 1 < H_ / 32) {
      int ko = (t + 1) * 32;
      GLOAD16(ga0 + ko, &As[cur ^ 1][(w * 32) * 32]);
      GLOAD16(ga1 + ko, &As[cur ^ 1][(w * 32 + 16) * 32]);
      GLOAD16(gb1 + ko, &B1s[cur ^ 1][(w * 16) * 32]);
      GLOAD16(gb3 + ko, &B2s[cur ^ 1][(w * 16) * 32]);
    }
    bf16x8 af[4], b1f[2], b2f[2];
#pragma unroll
    for (int fa = 0; fa < 4; fa++)
      af[fa] = *(const bf16x8*)&As[cur][(wr * 64 + fa * 16 + l15) * 32 + lg * 8];
#pragma unroll
    for (int fb = 0; fb < 2; fb++) {
      b1f[fb] = *(const bf16x8*)&B1s[cur][(wc * 32 + fb * 16 + l15) * 32 + lg * 8];
      b2f[fb] = *(const bf16x8*)&B2s[cur][(wc * 32 + fb * 16 + l15) * 32 + lg * 8];
    }
#pragma unroll
    for (int fa = 0; fa < 4; fa++)
#pragma unroll
      for (int fb = 0; fb < 2; fb++) {
        acc1[fa][fb] = __builtin_amdgcn_mfma_f32_16x16x32_bf16(af[fa], b1f[fb], acc1[fa][fb], 0, 0, 0);
        acc2[fa][fb] = __builtin_amdgcn_mfma_f32_16x16x32_bf16(af[fa], b2f[fb], acc2[fa][fb], 0, 0, 0);
      }
    __syncthreads();
  }
#pragma unroll
  for (int fa = 0; fa < 4; fa++)
#pragma unroll
    for (int r = 0; r < 4; r++) {
      int prow = row0 + wr * 64 + fa * 16 + lg * 4 + r;
      if (prow < ne) {
#pragma unroll
        for (int fb = 0; fb < 2; fb++) {
          int icol = col0 + wc * 32 + fb * 16 + l15;
          float h1 = acc1[fa][fb][r], h3 = acc2[fa][fb][r];
          float g = h1 / (1.0f + __expf(-h1)) * h3;
          G[(size_t)(pbase + prow) * II_ + icol] = f2bf(g);
        }
      }
    }
}

// ---------------- MoE down: 128x64 tile, BK=32, gload_lds dbuf, weighted store ----------------
__global__ __launch_bounds__(256) void k_moe_down(const unsigned short* __restrict__ G, const unsigned short* __restrict__ W2b,
                                                  const int* __restrict__ pairs_ts, const float* __restrict__ pairs_w,
                                                  const int* __restrict__ offsets, const int* __restrict__ counts,
                                                  float* __restrict__ Pbuf) {
  int e = blockIdx.z;
  int ne = counts[e];
  int row0 = blockIdx.y * 128;
  if (row0 >= ne) return;
  int col0 = blockIdx.x * 64;
  int pbase = offsets[e];
  __shared__ unsigned short As[2][128 * 32];
  __shared__ unsigned short Bs[2][64 * 32];
  int tid = threadIdx.x, lane = tid & 63, w = tid >> 6;
  int wr = w >> 1, wc = w & 1;
  int l15 = lane & 15, lg = lane >> 4;
  int srow = lane >> 2, schunk = lane & 3;

  int gr0 = row0 + w * 32 + srow, gr1 = gr0 + 16;
  int p0 = pbase + ((gr0 < ne) ? gr0 : 0);
  int p1 = pbase + ((gr1 < ne) ? gr1 : 0);
  const unsigned short* ga0 = G + (size_t)p0 * II_ + schunk * 8;
  const unsigned short* ga1 = G + (size_t)p1 * II_ + schunk * 8;
  const unsigned short* gb = W2b + ((size_t)e * H_ + col0 + w * 16 + srow) * II_ + schunk * 8;

  f32x4 acc[4][2];
  f32x4 z = {0.f, 0.f, 0.f, 0.f};
#pragma unroll
  for (int a = 0; a < 4; a++)
#pragma unroll
    for (int b = 0; b < 2; b++) acc[a][b] = z;

  GLOAD16(ga0, &As[0][(w * 32) * 32]);
  GLOAD16(ga1, &As[0][(w * 32 + 16) * 32]);
  GLOAD16(gb, &Bs[0][(w * 16) * 32]);
  __syncthreads();

  for (int t = 0; t < II_ / 32; ++t) {
    int cur = t & 1;
    if (t + 1 < II_ / 32) {
      int ko = (t + 1) * 32;
      GLOAD16(ga0 + ko, &As[cur ^ 1][(w * 32) * 32]);
      GLOAD16(ga1 + ko, &As[cur ^ 1][(w * 32 + 16) * 32]);
      GLOAD16(gb + ko, &Bs[cur ^ 1][(w * 16) * 32]);
    }
    bf16x8 af[4], bw2[2];
#pragma unroll
    for (int fa = 0; fa < 4; fa++)
      af[fa] = *(const bf16x8*)&As[cur][(wr * 64 + fa * 16 + l15) * 32 + lg * 8];
#pragma unroll
    for (int fb = 0; fb < 2; fb++)
      bw2[fb] = *(const bf16x8*)&Bs[cur][(wc * 32 + fb * 16 + l15) * 32 + lg * 8];
#pragma unroll
    for (int fa = 0; fa < 4; fa++)
#pragma unroll
      for (int fb = 0; fb < 2; fb++)
        acc[fa][fb] = __builtin_amdgcn_mfma_f32_16x16x32_bf16(af[fa], bw2[fb], acc[fa][fb], 0, 0, 0);
    __syncthreads();
  }
#pragma unroll
  for (int fa = 0; fa < 4; fa++)
#pragma unroll
    for (int r = 0; r < 4; r++) {
      int prow = row0 + wr * 64 + fa * 16 + lg * 4 + r;
      if (prow < ne) {
        int p = pbase + prow;
        int ts = pairs_ts[p];
        float wgt = pairs_w[p];
#pragma unroll
        for (int fb = 0; fb < 2; fb++) {
          int col = col0 + wc * 32 + fb * 16 + l15;
          Pbuf[(size_t)ts * H_ + col] = wgt * acc[fa][fb][r];
        }
      }
    }
}

// ---------------- final: out = rmsnorm(resid + P0 + P1) ----------------
__global__ __launch_bounds__(256) void k_final(const float* __restrict__ resid, const float* __restrict__ Pbuf,
                                               const float* __restrict__ w, float* __restrict__ out) {
  int row = blockIdx.x;
  int tid = threadIdx.x;
  float4 a = ((const float4*)(resid + (size_t)row * H_))[tid];
  float4 p0 = ((const float4*)(Pbuf + (size_t)(2 * row) * H_))[tid];
  float4 p1 = ((const float4*)(Pbuf + (size_t)(2 * row + 1) * H_))[tid];
  float4 v;
  v.x = a.x + p0.x + p1.x; v.y = a.y + p0.y + p1.y; v.z = a.z + p0.z + p1.z; v.w = a.w + p0.w + p1.w;
  float ss = v.x * v.x + v.y * v.y + v.z * v.z + v.w * v.w;
#pragma unroll
  for (int off = 32; off; off >>= 1) ss += __shfl_xor(ss, off, 64);
  __shared__ float red[4];
  int lane = tid & 63, wid = tid >> 6;
  if (lane == 0) red[wid] = ss;
  __syncthreads();
  float tot = red[0] + red[1] + red[2] + red[3];
  float inv = rsqrtf(tot * (1.0f / H_) + 1e-5f);
  float4 wv = ((const float4*)w)[tid];
  float4 o;
  o.x = v.x * inv * wv.x; o.y = v.y * inv * wv.y; o.z = v.z * inv * wv.z; o.w = v.w * inv * wv.w;
  ((float4*)(out + (size_t)row * H_))[tid] = o;
}

extern "C" void kernel_launch(void* const* d_in, const int* in_sizes, int n_in,
                              void* d_out, int out_size, void* d_ws, size_t ws_size,
                              hipStream_t stream) {
  const float* x = (const float*)d_in[0];
  const int* pos = (const int*)d_in[1];
  const float* qkv_w = (const float*)d_in[2];
  const float* o_w = (const float*)d_in[3];
  const float* nin_w = (const float*)d_in[4];
  const float* npost_w = (const float*)d_in[5];
  const float* nnext_w = (const float*)d_in[6];
  const float* gate_w = (const float*)d_in[7];
  const float* w1 = (const float*)d_in[8];
  const float* w3 = (const float*)d_in[9];
  const float* w2 = (const float*)d_in[10];
  float* out = (float*)d_out;

  // ---- persistent region (layout unchanged from the verified r15/r17/r19 config; h2/ct/st slots retained) ----
  float* resid = (float*)d_ws;                       // T*H
  float* h2 = resid + (size_t)T_ * H_;               // T*H (unused after fusion; slot retained)
  float* Pbuf = h2 + (size_t)T_ * H_;                // 2*T*H
  float* topw = Pbuf + (size_t)2 * T_ * H_;          // 2T
  float* pairsw = topw + T_ * 2;                     // 4096
  unsigned short* h2b = (unsigned short*)(pairsw + 4096);  // T*H
  unsigned short* G = h2b + (size_t)T_ * H_;         // 2*T*II
  int* topi = (int*)(G + (size_t)2 * T_ * II_);      // 2T
  int* ctrl = topi + T_ * 2;
  int* counts = ctrl;
  int* counts2 = ctrl + 8;
  int* offsets = ctrl + 16;
  int* pairs_ts = ctrl + 24;                         // 4096
  char* trans = (char*)(pairs_ts + 4096);
  trans = (char*)(((uintptr_t)trans + 255) & ~(uintptr_t)255);

  // ---- transient: attention phase ----
  unsigned short* Aq = (unsigned short*)trans;       // T*3072
  unsigned short* Bq = Aq + (size_t)T_ * 3072;       // 1536*3072
  unsigned short* Bo = Bq + (size_t)1536 * 3072;     // 1024*3072
  unsigned short* Ao = Bo + (size_t)1024 * 3072;     // T*3072
  float* qkvb = (float*)(Ao + (size_t)T_ * 3072);    // T*1536
  float* ct = qkvb + (size_t)T_ * 1536;              // T*32 (unused; slot retained)
  float* st = ct + (size_t)T_ * 32;                  // T*32 (unused; slot retained)
  unsigned short* uu = (unsigned short*)(st + (size_t)T_ * 32);
  unsigned short* Qhi = uu;  uu += (size_t)HQ_ * T_ * D_;
  unsigned short* Qlo = uu;  uu += (size_t)HQ_ * T_ * D_;
  unsigned short* Khi = uu;  uu += (size_t)HK_ * T_ * D_;
  unsigned short* Klo = uu;  uu += (size_t)HK_ * T_ * D_;
  unsigned short* Vthi = uu; uu += (size_t)HK_ * D_ * T_;
  unsigned short* Vtlo = uu; uu += (size_t)HK_ * D_ * T_;

  // ---- transient: MoE phase (aliases attention transients; conv runs after router) ----
  unsigned short* W1b = (unsigned short*)trans;      // E*I*H
  unsigned short* W3b = W1b + (size_t)NE_ * II_ * H_;
  unsigned short* W2b = W3b + (size_t)NE_ * II_ * H_;

  const int WCNT8 = (NE_ * II_ * H_) / 8;

  hipMemsetAsync(ctrl, 0, 64, stream);  // counts + counts2
  k_rmsnorm_split<<<T_, 256, 0, stream>>>(x, nin_w, Aq);
  k_wsplit<<<2048, 256, 0, stream>>>(qkv_w, Bq, H_, 1536 * H_ / 8);
  k_wsplit<<<2048, 256, 0, stream>>>(o_w, Bo, HQ_ * D_, H_ * HQ_ * D_ / 8);
  k_hgemm<0><<<dim3(1536 / 64, T_ / 128), 256, 0, stream>>>(Aq, Bq, qkvb, nullptr, 1536, 3 * H_);
  k_rope_prep<<<T_, 256, 0, stream>>>(qkvb, pos, Qhi, Qlo, Khi, Klo);
  k_vtrans<<<dim3(T_ / 64, HK_), 256, 0, stream>>>(qkvb, Vthi, Vtlo);
  k_attn_mfma<<<dim3(512), 256, 0, stream>>>(Qhi, Qlo, Khi, Klo, Vthi, Vtlo, Ao);
  k_hgemm<1><<<dim3(H_ / 64, T_ / 128), 256, 0, stream>>>(Ao, Bo, resid, x, H_, 3 * HQ_ * D_);
  k_rmsrouter<<<T_ / 4, 256, 0, stream>>>(resid, npost_w, gate_w, h2b, topi, topw, counts);
  k_scan<<<1, 64, 0, stream>>>(counts, offsets);
  k_build<<<T_ / 256, 256, 0, stream>>>(topi, topw, offsets, counts2, pairs_ts, pairsw);
  // weight pre-conversion (attention transients are dead now) — single fused launch
  k_conv3<<<4096, 256, 0, stream>>>(w1, w3, w2, W1b, W3b, W2b, WCNT8);
  k_moe_up<<<dim3(II_ / 64, T_ / 128, NE_), 256, 0, stream>>>(h2b, W1b, W3b, pairs_ts, offsets, counts, G);
  k_moe_down<<<dim3(H_ / 64, T_ / 128, NE_), 256, 0, stream>>>(G, W2b, pairs_ts, pairsw, offsets, counts, Pbuf);
  k_final<<<T_, 256, 0, stream>>>(resid, Pbuf, nnext_w, out);
}

// Round 21
// 461.853 us; speedup vs baseline: 1.0926x; 1.0427x over previous
//
#include <hip/hip_runtime.h>
#include <hip/hip_bf16.h>
#include <math.h>

#define T_ 2048
#define H_ 1024
#define HQ_ 16
#define HK_ 4
#define D_ 64
#define NE_ 8
#define II_ 2048

typedef __attribute__((ext_vector_type(8))) short bf16x8;
typedef __attribute__((ext_vector_type(8))) unsigned short u16x8;
typedef __attribute__((ext_vector_type(4))) float f32x4;

// async global->LDS DMA: 16B per lane, dest = wave-uniform base + lane*16
#define GLOAD16(g, l)                                                                   \
  __builtin_amdgcn_global_load_lds((const __attribute__((address_space(1))) unsigned int*)(g), \
                                   (__attribute__((address_space(3))) unsigned int*)(l), 16, 0, 0)

__device__ __forceinline__ unsigned short f2bf(float f) {
  unsigned int u = __float_as_uint(f);
  return (unsigned short)((u + 0x7fffu + ((u >> 16) & 1u)) >> 16);
}
__device__ __forceinline__ float bf2f(unsigned short h) {
  return __uint_as_float((unsigned int)h << 16);
}

// ---------------- rmsnorm writing expanded bf16x3 A' = [hi|hi|lo] along K'=3H ----------------
__global__ __launch_bounds__(256) void k_rmsnorm_split(const float* __restrict__ x, const float* __restrict__ w,
                                                       unsigned short* __restrict__ Aq) {
  int row = blockIdx.x;
  int tid = threadIdx.x;
  float4 v = ((const float4*)(x + (size_t)row * H_))[tid];
  float ss = v.x * v.x + v.y * v.y + v.z * v.z + v.w * v.w;
#pragma unroll
  for (int off = 32; off; off >>= 1) ss += __shfl_xor(ss, off, 64);
  __shared__ float red[4];
  int lane = tid & 63, wid = tid >> 6;
  if (lane == 0) red[wid] = ss;
  __syncthreads();
  float tot = red[0] + red[1] + red[2] + red[3];
  float inv = rsqrtf(tot * (1.0f / H_) + 1e-5f);
  float4 wv = ((const float4*)w)[tid];
  float4 o;
  o.x = v.x * inv * wv.x; o.y = v.y * inv * wv.y; o.z = v.z * inv * wv.z; o.w = v.w * inv * wv.w;
  ushort4 hi, lo;
  hi.x = f2bf(o.x); hi.y = f2bf(o.y); hi.z = f2bf(o.z); hi.w = f2bf(o.w);
  lo.x = f2bf(o.x - bf2f(hi.x)); lo.y = f2bf(o.y - bf2f(hi.y));
  lo.z = f2bf(o.z - bf2f(hi.z)); lo.w = f2bf(o.w - bf2f(hi.w));
  size_t base = (size_t)row * (3 * H_) + tid * 4;
  *(ushort4*)(Aq + base) = hi;
  *(ushort4*)(Aq + base + H_) = hi;
  *(ushort4*)(Aq + base + 2 * H_) = lo;
}

// ---------------- weight split: W[N][K] fp32 -> W'[N][3K] bf16 = [hi|lo|hi] ----------------
__global__ __launch_bounds__(256) void k_wsplit(const float* __restrict__ in, unsigned short* __restrict__ out,
                                                int K, int n8total) {
  int stride = gridDim.x * 256;
  int kc8 = K >> 3;
  for (int i = blockIdx.x * 256 + threadIdx.x; i < n8total; i += stride) {
    int n = i / kc8, kc = (i - n * kc8) * 8;
    const float4* p = (const float4*)(in + (size_t)n * K + kc);
    float4 a = p[0], b = p[1];
    u16x8 hi, lo;
    hi[0] = f2bf(a.x); hi[1] = f2bf(a.y); hi[2] = f2bf(a.z); hi[3] = f2bf(a.w);
    hi[4] = f2bf(b.x); hi[5] = f2bf(b.y); hi[6] = f2bf(b.z); hi[7] = f2bf(b.w);
    lo[0] = f2bf(a.x - bf2f(hi[0])); lo[1] = f2bf(a.y - bf2f(hi[1]));
    lo[2] = f2bf(a.z - bf2f(hi[2])); lo[3] = f2bf(a.w - bf2f(hi[3]));
    lo[4] = f2bf(b.x - bf2f(hi[4])); lo[5] = f2bf(b.y - bf2f(hi[5]));
    lo[6] = f2bf(b.z - bf2f(hi[6])); lo[7] = f2bf(b.w - bf2f(hi[7]));
    size_t ob = (size_t)n * 3 * K + kc;
    *(u16x8*)(out + ob) = hi;
    *(u16x8*)(out + ob + K) = lo;
    *(u16x8*)(out + ob + 2 * K) = hi;
  }
}

// ---------------- bf16 GEMM (expanded-K bf16x3), m97-style gload_lds + dbuf ----------------
template <int ADD>
__global__ __launch_bounds__(256) void k_hgemm(const unsigned short* __restrict__ A, const unsigned short* __restrict__ B,
                                               float* __restrict__ C, const float* __restrict__ addsrc,
                                               int N, int K3) {
  int m0 = blockIdx.y * 128, n0 = blockIdx.x * 64;
  __shared__ unsigned short As[2][128 * 32];
  __shared__ unsigned short Bs[2][64 * 32];
  int tid = threadIdx.x, lane = tid & 63, w = tid >> 6;
  int wr = w >> 1, wc = w & 1;
  int l15 = lane & 15, lg = lane >> 4;
  int srow = lane >> 2, schunk = lane & 3;

  const unsigned short* ga0 = A + (size_t)(m0 + w * 32 + srow) * K3 + schunk * 8;
  const unsigned short* ga1 = A + (size_t)(m0 + w * 32 + 16 + srow) * K3 + schunk * 8;
  const unsigned short* gb = B + (size_t)(n0 + w * 16 + srow) * K3 + schunk * 8;

  f32x4 acc[4][2];
  f32x4 z = {0.f, 0.f, 0.f, 0.f};
#pragma unroll
  for (int a = 0; a < 4; a++)
#pragma unroll
    for (int b = 0; b < 2; b++) acc[a][b] = z;

  GLOAD16(ga0, &As[0][(w * 32) * 32]);
  GLOAD16(ga1, &As[0][(w * 32 + 16) * 32]);
  GLOAD16(gb, &Bs[0][(w * 16) * 32]);
  __syncthreads();

  int nt = K3 / 32;
  for (int t = 0; t < nt; ++t) {
    int cur = t & 1;
    if (t + 1 < nt) {
      int ko = (t + 1) * 32;
      GLOAD16(ga0 + ko, &As[cur ^ 1][(w * 32) * 32]);
      GLOAD16(ga1 + ko, &As[cur ^ 1][(w * 32 + 16) * 32]);
      GLOAD16(gb + ko, &Bs[cur ^ 1][(w * 16) * 32]);
    }
    bf16x8 af[4], bw2[2];
#pragma unroll
    for (int fa = 0; fa < 4; fa++)
      af[fa] = *(const bf16x8*)&As[cur][(wr * 64 + fa * 16 + l15) * 32 + lg * 8];
#pragma unroll
    for (int fb = 0; fb < 2; fb++)
      bw2[fb] = *(const bf16x8*)&Bs[cur][(wc * 32 + fb * 16 + l15) * 32 + lg * 8];
#pragma unroll
    for (int fa = 0; fa < 4; fa++)
#pragma unroll
      for (int fb = 0; fb < 2; fb++)
        acc[fa][fb] = __builtin_amdgcn_mfma_f32_16x16x32_bf16(af[fa], bw2[fb], acc[fa][fb], 0, 0, 0);
    __syncthreads();
  }
#pragma unroll
  for (int fa = 0; fa < 4; fa++)
#pragma unroll
    for (int r = 0; r < 4; r++) {
      int row = m0 + wr * 64 + fa * 16 + lg * 4 + r;
#pragma unroll
      for (int fb = 0; fb < 2; fb++) {
        int col = n0 + wc * 32 + fb * 16 + l15;
        float v = acc[fa][fb][r];
        if (ADD) v += addsrc[(size_t)row * N + col];
        C[(size_t)row * N + col] = v;
      }
    }
}

// ---------------- RoPE apply + bf16 hi/lo split (cos/sin table computed in-block) ----------------
__global__ __launch_bounds__(256) void k_rope_prep(const float* __restrict__ qkv, const int* __restrict__ pos,
                                                   unsigned short* __restrict__ Qhi, unsigned short* __restrict__ Qlo,
                                                   unsigned short* __restrict__ Khi, unsigned short* __restrict__ Klo) {
  int t = blockIdx.x, tid = threadIdx.x;
  __shared__ float cs[32], sn[32];
  if (tid < 32) {
    float p = (float)pow(10000.0, (double)tid / 32.0);
    float freq = 1.0f / p;
    float ang = (float)pos[t] * freq;
    cs[tid] = cosf(ang);
    sn[tid] = sinf(ang);
  }
  __syncthreads();
  const float* row = qkv + (size_t)t * 1536;
#pragma unroll 2
  for (int it = tid; it < 512; it += 256) {
    int h = it >> 5, i = it & 31;
    float c = cs[i], s = sn[i];
    float x1 = row[h * 64 + i], x2 = row[h * 64 + i + 32];
    float a = (x1 * c - x2 * s) * 0.125f;
    float b = (x2 * c + x1 * s) * 0.125f;
    size_t base = ((size_t)h * T_ + t) * 64 + i;
    unsigned short ah = f2bf(a), bh = f2bf(b);
    Qhi[base] = ah; Qhi[base + 32] = bh;
    Qlo[base] = f2bf(a - bf2f(ah));
    Qlo[base + 32] = f2bf(b - bf2f(bh));
  }
  if (tid < 128) {
    int h = tid >> 5, i = tid & 31;
    float c = cs[i], s = sn[i];
    float x1 = row[1024 + h * 64 + i], x2 = row[1024 + h * 64 + i + 32];
    float a = x1 * c - x2 * s;
    float b = x2 * c + x1 * s;
    size_t base = ((size_t)h * T_ + t) * 64 + i;
    unsigned short ah = f2bf(a), bh = f2bf(b);
    Khi[base] = ah; Khi[base + 32] = bh;
    Klo[base] = f2bf(a - bf2f(ah));
    Klo[base + 32] = f2bf(b - bf2f(bh));
  }
}

// ---------------- V transpose + split: Vthi/Vtlo [kvh][d][t] ----------------
__global__ __launch_bounds__(256) void k_vtrans(const float* __restrict__ qkv, unsigned short* __restrict__ Vthi,
                                                unsigned short* __restrict__ Vtlo) {
  int t0 = blockIdx.x * 64, h = blockIdx.y;
  __shared__ float tile[64][65];
  int tid = threadIdx.x;
  int c = tid & 63, w = tid >> 6;
  for (int r = w; r < 64; r += 4)
    tile[r][c] = qkv[(size_t)(t0 + r) * 1536 + 1280 + h * 64 + c];
  __syncthreads();
  for (int d = w; d < 64; d += 4) {
    float v = tile[c][d];
    unsigned short hi = f2bf(v);
    size_t idx = ((size_t)h * 64 + d) * T_ + t0 + c;
    Vthi[idx] = hi;
    Vtlo[idx] = f2bf(v - bf2f(hi));
  }
}

// ---------------- flash attention, bf16x3; Ps aliases Ks (36.9KB LDS -> 4 blk/CU), direct staging ----------------
__global__ __launch_bounds__(256) void k_attn_mfma(const unsigned short* __restrict__ Qhi,
                                                   const unsigned short* __restrict__ Qlo,
                                                   const unsigned short* __restrict__ Khi,
                                                   const unsigned short* __restrict__ Klo,
                                                   const unsigned short* __restrict__ Vthi,
                                                   const unsigned short* __restrict__ Vtlo,
                                                   unsigned short* __restrict__ Ao) {
  int bid = blockIdx.x;
  int kk = bid >> 4;
  int head = bid & 15;
  // heavy-first: qidx 31..16 dispatch first, then 0..15
  int qidx = (kk < 16) ? (31 - kk) : (kk - 16);
  int qb = qidx * 64;
  int kvh = head >> 2;
  int tid = threadIdx.x, lane = tid & 63, w = tid >> 6;
  int l15 = lane & 15, lg = lane >> 4;

  // 4 x (64*72) shorts = 36.9 KB. Ps aliases Ks (Ks dead after QK^T; barrier-protected).
  __shared__ unsigned short S[4 * 64 * 72];
  unsigned short* KsH = S;
  unsigned short* KsL = S + 4608;
  unsigned short* VsH = S + 9216;
  unsigned short* VsL = S + 13824;
  unsigned short* PsH = KsH;
  unsigned short* PsL = KsL;

  bf16x8 qh[2], ql[2];
  {
    size_t qbase = ((size_t)head * T_ + qb + w * 16 + l15) * 64 + lg * 8;
    qh[0] = *(const bf16x8*)(Qhi + qbase);
    qh[1] = *(const bf16x8*)(Qhi + qbase + 32);
    ql[0] = *(const bf16x8*)(Qlo + qbase);
    ql[1] = *(const bf16x8*)(Qlo + qbase + 32);
  }
  f32x4 z = {0.f, 0.f, 0.f, 0.f};
  f32x4 Oa[4];
  float mrow[4], lrow[4];
#pragma unroll
  for (int r = 0; r < 4; r++) { mrow[r] = -1e30f; lrow[r] = 0.f; }
#pragma unroll
  for (int dg = 0; dg < 4; dg++) Oa[dg] = z;

  for (int jb = 0; jb <= qb; jb += 64) {
    // direct staging (short register liveness; previous tile's LDS reads protected by tile-end barrier)
    for (int c = tid; c < 512; c += 256) {
      int r = c >> 3, g = (c & 7) * 8;
      size_t kgl = ((size_t)kvh * T_ + jb + r) * 64 + g;
      size_t vgl = ((size_t)kvh * 64 + r) * T_ + jb + g;
      *(uint4*)&KsH[r * 72 + g] = *(const uint4*)(Khi + kgl);
      *(uint4*)&KsL[r * 72 + g] = *(const uint4*)(Klo + kgl);
      *(uint4*)&VsH[r * 72 + g] = *(const uint4*)(Vthi + vgl);
      *(uint4*)&VsL[r * 72 + g] = *(const uint4*)(Vtlo + vgl);
    }
    __syncthreads();

    f32x4 sc[4];
    sc[0] = z; sc[1] = z; sc[2] = z; sc[3] = z;
#pragma unroll
    for (int kg = 0; kg < 4; kg++) {
      int ba = (kg * 16 + l15) * 72 + lg * 8;
      bf16x8 bh0 = *(const bf16x8*)&KsH[ba];
      bf16x8 bh1 = *(const bf16x8*)&KsH[ba + 32];
      bf16x8 bl0 = *(const bf16x8*)&KsL[ba];
      bf16x8 bl1 = *(const bf16x8*)&KsL[ba + 32];
      sc[kg] = __builtin_amdgcn_mfma_f32_16x16x32_bf16(qh[0], bh0, sc[kg], 0, 0, 0);
      sc[kg] = __builtin_amdgcn_mfma_f32_16x16x32_bf16(qh[1], bh1, sc[kg], 0, 0, 0);
      sc[kg] = __builtin_amdgcn_mfma_f32_16x16x32_bf16(qh[0], bl0, sc[kg], 0, 0, 0);
      sc[kg] = __builtin_amdgcn_mfma_f32_16x16x32_bf16(qh[1], bl1, sc[kg], 0, 0, 0);
      sc[kg] = __builtin_amdgcn_mfma_f32_16x16x32_bf16(ql[0], bh0, sc[kg], 0, 0, 0);
      sc[kg] = __builtin_amdgcn_mfma_f32_16x16x32_bf16(ql[1], bh1, sc[kg], 0, 0, 0);
    }
    if (jb == qb) {
      int rb = w * 16 + lg * 4;
#pragma unroll
      for (int kg = 0; kg < 4; kg++) {
        int col = kg * 16 + l15;
#pragma unroll
        for (int r = 0; r < 4; r++)
          if (col > rb + r) sc[kg][r] = -1e30f;
      }
    }
#pragma unroll
    for (int r = 0; r < 4; r++) {
      float mt = fmaxf(fmaxf(sc[0][r], sc[1][r]), fmaxf(sc[2][r], sc[3][r]));
      mt = fmaxf(mt, __shfl_xor(mt, 1, 64));
      mt = fmaxf(mt, __shfl_xor(mt, 2, 64));
      mt = fmaxf(mt, __shfl_xor(mt, 4, 64));
      mt = fmaxf(mt, __shfl_xor(mt, 8, 64));
      float mnew = fmaxf(mrow[r], mt);
      float corr = __expf(mrow[r] - mnew);
      mrow[r] = mnew;
      float s = 0.f;
#pragma unroll
      for (int kg = 0; kg < 4; kg++) {
        float p = __expf(sc[kg][r] - mnew);
        sc[kg][r] = p;
        s += p;
      }
      s += __shfl_xor(s, 1, 64);
      s += __shfl_xor(s, 2, 64);
      s += __shfl_xor(s, 4, 64);
      s += __shfl_xor(s, 8, 64);
      lrow[r] = lrow[r] * corr + s;
      // per-ROW rescale (Oa[dg] components are 4 different rows)
#pragma unroll
      for (int dg = 0; dg < 4; dg++) Oa[dg][r] *= corr;
    }
    __syncthreads();  // all waves' QK reads of Ks done before Ps (alias) overwrite
    {
      int rb = w * 16 + lg * 4;
#pragma unroll
      for (int kg = 0; kg < 4; kg++) {
        int col = kg * 16 + l15;
#pragma unroll
        for (int r = 0; r < 4; r++) {
          float p = sc[kg][r];
          unsigned short ph = f2bf(p);
          PsH[(rb + r) * 72 + col] = ph;
          PsL[(rb + r) * 72 + col] = f2bf(p - bf2f(ph));
        }
      }
    }
    {
      // PV: A-frag rows w*16..w*16+15 == rows this wave just wrote (same-wave, no barrier)
      int ab = (w * 16 + l15) * 72 + lg * 8;
      bf16x8 ph0 = *(const bf16x8*)&PsH[ab];
      bf16x8 ph1 = *(const bf16x8*)&PsH[ab + 32];
      bf16x8 pl0 = *(const bf16x8*)&PsL[ab];
      bf16x8 pl1 = *(const bf16x8*)&PsL[ab + 32];
#pragma unroll
      for (int dg = 0; dg < 4; dg++) {
        int vb = (dg * 16 + l15) * 72 + lg * 8;
        bf16x8 vh0 = *(const bf16x8*)&VsH[vb];
        bf16x8 vh1 = *(const bf16x8*)&VsH[vb + 32];
        bf16x8 vl0 = *(const bf16x8*)&VsL[vb];
        bf16x8 vl1 = *(const bf16x8*)&VsL[vb + 32];
        Oa[dg] = __builtin_amdgcn_mfma_f32_16x16x32_bf16(ph0, vh0, Oa[dg], 0, 0, 0);
        Oa[dg] = __builtin_amdgcn_mfma_f32_16x16x32_bf16(ph1, vh1, Oa[dg], 0, 0, 0);
        Oa[dg] = __builtin_amdgcn_mfma_f32_16x16x32_bf16(ph0, vl0, Oa[dg], 0, 0, 0);
        Oa[dg] = __builtin_amdgcn_mfma_f32_16x16x32_bf16(ph1, vl1, Oa[dg], 0, 0, 0);
        Oa[dg] = __builtin_amdgcn_mfma_f32_16x16x32_bf16(pl0, vh0, Oa[dg], 0, 0, 0);
        Oa[dg] = __builtin_amdgcn_mfma_f32_16x16x32_bf16(pl1, vh1, Oa[dg], 0, 0, 0);
      }
    }
    __syncthreads();  // Ps/Vs reads done before next tile's staging writes
  }
#pragma unroll
  for (int r = 0; r < 4; r++) {
    float inv = 1.0f / lrow[r];
    size_t rb2 = (size_t)(qb + w * 16 + lg * 4 + r) * 3072 + head * 64;
#pragma unroll
    for (int dg = 0; dg < 4; dg++) {
      float v = Oa[dg][r] * inv;
      unsigned short hi2 = f2bf(v);
      unsigned short lo2 = f2bf(v - bf2f(hi2));
      Ao[rb2 + dg * 16 + l15] = hi2;
      Ao[rb2 + 1024 + dg * 16 + l15] = hi2;
      Ao[rb2 + 2048 + dg * 16 + l15] = lo2;
    }
  }
}

// ---------------- fused rmsnorm(post) + router: one wave per token ----------------
__global__ __launch_bounds__(256) void k_rmsrouter(const float* __restrict__ resid, const float* __restrict__ w,
                                                   const float* __restrict__ gw, unsigned short* __restrict__ h2b,
                                                   int* __restrict__ topi, float* __restrict__ topw,
                                                   int* __restrict__ counts) {
  int wid = threadIdx.x >> 6, lane = threadIdx.x & 63;
  int t = blockIdx.x * 4 + wid;
  const float* hr = resid + (size_t)t * H_;
  float hv[16];
#pragma unroll
  for (int i = 0; i < 16; i++) hv[i] = hr[lane + 64 * i];
  float ss = 0.f;
#pragma unroll
  for (int i = 0; i < 16; i++) ss += hv[i] * hv[i];
#pragma unroll
  for (int off = 32; off; off >>= 1) ss += __shfl_xor(ss, off, 64);
  float inv = rsqrtf(ss * (1.0f / H_) + 1e-5f);
#pragma unroll
  for (int i = 0; i < 16; i++) {
    hv[i] = hv[i] * inv * w[lane + 64 * i];
    h2b[(size_t)t * H_ + lane + 64 * i] = f2bf(hv[i]);
  }
  float le[8];
#pragma unroll
  for (int e = 0; e < 8; e++) {
    const float* g = gw + (size_t)e * H_;
    float acc = 0.f;
#pragma unroll
    for (int i = 0; i < 16; i++) acc += hv[i] * g[lane + 64 * i];
#pragma unroll
    for (int off = 32; off; off >>= 1) acc += __shfl_xor(acc, off, 64);
    le[e] = acc;
  }
  if (lane == 0) {
    int i0 = 0;
#pragma unroll
    for (int e = 1; e < 8; e++)
      if (le[e] > le[i0]) i0 = e;
    int i1 = (i0 == 0) ? 1 : 0;
#pragma unroll
    for (int e = 0; e < 8; e++) {
      if (e == i0) continue;
      if (le[e] > le[i1]) i1 = e;
    }
    float w1r = expf(le[i1] - le[i0]);
    float denom = 1.0f + w1r;
    topi[t * 2 + 0] = i0;
    topi[t * 2 + 1] = i1;
    topw[t * 2 + 0] = 1.0f / denom;
    topw[t * 2 + 1] = w1r / denom;
    atomicAdd(&counts[i0], 1);
    atomicAdd(&counts[i1], 1);
  }
}

// ---------------- fused scan + build: one block, LDS offsets + LDS slot counters ----------------
__global__ __launch_bounds__(256) void k_scanbuild(const int* __restrict__ counts, int* __restrict__ offsets,
                                                   const int* __restrict__ topi, const float* __restrict__ topw,
                                                   int* __restrict__ pairs_ts, float* __restrict__ pairs_w) {
  __shared__ int offs[NE_];
  __shared__ int cnt2[NE_];
  int tid = threadIdx.x;
  if (tid == 0) {
    int off = 0;
    for (int e = 0; e < NE_; e++) { offs[e] = off; offsets[e] = off; off += counts[e]; }
  }
  if (tid < NE_) cnt2[tid] = 0;
  __syncthreads();
  for (int t = tid; t < T_; t += 256) {
#pragma unroll
    for (int s = 0; s < 2; s++) {
      int e = topi[t * 2 + s];
      int slot = atomicAdd(&cnt2[e], 1);
      int p = offs[e] + slot;
      pairs_ts[p] = t * 2 + s;
      pairs_w[p] = topw[t * 2 + s];
    }
  }
}

// ---------------- fp32 -> bf16 bulk convert, all three MoE weights in one launch ----------------
__global__ __launch_bounds__(256) void k_conv3(const float* __restrict__ w1, const float* __restrict__ w3,
                                               const float* __restrict__ w2, unsigned short* __restrict__ W1b,
                                               unsigned short* __restrict__ W3b, unsigned short* __restrict__ W2b,
                                               int n8each) {
  int stride = gridDim.x * 256;
  int total = 3 * n8each;
  for (int i = blockIdx.x * 256 + threadIdx.x; i < total; i += stride) {
    int sel = i / n8each;
    int j = i - sel * n8each;
    const float* in = (sel == 0) ? w1 : (sel == 1) ? w3 : w2;
    unsigned short* out = (sel == 0) ? W1b : (sel == 1) ? W3b : W2b;
    const float4* p = (const float4*)in + (size_t)j * 2;
    float4 a = p[0], b = p[1];
    u16x8 t;
    t[0] = f2bf(a.x); t[1] = f2bf(a.y); t[2] = f2bf(a.z); t[3] = f2bf(a.w);
    t[4] = f2bf(b.x); t[5] = f2bf(b.y); t[6] = f2bf(b.z); t[7] = f2bf(b.w);
    *((u16x8*)out + j) = t;
  }
}

// ---------------- MoE up: 128x64 tile, BK=32, gload_lds dbuf, silu epilogue ----------------
__global__ __launch_bounds__(256) void k_moe_up(const unsigned short* __restrict__ h2b, const unsigned short* __restrict__ W1b,
                                                const unsigned short* __restrict__ W3b, const int* __restrict__ pairs_ts,
                                                const int* __restrict__ offsets, const int* __restrict__ counts,
                                                unsigned short* __restrict__ G) {
  int e = blockIdx.z;
  int ne = counts[e];
  int row0 = blockIdx.y * 128;
  if (row0 >= ne) return;
  int col0 = blockIdx.x * 64;
  int pbase = offsets[e];
  __shared__ unsigned short As[2][128 * 32];
  __shared__ unsigned short B1s[2][64 * 32];
  __shared__ unsigned short B2s[2][64 * 32];
  int tid = threadIdx.x, lane = tid & 63, w = tid >> 6;
  int wr = w >> 1, wc = w & 1;
  int l15 = lane & 15, lg = lane >> 4;
  int srow = lane >> 2, schunk = lane & 3;

  int gr0 = row0 + w * 32 + srow, gr1 = gr0 + 16;
  int tok0 = (gr0 < ne) ? (pairs_ts[pbase + gr0] >> 1) : 0;
  int tok1 = (gr1 < ne) ? (pairs_ts[pbase + gr1] >> 1) : 0;
  const unsigned short* ga0 = h2b + (size_t)tok0 * H_ + schunk * 8;
  const unsigned short* ga1 = h2b + (size_t)tok1 * H_ + schunk * 8;
  const unsigned short* gb1 = W1b + ((size_t)e * II_ + col0 + w * 16 + srow) * H_ + schunk * 8;
  const unsigned short* gb3 = W3b + ((size_t)e * II_ + col0 + w * 16 + srow) * H_ + schunk * 8;

  f32x4 acc1[4][2], acc2[4][2];
  f32x4 z = {0.f, 0.f, 0.f, 0.f};
#pragma unroll
  for (int a = 0; a < 4; a++)
#pragma unroll
    for (int b = 0; b < 2; b++) { acc1[a][b] = z; acc2[a][b] = z; }

  GLOAD16(ga0, &As[0][(w * 32) * 32]);
  GLOAD16(ga1, &As[0][(w * 32 + 16) * 32]);
  GLOAD16(gb1, &B1s[0][(w * 16) * 32]);
  GLOAD16(gb3, &B2s[0][(w * 16) * 32]);
  __syncthreads();

  for (int t = 0; t < H_ / 32; ++t) {
    int cur = t & 1;
    if (t + 1 < H_ / 32) {
      int ko = (t + 1) * 32;
      GLOAD16(ga0 + ko, &As[cur ^ 1][(w * 32) * 32]);
      GLOAD16(ga1 + ko, &As[cur ^ 1][(w * 32 + 16) * 32]);
      GLOAD16(gb1 + ko, &B1s[cur ^ 1][(w * 16) * 32]);
      GLOAD16(gb3 + ko, &B2s[cur ^ 1][(w * 16) * 32]);
    }
    bf16x8 af[4], b1f[2], b2f[2];
#pragma unroll
    for (int fa = 0; fa < 4; fa++)
      af[fa] = *(const bf16x8*)&As[cur][(wr * 64 + fa * 16 + l15) * 32 + lg * 8];
#pragma unroll
    for (int fb = 0; fb < 2; fb++) {
      b1f[fb] = *(const bf16x8*)&B1s[cur][(wc * 32 + fb * 16 + l15) * 32 + lg * 8];
      b2f[fb] = *(const bf16x8*)&B2s[cur][(wc * 32 + fb * 16 + l15) * 32 + lg * 8];
    }
#pragma unroll
    for (int fa = 0; fa < 4; fa++)
#pragma unroll
      for (int fb = 0; fb < 2; fb++) {
        acc1[fa][fb] = __builtin_amdgcn_mfma_f32_16x16x32_bf16(af[fa], b1f[fb], acc1[fa][fb], 0, 0, 0);
        acc2[fa][fb] = __builtin_amdgcn_mfma_f32_16x16x32_bf16(af[fa], b2f[fb], acc2[fa][fb], 0, 0, 0);
      }
    __syncthreads();
  }
#pragma unroll
  for (int fa = 0; fa < 4; fa++)
#pragma unroll
    for (int r = 0; r < 4; r++) {
      int prow = row0 + wr * 64 + fa * 16 + lg * 4 + r;
      if (prow < ne) {
#pragma unroll
        for (int fb = 0; fb < 2; fb++) {
          int icol = col0 + wc * 32 + fb * 16 + l15;
          float h1 = acc1[fa][fb][r], h3 = acc2[fa][fb][r];
          float g = h1 / (1.0f + __expf(-h1)) * h3;
          G[(size_t)(pbase + prow) * II_ + icol] = f2bf(g);
        }
      }
    }
}

// ---------------- MoE down: 128x64 tile, BK=32, gload_lds dbuf, weighted store ----------------
__global__ __launch_bounds__(256) void k_moe_down(const unsigned short* __restrict__ G, const unsigned short* __restrict__ W2b,
                                                  const int* __restrict__ pairs_ts, const float* __restrict__ pairs_w,
                                                  const int* __restrict__ offsets, const int* __restrict__ counts,
                                                  float* __restrict__ Pbuf) {
  int e = blockIdx.z;
  int ne = counts[e];
  int row0 = blockIdx.y * 128;
  if (row0 >= ne) return;
  int col0 = blockIdx.x * 64;
  int pbase = offsets[e];
  __shared__ unsigned short As[2][128 * 32];
  __shared__ unsigned short Bs[2][64 * 32];
  int tid = threadIdx.x, lane = tid & 63, w = tid >> 6;
  int wr = w >> 1, wc = w & 1;
  int l15 = lane & 15, lg = lane >> 4;
  int srow = lane >> 2, schunk = lane & 3;

  int gr0 = row0 + w * 32 + srow, gr1 = gr0 + 16;
  int p0 = pbase + ((gr0 < ne) ? gr0 : 0);
  int p1 = pbase + ((gr1 < ne) ? gr1 : 0);
  const unsigned short* ga0 = G + (size_t)p0 * II_ + schunk * 8;
  const unsigned short* ga1 = G + (size_t)p1 * II_ + schunk * 8;
  const unsigned short* gb = W2b + ((size_t)e * H_ + col0 + w * 16 + srow) * II_ + schunk * 8;

  f32x4 acc[4][2];
  f32x4 z = {0.f, 0.f, 0.f, 0.f};
#pragma unroll
  for (int a = 0; a < 4; a++)
#pragma unroll
    for (int b = 0; b < 2; b++) acc[a][b] = z;

  GLOAD16(ga0, &As[0][(w * 32) * 32]);
  GLOAD16(ga1, &As[0][(w * 32 + 16) * 32]);
  GLOAD16(gb, &Bs[0][(w * 16) * 32]);
  __syncthreads();

  for (int t = 0; t < II_ / 32; ++t) {
    int cur = t & 1;
    if (t + 1 < II_ / 32) {
      int ko = (t + 1) * 32;
      GLOAD16(ga0 + ko, &As[cur ^ 1][(w * 32) * 32]);
      GLOAD16(ga1 + ko, &As[cur ^ 1][(w * 32 + 16) * 32]);
      GLOAD16(gb + ko, &Bs[cur ^ 1][(w * 16) * 32]);
    }
    bf16x8 af[4], bw2[2];
#pragma unroll
    for (int fa = 0; fa < 4; fa++)
      af[fa] = *(const bf16x8*)&As[cur][(wr * 64 + fa * 16 + l15) * 32 + lg * 8];
#pragma unroll
    for (int fb = 0; fb < 2; fb++)
      bw2[fb] = *(const bf16x8*)&Bs[cur][(wc * 32 + fb * 16 + l15) * 32 + lg * 8];
#pragma unroll
    for (int fa = 0; fa < 4; fa++)
#pragma unroll
      for (int fb = 0; fb < 2; fb++)
        acc[fa][fb] = __builtin_amdgcn_mfma_f32_16x16x32_bf16(af[fa], bw2[fb], acc[fa][fb], 0, 0, 0);
    __syncthreads();
  }
#pragma unroll
  for (int fa = 0; fa < 4; fa++)
#pragma unroll
    for (int r = 0; r < 4; r++) {
      int prow = row0 + wr * 64 + fa * 16 + lg * 4 + r;
      if (prow < ne) {
        int p = pbase + prow;
        int ts = pairs_ts[p];
        float wgt = pairs_w[p];
#pragma unroll
        for (int fb = 0; fb < 2; fb++) {
          int col = col0 + wc * 32 + fb * 16 + l15;
          Pbuf[(size_t)ts * H_ + col] = wgt * acc[fa][fb][r];
        }
      }
    }
}

// ---------------- final: out = rmsnorm(resid + P0 + P1) ----------------
__global__ __launch_bounds__(256) void k_final(const float* __restrict__ resid, const float* __restrict__ Pbuf,
                                               const float* __restrict__ w, float* __restrict__ out) {
  int row = blockIdx.x;
  int tid = threadIdx.x;
  float4 a = ((const float4*)(resid + (size_t)row * H_))[tid];
  float4 p0 = ((const float4*)(Pbuf + (size_t)(2 * row) * H_))[tid];
  float4 p1 = ((const float4*)(Pbuf + (size_t)(2 * row + 1) * H_))[tid];
  float4 v;
  v.x = a.x + p0.x + p1.x; v.y = a.y + p0.y + p1.y; v.z = a.z + p0.z + p1.z; v.w = a.w + p0.w + p1.w;
  float ss = v.x * v.x + v.y * v.y + v.z * v.z + v.w * v.w;
#pragma unroll
  for (int off = 32; off; off >>= 1) ss += __shfl_xor(ss, off, 64);
  __shared__ float red[4];
  int lane = tid & 63, wid = tid >> 6;
  if (lane == 0) red[wid] = ss;
  __syncthreads();
  float tot = red[0] + red[1] + red[2] + red[3];
  float inv = rsqrtf(tot * (1.0f / H_) + 1e-5f);
  float4 wv = ((const float4*)w)[tid];
  float4 o;
  o.x = v.x * inv * wv.x; o.y = v.y * inv * wv.y; o.z = v.z * inv * wv.z; o.w = v.w * inv * wv.w;
  ((float4*)(out + (size_t)row * H_))[tid] = o;
}

extern "C" void kernel_launch(void* const* d_in, const int* in_sizes, int n_in,
                              void* d_out, int out_size, void* d_ws, size_t ws_size,
                              hipStream_t stream) {
  const float* x = (const float*)d_in[0];
  const int* pos = (const int*)d_in[1];
  const float* qkv_w = (const float*)d_in[2];
  const float* o_w = (const float*)d_in[3];
  const float* nin_w = (const float*)d_in[4];
  const float* npost_w = (const float*)d_in[5];
  const float* nnext_w = (const float*)d_in[6];
  const float* gate_w = (const float*)d_in[7];
  const float* w1 = (const float*)d_in[8];
  const float* w3 = (const float*)d_in[9];
  const float* w2 = (const float*)d_in[10];
  float* out = (float*)d_out;

  // ---- persistent region (layout unchanged from the verified config; unused slots retained) ----
  float* resid = (float*)d_ws;                       // T*H
  float* h2 = resid + (size_t)T_ * H_;               // T*H (unused; slot retained)
  float* Pbuf = h2 + (size_t)T_ * H_;                // 2*T*H
  float* topw = Pbuf + (size_t)2 * T_ * H_;          // 2T
  float* pairsw = topw + T_ * 2;                     // 4096
  unsigned short* h2b = (unsigned short*)(pairsw + 4096);  // T*H
  unsigned short* G = h2b + (size_t)T_ * H_;         // 2*T*II
  int* topi = (int*)(G + (size_t)2 * T_ * II_);      // 2T
  int* ctrl = topi + T_ * 2;
  int* counts = ctrl;
  int* counts2 = ctrl + 8;                           // (unused; slot retained)
  int* offsets = ctrl + 16;
  int* pairs_ts = ctrl + 24;                         // 4096
  char* trans = (char*)(pairs_ts + 4096);
  trans = (char*)(((uintptr_t)trans + 255) & ~(uintptr_t)255);

  // ---- transient: attention phase ----
  unsigned short* Aq = (unsigned short*)trans;       // T*3072
  unsigned short* Bq = Aq + (size_t)T_ * 3072;       // 1536*3072
  unsigned short* Bo = Bq + (size_t)1536 * 3072;     // 1024*3072
  unsigned short* Ao = Bo + (size_t)1024 * 3072;     // T*3072
  float* qkvb = (float*)(Ao + (size_t)T_ * 3072);    // T*1536
  float* ct = qkvb + (size_t)T_ * 1536;              // T*32 (unused; slot retained)
  float* st = ct + (size_t)T_ * 32;                  // T*32 (unused; slot retained)
  unsigned short* uu = (unsigned short*)(st + (size_t)T_ * 32);
  unsigned short* Qhi = uu;  uu += (size_t)HQ_ * T_ * D_;
  unsigned short* Qlo = uu;  uu += (size_t)HQ_ * T_ * D_;
  unsigned short* Khi = uu;  uu += (size_t)HK_ * T_ * D_;
  unsigned short* Klo = uu;  uu += (size_t)HK_ * T_ * D_;
  unsigned short* Vthi = uu; uu += (size_t)HK_ * D_ * T_;
  unsigned short* Vtlo = uu; uu += (size_t)HK_ * D_ * T_;

  // ---- transient: MoE phase (aliases attention transients; conv runs after router) ----
  unsigned short* W1b = (unsigned short*)trans;      // E*I*H
  unsigned short* W3b = W1b + (size_t)NE_ * II_ * H_;
  unsigned short* W2b = W3b + (size_t)NE_ * II_ * H_;

  const int WCNT8 = (NE_ * II_ * H_) / 8;

  hipMemsetAsync(ctrl, 0, 64, stream);  // counts (+ retained counts2 slot)
  k_rmsnorm_split<<<T_, 256, 0, stream>>>(x, nin_w, Aq);
  k_wsplit<<<2048, 256, 0, stream>>>(qkv_w, Bq, H_, 1536 * H_ / 8);
  k_wsplit<<<2048, 256, 0, stream>>>(o_w, Bo, HQ_ * D_, H_ * HQ_ * D_ / 8);
  k_hgemm<0><<<dim3(1536 / 64, T_ / 128), 256, 0, stream>>>(Aq, Bq, qkvb, nullptr, 1536, 3 * H_);
  k_rope_prep<<<T_, 256, 0, stream>>>(qkvb, pos, Qhi, Qlo, Khi, Klo);
  k_vtrans<<<dim3(T_ / 64, HK_), 256, 0, stream>>>(qkvb, Vthi, Vtlo);
  k_attn_mfma<<<dim3(512), 256, 0, stream>>>(Qhi, Qlo, Khi, Klo, Vthi, Vtlo, Ao);
  k_hgemm<1><<<dim3(H_ / 64, T_ / 128), 256, 0, stream>>>(Ao, Bo, resid, x, H_, 3 * HQ_ * D_);
  k_rmsrouter<<<T_ / 4, 256, 0, stream>>>(resid, npost_w, gate_w, h2b, topi, topw, counts);
  k_scanbuild<<<1, 256, 0, stream>>>(counts, offsets, topi, topw, pairs_ts, pairsw);
  // weight pre-conversion (attention transients are dead now) — single fused launch
  k_conv3<<<4096, 256, 0, stream>>>(w1, w3, w2, W1b, W3b, W2b, WCNT8);
  k_moe_up<<<dim3(II_ / 64, T_ / 128, NE_), 256, 0, stream>>>(h2b, W1b, W3b, pairs_ts, offsets, counts, G);
  k_moe_down<<<dim3(H_ / 64, T_ / 128, NE_), 256, 0, stream>>>(G, W2b, pairs_ts, pairsw, offsets, counts, Pbuf);
  k_final<<<T_, 256, 0, stream>>>(resid, Pbuf, nnext_w, out);
}

// Round 22
// 461.220 us; speedup vs baseline: 1.0941x; 1.0014x over previous
//
#include <hip/hip_runtime.h>
#include <hip/hip_bf16.h>
#include <math.h>

#define T_ 2048
#define H_ 1024
#define HQ_ 16
#define HK_ 4
#define D_ 64
#define NE_ 8
#define II_ 2048

typedef __attribute__((ext_vector_type(8))) short bf16x8;
typedef __attribute__((ext_vector_type(8))) unsigned short u16x8;
typedef __attribute__((ext_vector_type(4))) float f32x4;

// async global->LDS DMA: 16B per lane, dest = wave-uniform base + lane*16
#define GLOAD16(g, l)                                                                   \
  __builtin_amdgcn_global_load_lds((const __attribute__((address_space(1))) unsigned int*)(g), \
                                   (__attribute__((address_space(3))) unsigned int*)(l), 16, 0, 0)

__device__ __forceinline__ unsigned short f2bf(float f) {
  unsigned int u = __float_as_uint(f);
  return (unsigned short)((u + 0x7fffu + ((u >> 16) & 1u)) >> 16);
}
__device__ __forceinline__ float bf2f(unsigned short h) {
  return __uint_as_float((unsigned int)h << 16);
}

__device__ __forceinline__ void wsplit_body(const float* __restrict__ in, unsigned short* __restrict__ out,
                                            int K, int n8total, int vbid, int nblocks) {
  int stride = nblocks * 256;
  int kc8 = K >> 3;
  for (int i = vbid * 256 + (int)threadIdx.x; i < n8total; i += stride) {
    int n = i / kc8, kc = (i - n * kc8) * 8;
    const float4* p = (const float4*)(in + (size_t)n * K + kc);
    float4 a = p[0], b = p[1];
    u16x8 hi, lo;
    hi[0] = f2bf(a.x); hi[1] = f2bf(a.y); hi[2] = f2bf(a.z); hi[3] = f2bf(a.w);
    hi[4] = f2bf(b.x); hi[5] = f2bf(b.y); hi[6] = f2bf(b.z); hi[7] = f2bf(b.w);
    lo[0] = f2bf(a.x - bf2f(hi[0])); lo[1] = f2bf(a.y - bf2f(hi[1]));
    lo[2] = f2bf(a.z - bf2f(hi[2])); lo[3] = f2bf(a.w - bf2f(hi[3]));
    lo[4] = f2bf(b.x - bf2f(hi[4])); lo[5] = f2bf(b.y - bf2f(hi[5]));
    lo[6] = f2bf(b.z - bf2f(hi[6])); lo[7] = f2bf(b.w - bf2f(hi[7]));
    size_t ob = (size_t)n * 3 * K + kc;
    *(u16x8*)(out + ob) = hi;
    *(u16x8*)(out + ob + K) = lo;
    *(u16x8*)(out + ob + 2 * K) = hi;
  }
}

// ---------------- fused prep: rmsnorm_split (blocks 0..T-1) + wsplit qkv_w + wsplit o_w ----------------
__global__ __launch_bounds__(256) void k_prep(const float* __restrict__ x, const float* __restrict__ nin_w,
                                              unsigned short* __restrict__ Aq, const float* __restrict__ qkv_w,
                                              unsigned short* __restrict__ Bq, const float* __restrict__ o_w,
                                              unsigned short* __restrict__ Bo) {
  int bid = blockIdx.x;
  if (bid < T_) {
    int row = bid;
    int tid = threadIdx.x;
    float4 v = ((const float4*)(x + (size_t)row * H_))[tid];
    float ss = v.x * v.x + v.y * v.y + v.z * v.z + v.w * v.w;
#pragma unroll
    for (int off = 32; off; off >>= 1) ss += __shfl_xor(ss, off, 64);
    __shared__ float red[4];
    int lane = tid & 63, wid = tid >> 6;
    if (lane == 0) red[wid] = ss;
    __syncthreads();
    float tot = red[0] + red[1] + red[2] + red[3];
    float inv = rsqrtf(tot * (1.0f / H_) + 1e-5f);
    float4 wv = ((const float4*)nin_w)[tid];
    float4 o;
    o.x = v.x * inv * wv.x; o.y = v.y * inv * wv.y; o.z = v.z * inv * wv.z; o.w = v.w * inv * wv.w;
    ushort4 hi, lo;
    hi.x = f2bf(o.x); hi.y = f2bf(o.y); hi.z = f2bf(o.z); hi.w = f2bf(o.w);
    lo.x = f2bf(o.x - bf2f(hi.x)); lo.y = f2bf(o.y - bf2f(hi.y));
    lo.z = f2bf(o.z - bf2f(hi.z)); lo.w = f2bf(o.w - bf2f(hi.w));
    size_t base = (size_t)row * (3 * H_) + tid * 4;
    *(ushort4*)(Aq + base) = hi;
    *(ushort4*)(Aq + base + H_) = hi;
    *(ushort4*)(Aq + base + 2 * H_) = lo;
  } else if (bid < T_ + 2048) {
    wsplit_body(qkv_w, Bq, H_, 1536 * H_ / 8, bid - T_, 2048);
  } else {
    wsplit_body(o_w, Bo, HQ_ * D_, H_ * HQ_ * D_ / 8, bid - T_ - 2048, 2048);
  }
}

// ---------------- bf16 GEMM (expanded-K bf16x3), m97-style gload_lds + dbuf ----------------
template <int ADD>
__global__ __launch_bounds__(256) void k_hgemm(const unsigned short* __restrict__ A, const unsigned short* __restrict__ B,
                                               float* __restrict__ C, const float* __restrict__ addsrc,
                                               int N, int K3) {
  int m0 = blockIdx.y * 128, n0 = blockIdx.x * 64;
  __shared__ unsigned short As[2][128 * 32];
  __shared__ unsigned short Bs[2][64 * 32];
  int tid = threadIdx.x, lane = tid & 63, w = tid >> 6;
  int wr = w >> 1, wc = w & 1;
  int l15 = lane & 15, lg = lane >> 4;
  int srow = lane >> 2, schunk = lane & 3;

  const unsigned short* ga0 = A + (size_t)(m0 + w * 32 + srow) * K3 + schunk * 8;
  const unsigned short* ga1 = A + (size_t)(m0 + w * 32 + 16 + srow) * K3 + schunk * 8;
  const unsigned short* gb = B + (size_t)(n0 + w * 16 + srow) * K3 + schunk * 8;

  f32x4 acc[4][2];
  f32x4 z = {0.f, 0.f, 0.f, 0.f};
#pragma unroll
  for (int a = 0; a < 4; a++)
#pragma unroll
    for (int b = 0; b < 2; b++) acc[a][b] = z;

  GLOAD16(ga0, &As[0][(w * 32) * 32]);
  GLOAD16(ga1, &As[0][(w * 32 + 16) * 32]);
  GLOAD16(gb, &Bs[0][(w * 16) * 32]);
  __syncthreads();

  int nt = K3 / 32;
  for (int t = 0; t < nt; ++t) {
    int cur = t & 1;
    if (t + 1 < nt) {
      int ko = (t + 1) * 32;
      GLOAD16(ga0 + ko, &As[cur ^ 1][(w * 32) * 32]);
      GLOAD16(ga1 + ko, &As[cur ^ 1][(w * 32 + 16) * 32]);
      GLOAD16(gb + ko, &Bs[cur ^ 1][(w * 16) * 32]);
    }
    bf16x8 af[4], bw2[2];
#pragma unroll
    for (int fa = 0; fa < 4; fa++)
      af[fa] = *(const bf16x8*)&As[cur][(wr * 64 + fa * 16 + l15) * 32 + lg * 8];
#pragma unroll
    for (int fb = 0; fb < 2; fb++)
      bw2[fb] = *(const bf16x8*)&Bs[cur][(wc * 32 + fb * 16 + l15) * 32 + lg * 8];
#pragma unroll
    for (int fa = 0; fa < 4; fa++)
#pragma unroll
      for (int fb = 0; fb < 2; fb++)
        acc[fa][fb] = __builtin_amdgcn_mfma_f32_16x16x32_bf16(af[fa], bw2[fb], acc[fa][fb], 0, 0, 0);
    __syncthreads();
  }
#pragma unroll
  for (int fa = 0; fa < 4; fa++)
#pragma unroll
    for (int r = 0; r < 4; r++) {
      int row = m0 + wr * 64 + fa * 16 + lg * 4 + r;
#pragma unroll
      for (int fb = 0; fb < 2; fb++) {
        int col = n0 + wc * 32 + fb * 16 + l15;
        float v = acc[fa][fb][r];
        if (ADD) v += addsrc[(size_t)row * N + col];
        C[(size_t)row * N + col] = v;
      }
    }
}

// ---------------- fused RoPE (blocks 0..T-1) + V transpose (blocks T..T+127) ----------------
__global__ __launch_bounds__(256) void k_rope_vtrans(const float* __restrict__ qkv, const int* __restrict__ pos,
                                                     unsigned short* __restrict__ Qhi, unsigned short* __restrict__ Qlo,
                                                     unsigned short* __restrict__ Khi, unsigned short* __restrict__ Klo,
                                                     unsigned short* __restrict__ Vthi, unsigned short* __restrict__ Vtlo) {
  int bid = blockIdx.x;
  int tid = threadIdx.x;
  if (bid < T_) {
    int t = bid;
    __shared__ float cs[32], sn[32];
    if (tid < 32) {
      float p = (float)pow(10000.0, (double)tid / 32.0);
      float freq = 1.0f / p;
      float ang = (float)pos[t] * freq;
      cs[tid] = cosf(ang);
      sn[tid] = sinf(ang);
    }
    __syncthreads();
    const float* row = qkv + (size_t)t * 1536;
#pragma unroll 2
    for (int it = tid; it < 512; it += 256) {
      int h = it >> 5, i = it & 31;
      float c = cs[i], s = sn[i];
      float x1 = row[h * 64 + i], x2 = row[h * 64 + i + 32];
      float a = (x1 * c - x2 * s) * 0.125f;
      float b = (x2 * c + x1 * s) * 0.125f;
      size_t base = ((size_t)h * T_ + t) * 64 + i;
      unsigned short ah = f2bf(a), bh = f2bf(b);
      Qhi[base] = ah; Qhi[base + 32] = bh;
      Qlo[base] = f2bf(a - bf2f(ah));
      Qlo[base + 32] = f2bf(b - bf2f(bh));
    }
    if (tid < 128) {
      int h = tid >> 5, i = tid & 31;
      float c = cs[i], s = sn[i];
      float x1 = row[1024 + h * 64 + i], x2 = row[1024 + h * 64 + i + 32];
      float a = x1 * c - x2 * s;
      float b = x2 * c + x1 * s;
      size_t base = ((size_t)h * T_ + t) * 64 + i;
      unsigned short ah = f2bf(a), bh = f2bf(b);
      Khi[base] = ah; Khi[base + 32] = bh;
      Klo[base] = f2bf(a - bf2f(ah));
      Klo[base + 32] = f2bf(b - bf2f(bh));
    }
  } else {
    int vb = bid - T_;          // 0..127
    int h = vb >> 5;            // 0..3
    int t0 = (vb & 31) * 64;    // 0..1984
    __shared__ float tile[64][65];
    int c = tid & 63, w = tid >> 6;
    for (int r = w; r < 64; r += 4)
      tile[r][c] = qkv[(size_t)(t0 + r) * 1536 + 1280 + h * 64 + c];
    __syncthreads();
    for (int d = w; d < 64; d += 4) {
      float v = tile[c][d];
      unsigned short hi = f2bf(v);
      size_t idx = ((size_t)h * 64 + d) * T_ + t0 + c;
      Vthi[idx] = hi;
      Vtlo[idx] = f2bf(v - bf2f(hi));
    }
  }
}

// ---------------- flash attention, bf16x3; Ps aliases Ks (36.9KB LDS -> 4 blk/CU), direct staging ----------------
__global__ __launch_bounds__(256) void k_attn_mfma(const unsigned short* __restrict__ Qhi,
                                                   const unsigned short* __restrict__ Qlo,
                                                   const unsigned short* __restrict__ Khi,
                                                   const unsigned short* __restrict__ Klo,
                                                   const unsigned short* __restrict__ Vthi,
                                                   const unsigned short* __restrict__ Vtlo,
                                                   unsigned short* __restrict__ Ao) {
  int bid = blockIdx.x;
  int kk = bid >> 4;
  int head = bid & 15;
  // heavy-first: qidx 31..16 dispatch first, then 0..15
  int qidx = (kk < 16) ? (31 - kk) : (kk - 16);
  int qb = qidx * 64;
  int kvh = head >> 2;
  int tid = threadIdx.x, lane = tid & 63, w = tid >> 6;
  int l15 = lane & 15, lg = lane >> 4;

  // 4 x (64*72) shorts = 36.9 KB. Ps aliases Ks (Ks dead after QK^T; barrier-protected).
  __shared__ unsigned short S[4 * 64 * 72];
  unsigned short* KsH = S;
  unsigned short* KsL = S + 4608;
  unsigned short* VsH = S + 9216;
  unsigned short* VsL = S + 13824;
  unsigned short* PsH = KsH;
  unsigned short* PsL = KsL;

  bf16x8 qh[2], ql[2];
  {
    size_t qbase = ((size_t)head * T_ + qb + w * 16 + l15) * 64 + lg * 8;
    qh[0] = *(const bf16x8*)(Qhi + qbase);
    qh[1] = *(const bf16x8*)(Qhi + qbase + 32);
    ql[0] = *(const bf16x8*)(Qlo + qbase);
    ql[1] = *(const bf16x8*)(Qlo + qbase + 32);
  }
  f32x4 z = {0.f, 0.f, 0.f, 0.f};
  f32x4 Oa[4];
  float mrow[4], lrow[4];
#pragma unroll
  for (int r = 0; r < 4; r++) { mrow[r] = -1e30f; lrow[r] = 0.f; }
#pragma unroll
  for (int dg = 0; dg < 4; dg++) Oa[dg] = z;

  for (int jb = 0; jb <= qb; jb += 64) {
    // direct staging (short register liveness; previous tile's LDS reads protected by tile-end barrier)
    for (int c = tid; c < 512; c += 256) {
      int r = c >> 3, g = (c & 7) * 8;
      size_t kgl = ((size_t)kvh * T_ + jb + r) * 64 + g;
      size_t vgl = ((size_t)kvh * 64 + r) * T_ + jb + g;
      *(uint4*)&KsH[r * 72 + g] = *(const uint4*)(Khi + kgl);
      *(uint4*)&KsL[r * 72 + g] = *(const uint4*)(Klo + kgl);
      *(uint4*)&VsH[r * 72 + g] = *(const uint4*)(Vthi + vgl);
      *(uint4*)&VsL[r * 72 + g] = *(const uint4*)(Vtlo + vgl);
    }
    __syncthreads();

    f32x4 sc[4];
    sc[0] = z; sc[1] = z; sc[2] = z; sc[3] = z;
#pragma unroll
    for (int kg = 0; kg < 4; kg++) {
      int ba = (kg * 16 + l15) * 72 + lg * 8;
      bf16x8 bh0 = *(const bf16x8*)&KsH[ba];
      bf16x8 bh1 = *(const bf16x8*)&KsH[ba + 32];
      bf16x8 bl0 = *(const bf16x8*)&KsL[ba];
      bf16x8 bl1 = *(const bf16x8*)&KsL[ba + 32];
      sc[kg] = __builtin_amdgcn_mfma_f32_16x16x32_bf16(qh[0], bh0, sc[kg], 0, 0, 0);
      sc[kg] = __builtin_amdgcn_mfma_f32_16x16x32_bf16(qh[1], bh1, sc[kg], 0, 0, 0);
      sc[kg] = __builtin_amdgcn_mfma_f32_16x16x32_bf16(qh[0], bl0, sc[kg], 0, 0, 0);
      sc[kg] = __builtin_amdgcn_mfma_f32_16x16x32_bf16(qh[1], bl1, sc[kg], 0, 0, 0);
      sc[kg] = __builtin_amdgcn_mfma_f32_16x16x32_bf16(ql[0], bh0, sc[kg], 0, 0, 0);
      sc[kg] = __builtin_amdgcn_mfma_f32_16x16x32_bf16(ql[1], bh1, sc[kg], 0, 0, 0);
    }
    if (jb == qb) {
      int rb = w * 16 + lg * 4;
#pragma unroll
      for (int kg = 0; kg < 4; kg++) {
        int col = kg * 16 + l15;
#pragma unroll
        for (int r = 0; r < 4; r++)
          if (col > rb + r) sc[kg][r] = -1e30f;
      }
    }
#pragma unroll
    for (int r = 0; r < 4; r++) {
      float mt = fmaxf(fmaxf(sc[0][r], sc[1][r]), fmaxf(sc[2][r], sc[3][r]));
      mt = fmaxf(mt, __shfl_xor(mt, 1, 64));
      mt = fmaxf(mt, __shfl_xor(mt, 2, 64));
      mt = fmaxf(mt, __shfl_xor(mt, 4, 64));
      mt = fmaxf(mt, __shfl_xor(mt, 8, 64));
      float mnew = fmaxf(mrow[r], mt);
      float corr = __expf(mrow[r] - mnew);
      mrow[r] = mnew;
      float s = 0.f;
#pragma unroll
      for (int kg = 0; kg < 4; kg++) {
        float p = __expf(sc[kg][r] - mnew);
        sc[kg][r] = p;
        s += p;
      }
      s += __shfl_xor(s, 1, 64);
      s += __shfl_xor(s, 2, 64);
      s += __shfl_xor(s, 4, 64);
      s += __shfl_xor(s, 8, 64);
      lrow[r] = lrow[r] * corr + s;
      // per-ROW rescale (Oa[dg] components are 4 different rows)
#pragma unroll
      for (int dg = 0; dg < 4; dg++) Oa[dg][r] *= corr;
    }
    __syncthreads();  // all waves' QK reads of Ks done before Ps (alias) overwrite
    {
      int rb = w * 16 + lg * 4;
#pragma unroll
      for (int kg = 0; kg < 4; kg++) {
        int col = kg * 16 + l15;
#pragma unroll
        for (int r = 0; r < 4; r++) {
          float p = sc[kg][r];
          unsigned short ph = f2bf(p);
          PsH[(rb + r) * 72 + col] = ph;
          PsL[(rb + r) * 72 + col] = f2bf(p - bf2f(ph));
        }
      }
    }
    {
      // PV: A-frag rows w*16..w*16+15 == rows this wave just wrote (same-wave, no barrier)
      int ab = (w * 16 + l15) * 72 + lg * 8;
      bf16x8 ph0 = *(const bf16x8*)&PsH[ab];
      bf16x8 ph1 = *(const bf16x8*)&PsH[ab + 32];
      bf16x8 pl0 = *(const bf16x8*)&PsL[ab];
      bf16x8 pl1 = *(const bf16x8*)&PsL[ab + 32];
#pragma unroll
      for (int dg = 0; dg < 4; dg++) {
        int vb = (dg * 16 + l15) * 72 + lg * 8;
        bf16x8 vh0 = *(const bf16x8*)&VsH[vb];
        bf16x8 vh1 = *(const bf16x8*)&VsH[vb + 32];
        bf16x8 vl0 = *(const bf16x8*)&VsL[vb];
        bf16x8 vl1 = *(const bf16x8*)&VsL[vb + 32];
        Oa[dg] = __builtin_amdgcn_mfma_f32_16x16x32_bf16(ph0, vh0, Oa[dg], 0, 0, 0);
        Oa[dg] = __builtin_amdgcn_mfma_f32_16x16x32_bf16(ph1, vh1, Oa[dg], 0, 0, 0);
        Oa[dg] = __builtin_amdgcn_mfma_f32_16x16x32_bf16(ph0, vl0, Oa[dg], 0, 0, 0);
        Oa[dg] = __builtin_amdgcn_mfma_f32_16x16x32_bf16(ph1, vl1, Oa[dg], 0, 0, 0);
        Oa[dg] = __builtin_amdgcn_mfma_f32_16x16x32_bf16(pl0, vh0, Oa[dg], 0, 0, 0);
        Oa[dg] = __builtin_amdgcn_mfma_f32_16x16x32_bf16(pl1, vh1, Oa[dg], 0, 0, 0);
      }
    }
    __syncthreads();  // Ps/Vs reads done before next tile's staging writes
  }
#pragma unroll
  for (int r = 0; r < 4; r++) {
    float inv = 1.0f / lrow[r];
    size_t rb2 = (size_t)(qb + w * 16 + lg * 4 + r) * 3072 + head * 64;
#pragma unroll
    for (int dg = 0; dg < 4; dg++) {
      float v = Oa[dg][r] * inv;
      unsigned short hi2 = f2bf(v);
      unsigned short lo2 = f2bf(v - bf2f(hi2));
      Ao[rb2 + dg * 16 + l15] = hi2;
      Ao[rb2 + 1024 + dg * 16 + l15] = hi2;
      Ao[rb2 + 2048 + dg * 16 + l15] = lo2;
    }
  }
}

// ---------------- fused rmsnorm(post) + router: one wave per token ----------------
__global__ __launch_bounds__(256) void k_rmsrouter(const float* __restrict__ resid, const float* __restrict__ w,
                                                   const float* __restrict__ gw, unsigned short* __restrict__ h2b,
                                                   int* __restrict__ topi, float* __restrict__ topw,
                                                   int* __restrict__ counts) {
  int wid = threadIdx.x >> 6, lane = threadIdx.x & 63;
  int t = blockIdx.x * 4 + wid;
  const float* hr = resid + (size_t)t * H_;
  float hv[16];
#pragma unroll
  for (int i = 0; i < 16; i++) hv[i] = hr[lane + 64 * i];
  float ss = 0.f;
#pragma unroll
  for (int i = 0; i < 16; i++) ss += hv[i] * hv[i];
#pragma unroll
  for (int off = 32; off; off >>= 1) ss += __shfl_xor(ss, off, 64);
  float inv = rsqrtf(ss * (1.0f / H_) + 1e-5f);
#pragma unroll
  for (int i = 0; i < 16; i++) {
    hv[i] = hv[i] * inv * w[lane + 64 * i];
    h2b[(size_t)t * H_ + lane + 64 * i] = f2bf(hv[i]);
  }
  float le[8];
#pragma unroll
  for (int e = 0; e < 8; e++) {
    const float* g = gw + (size_t)e * H_;
    float acc = 0.f;
#pragma unroll
    for (int i = 0; i < 16; i++) acc += hv[i] * g[lane + 64 * i];
#pragma unroll
    for (int off = 32; off; off >>= 1) acc += __shfl_xor(acc, off, 64);
    le[e] = acc;
  }
  if (lane == 0) {
    int i0 = 0;
#pragma unroll
    for (int e = 1; e < 8; e++)
      if (le[e] > le[i0]) i0 = e;
    int i1 = (i0 == 0) ? 1 : 0;
#pragma unroll
    for (int e = 0; e < 8; e++) {
      if (e == i0) continue;
      if (le[e] > le[i1]) i1 = e;
    }
    float w1r = expf(le[i1] - le[i0]);
    float denom = 1.0f + w1r;
    topi[t * 2 + 0] = i0;
    topi[t * 2 + 1] = i1;
    topw[t * 2 + 0] = 1.0f / denom;
    topw[t * 2 + 1] = w1r / denom;
    atomicAdd(&counts[i0], 1);
    atomicAdd(&counts[i1], 1);
  }
}

// ---------------- fused scan + build: one block, LDS offsets + LDS slot counters ----------------
__global__ __launch_bounds__(256) void k_scanbuild(const int* __restrict__ counts, int* __restrict__ offsets,
                                                   const int* __restrict__ topi, const float* __restrict__ topw,
                                                   int* __restrict__ pairs_ts, float* __restrict__ pairs_w) {
  __shared__ int offs[NE_];
  __shared__ int cnt2[NE_];
  int tid = threadIdx.x;
  if (tid == 0) {
    int off = 0;
    for (int e = 0; e < NE_; e++) { offs[e] = off; offsets[e] = off; off += counts[e]; }
  }
  if (tid < NE_) cnt2[tid] = 0;
  __syncthreads();
  for (int t = tid; t < T_; t += 256) {
#pragma unroll
    for (int s = 0; s < 2; s++) {
      int e = topi[t * 2 + s];
      int slot = atomicAdd(&cnt2[e], 1);
      int p = offs[e] + slot;
      pairs_ts[p] = t * 2 + s;
      pairs_w[p] = topw[t * 2 + s];
    }
  }
}

// ---------------- fp32 -> bf16 bulk convert, all three MoE weights in one launch ----------------
__global__ __launch_bounds__(256) void k_conv3(const float* __restrict__ w1, const float* __restrict__ w3,
                                               const float* __restrict__ w2, unsigned short* __restrict__ W1b,
                                               unsigned short* __restrict__ W3b, unsigned short* __restrict__ W2b,
                                               int n8each) {
  int stride = gridDim.x * 256;
  int total = 3 * n8each;
  for (int i = blockIdx.x * 256 + threadIdx.x; i < total; i += stride) {
    int sel = i / n8each;
    int j = i - sel * n8each;
    const float* in = (sel == 0) ? w1 : (sel == 1) ? w3 : w2;
    unsigned short* out = (sel == 0) ? W1b : (sel == 1) ? W3b : W2b;
    const float4* p = (const float4*)in + (size_t)j * 2;
    float4 a = p[0], b = p[1];
    u16x8 t;
    t[0] = f2bf(a.x); t[1] = f2bf(a.y); t[2] = f2bf(a.z); t[3] = f2bf(a.w);
    t[4] = f2bf(b.x); t[5] = f2bf(b.y); t[6] = f2bf(b.z); t[7] = f2bf(b.w);
    *((u16x8*)out + j) = t;
  }
}

// ---------------- MoE up: 128x64 tile, BK=32, gload_lds dbuf, silu epilogue ----------------
__global__ __launch_bounds__(256) void k_moe_up(const unsigned short* __restrict__ h2b, const unsigned short* __restrict__ W1b,
                                                const unsigned short* __restrict__ W3b, const int* __restrict__ pairs_ts,
                                                const int* __restrict__ offsets, const int* __restrict__ counts,
                                                unsigned short* __restrict__ G) {
  int e = blockIdx.z;
  int ne = counts[e];
  int row0 = blockIdx.y * 128;
  if (row0 >= ne) return;
  int col0 = blockIdx.x * 64;
  int pbase = offsets[e];
  __shared__ unsigned short As[2][128 * 32];
  __shared__ unsigned short B1s[2][64 * 32];
  __shared__ unsigned short B2s[2][64 * 32];
  int tid = threadIdx.x, lane = tid & 63, w = tid >> 6;
  int wr = w >> 1, wc = w & 1;
  int l15 = lane & 15, lg = lane >> 4;
  int srow = lane >> 2, schunk = lane & 3;

  int gr0 = row0 + w * 32 + srow, gr1 = gr0 + 16;
  int tok0 = (gr0 < ne) ? (pairs_ts[pbase + gr0] >> 1) : 0;
  int tok1 = (gr1 < ne) ? (pairs_ts[pbase + gr1] >> 1) : 0;
  const unsigned short* ga0 = h2b + (size_t)tok0 * H_ + schunk * 8;
  const unsigned short* ga1 = h2b + (size_t)tok1 * H_ + schunk * 8;
  const unsigned short* gb1 = W1b + ((size_t)e * II_ + col0 + w * 16 + srow) * H_ + schunk * 8;
  const unsigned short* gb3 = W3b + ((size_t)e * II_ + col0 + w * 16 + srow) * H_ + schunk * 8;

  f32x4 acc1[4][2], acc2[4][2];
  f32x4 z = {0.f, 0.f, 0.f, 0.f};
#pragma unroll
  for (int a = 0; a < 4; a++)
#pragma unroll
    for (int b = 0; b < 2; b++) { acc1[a][b] = z; acc2[a][b] = z; }

  GLOAD16(ga0, &As[0][(w * 32) * 32]);
  GLOAD16(ga1, &As[0][(w * 32 + 16) * 32]);
  GLOAD16(gb1, &B1s[0][(w * 16) * 32]);
  GLOAD16(gb3, &B2s[0][(w * 16) * 32]);
  __syncthreads();

  for (int t = 0; t < H_ / 32; ++t) {
    int cur = t & 1;
    if (t + 1 < H_ / 32) {
      int ko = (t + 1) * 32;
      GLOAD16(ga0 + ko, &As[cur ^ 1][(w * 32) * 32]);
      GLOAD16(ga1 + ko, &As[cur ^ 1][(w * 32 + 16) * 32]);
      GLOAD16(gb1 + ko, &B1s[cur ^ 1][(w * 16) * 32]);
      GLOAD16(gb3 + ko, &B2s[cur ^ 1][(w * 16) * 32]);
    }
    bf16x8 af[4], b1f[2], b2f[2];
#pragma unroll
    for (int fa = 0; fa < 4; fa++)
      af[fa] = *(const bf16x8*)&As[cur][(wr * 64 + fa * 16 + l15) * 32 + lg * 8];
#pragma unroll
    for (int fb = 0; fb < 2; fb++) {
      b1f[fb] = *(const bf16x8*)&B1s[cur][(wc * 32 + fb * 16 + l15) * 32 + lg * 8];
      b2f[fb] = *(const bf16x8*)&B2s[cur][(wc * 32 + fb * 16 + l15) * 32 + lg * 8];
    }
#pragma unroll
    for (int fa = 0; fa < 4; fa++)
#pragma unroll
      for (int fb = 0; fb < 2; fb++) {
        acc1[fa][fb] = __builtin_amdgcn_mfma_f32_16x16x32_bf16(af[fa], b1f[fb], acc1[fa][fb], 0, 0, 0);
        acc2[fa][fb] = __builtin_amdgcn_mfma_f32_16x16x32_bf16(af[fa], b2f[fb], acc2[fa][fb], 0, 0, 0);
      }
    __syncthreads();
  }
#pragma unroll
  for (int fa = 0; fa < 4; fa++)
#pragma unroll
    for (int r = 0; r < 4; r++) {
      int prow = row0 + wr * 64 + fa * 16 + lg * 4 + r;
      if (prow < ne) {
#pragma unroll
        for (int fb = 0; fb < 2; fb++) {
          int icol = col0 + wc * 32 + fb * 16 + l15;
          float h1 = acc1[fa][fb][r], h3 = acc2[fa][fb][r];
          float g = h1 / (1.0f + __expf(-h1)) * h3;
          G[(size_t)(pbase + prow) * II_ + icol] = f2bf(g);
        }
      }
    }
}

// ---------------- MoE down: 128x64 tile, BK=32, gload_lds dbuf, weighted store ----------------
__global__ __launch_bounds__(256) void k_moe_down(const unsigned short* __restrict__ G, const unsigned short* __restrict__ W2b,
                                                  const int* __restrict__ pairs_ts, const float* __restrict__ pairs_w,
                                                  const int* __restrict__ offsets, const int* __restrict__ counts,
                                                  float* __restrict__ Pbuf) {
  int e = blockIdx.z;
  int ne = counts[e];
  int row0 = blockIdx.y * 128;
  if (row0 >= ne) return;
  int col0 = blockIdx.x * 64;
  int pbase = offsets[e];
  __shared__ unsigned short As[2][128 * 32];
  __shared__ unsigned short Bs[2][64 * 32];
  int tid = threadIdx.x, lane = tid & 63, w = tid >> 6;
  int wr = w >> 1, wc = w & 1;
  int l15 = lane & 15, lg = lane >> 4;
  int srow = lane >> 2, schunk = lane & 3;

  int gr0 = row0 + w * 32 + srow, gr1 = gr0 + 16;
  int p0 = pbase + ((gr0 < ne) ? gr0 : 0);
  int p1 = pbase + ((gr1 < ne) ? gr1 : 0);
  const unsigned short* ga0 = G + (size_t)p0 * II_ + schunk * 8;
  const unsigned short* ga1 = G + (size_t)p1 * II_ + schunk * 8;
  const unsigned short* gb = W2b + ((size_t)e * H_ + col0 + w * 16 + srow) * II_ + schunk * 8;

  f32x4 acc[4][2];
  f32x4 z = {0.f, 0.f, 0.f, 0.f};
#pragma unroll
  for (int a = 0; a < 4; a++)
#pragma unroll
    for (int b = 0; b < 2; b++) acc[a][b] = z;

  GLOAD16(ga0, &As[0][(w * 32) * 32]);
  GLOAD16(ga1, &As[0][(w * 32 + 16) * 32]);
  GLOAD16(gb, &Bs[0][(w * 16) * 32]);
  __syncthreads();

  for (int t = 0; t < II_ / 32; ++t) {
    int cur = t & 1;
    if (t + 1 < II_ / 32) {
      int ko = (t + 1) * 32;
      GLOAD16(ga0 + ko, &As[cur ^ 1][(w * 32) * 32]);
      GLOAD16(ga1 + ko, &As[cur ^ 1][(w * 32 + 16) * 32]);
      GLOAD16(gb + ko, &Bs[cur ^ 1][(w * 16) * 32]);
    }
    bf16x8 af[4], bw2[2];
#pragma unroll
    for (int fa = 0; fa < 4; fa++)
      af[fa] = *(const bf16x8*)&As[cur][(wr * 64 + fa * 16 + l15) * 32 + lg * 8];
#pragma unroll
    for (int fb = 0; fb < 2; fb++)
      bw2[fb] = *(const bf16x8*)&Bs[cur][(wc * 32 + fb * 16 + l15) * 32 + lg * 8];
#pragma unroll
    for (int fa = 0; fa < 4; fa++)
#pragma unroll
      for (int fb = 0; fb < 2; fb++)
        acc[fa][fb] = __builtin_amdgcn_mfma_f32_16x16x32_bf16(af[fa], bw2[fb], acc[fa][fb], 0, 0, 0);
    __syncthreads();
  }
#pragma unroll
  for (int fa = 0; fa < 4; fa++)
#pragma unroll
    for (int r = 0; r < 4; r++) {
      int prow = row0 + wr * 64 + fa * 16 + lg * 4 + r;
      if (prow < ne) {
        int p = pbase + prow;
        int ts = pairs_ts[p];
        float wgt = pairs_w[p];
#pragma unroll
        for (int fb = 0; fb < 2; fb++) {
          int col = col0 + wc * 32 + fb * 16 + l15;
          Pbuf[(size_t)ts * H_ + col] = wgt * acc[fa][fb][r];
        }
      }
    }
}

// ---------------- final: out = rmsnorm(resid + P0 + P1) ----------------
__global__ __launch_bounds__(256) void k_final(const float* __restrict__ resid, const float* __restrict__ Pbuf,
                                               const float* __restrict__ w, float* __restrict__ out) {
  int row = blockIdx.x;
  int tid = threadIdx.x;
  float4 a = ((const float4*)(resid + (size_t)row * H_))[tid];
  float4 p0 = ((const float4*)(Pbuf + (size_t)(2 * row) * H_))[tid];
  float4 p1 = ((const float4*)(Pbuf + (size_t)(2 * row + 1) * H_))[tid];
  float4 v;
  v.x = a.x + p0.x + p1.x; v.y = a.y + p0.y + p1.y; v.z = a.z + p0.z + p1.z; v.w = a.w + p0.w + p1.w;
  float ss = v.x * v.x + v.y * v.y + v.z * v.z + v.w * v.w;
#pragma unroll
  for (int off = 32; off; off >>= 1) ss += __shfl_xor(ss, off, 64);
  __shared__ float red[4];
  int lane = tid & 63, wid = tid >> 6;
  if (lane == 0) red[wid] = ss;
  __syncthreads();
  float tot = red[0] + red[1] + red[2] + red[3];
  float inv = rsqrtf(tot * (1.0f / H_) + 1e-5f);
  float4 wv = ((const float4*)w)[tid];
  float4 o;
  o.x = v.x * inv * wv.x; o.y = v.y * inv * wv.y; o.z = v.z * inv * wv.z; o.w = v.w * inv * wv.w;
  ((float4*)(out + (size_t)row * H_))[tid] = o;
}

extern "C" void kernel_launch(void* const* d_in, const int* in_sizes, int n_in,
                              void* d_out, int out_size, void* d_ws, size_t ws_size,
                              hipStream_t stream) {
  const float* x = (const float*)d_in[0];
  const int* pos = (const int*)d_in[1];
  const float* qkv_w = (const float*)d_in[2];
  const float* o_w = (const float*)d_in[3];
  const float* nin_w = (const float*)d_in[4];
  const float* npost_w = (const float*)d_in[5];
  const float* nnext_w = (const float*)d_in[6];
  const float* gate_w = (const float*)d_in[7];
  const float* w1 = (const float*)d_in[8];
  const float* w3 = (const float*)d_in[9];
  const float* w2 = (const float*)d_in[10];
  float* out = (float*)d_out;

  // ---- persistent region (layout unchanged from the verified config; unused slots retained) ----
  float* resid = (float*)d_ws;                       // T*H
  float* h2 = resid + (size_t)T_ * H_;               // T*H (unused; slot retained)
  float* Pbuf = h2 + (size_t)T_ * H_;                // 2*T*H
  float* topw = Pbuf + (size_t)2 * T_ * H_;          // 2T
  float* pairsw = topw + T_ * 2;                     // 4096
  unsigned short* h2b = (unsigned short*)(pairsw + 4096);  // T*H
  unsigned short* G = h2b + (size_t)T_ * H_;         // 2*T*II
  int* topi = (int*)(G + (size_t)2 * T_ * II_);      // 2T
  int* ctrl = topi + T_ * 2;
  int* counts = ctrl;
  int* counts2 = ctrl + 8;                           // (unused; slot retained)
  int* offsets = ctrl + 16;
  int* pairs_ts = ctrl + 24;                         // 4096
  char* trans = (char*)(pairs_ts + 4096);
  trans = (char*)(((uintptr_t)trans + 255) & ~(uintptr_t)255);

  // ---- transient: attention phase ----
  unsigned short* Aq = (unsigned short*)trans;       // T*3072
  unsigned short* Bq = Aq + (size_t)T_ * 3072;       // 1536*3072
  unsigned short* Bo = Bq + (size_t)1536 * 3072;     // 1024*3072
  unsigned short* Ao = Bo + (size_t)1024 * 3072;     // T*3072
  float* qkvb = (float*)(Ao + (size_t)T_ * 3072);    // T*1536
  float* ct = qkvb + (size_t)T_ * 1536;              // T*32 (unused; slot retained)
  float* st = ct + (size_t)T_ * 32;                  // T*32 (unused; slot retained)
  unsigned short* uu = (unsigned short*)(st + (size_t)T_ * 32);
  unsigned short* Qhi = uu;  uu += (size_t)HQ_ * T_ * D_;
  unsigned short* Qlo = uu;  uu += (size_t)HQ_ * T_ * D_;
  unsigned short* Khi = uu;  uu += (size_t)HK_ * T_ * D_;
  unsigned short* Klo = uu;  uu += (size_t)HK_ * T_ * D_;
  unsigned short* Vthi = uu; uu += (size_t)HK_ * D_ * T_;
  unsigned short* Vtlo = uu; uu += (size_t)HK_ * D_ * T_;

  // ---- transient: MoE phase (aliases attention transients; conv runs after router) ----
  unsigned short* W1b = (unsigned short*)trans;      // E*I*H
  unsigned short* W3b = W1b + (size_t)NE_ * II_ * H_;
  unsigned short* W2b = W3b + (size_t)NE_ * II_ * H_;

  const int WCNT8 = (NE_ * II_ * H_) / 8;

  hipMemsetAsync(ctrl, 0, 64, stream);  // counts (+ retained counts2 slot)
  k_prep<<<dim3(T_ + 4096), 256, 0, stream>>>(x, nin_w, Aq, qkv_w, Bq, o_w, Bo);
  k_hgemm<0><<<dim3(1536 / 64, T_ / 128), 256, 0, stream>>>(Aq, Bq, qkvb, nullptr, 1536, 3 * H_);
  k_rope_vtrans<<<dim3(T_ + 128), 256, 0, stream>>>(qkvb, pos, Qhi, Qlo, Khi, Klo, Vthi, Vtlo);
  k_attn_mfma<<<dim3(512), 256, 0, stream>>>(Qhi, Qlo, Khi, Klo, Vthi, Vtlo, Ao);
  k_hgemm<1><<<dim3(H_ / 64, T_ / 128), 256, 0, stream>>>(Ao, Bo, resid, x, H_, 3 * HQ_ * D_);
  k_rmsrouter<<<T_ / 4, 256, 0, stream>>>(resid, npost_w, gate_w, h2b, topi, topw, counts);
  k_scanbuild<<<1, 256, 0, stream>>>(counts, offsets, topi, topw, pairs_ts, pairsw);
  // weight pre-conversion (attention transients are dead now) — single fused launch
  k_conv3<<<4096, 256, 0, stream>>>(w1, w3, w2, W1b, W3b, W2b, WCNT8);
  k_moe_up<<<dim3(II_ / 64, T_ / 128, NE_), 256, 0, stream>>>(h2b, W1b, W3b, pairs_ts, offsets, counts, G);
  k_moe_down<<<dim3(H_ / 64, T_ / 128, NE_), 256, 0, stream>>>(G, W2b, pairs_ts, pairsw, offsets, counts, Pbuf);
  k_final<<<T_, 256, 0, stream>>>(resid, Pbuf, nnext_w, out);
}

// Round 23
// 459.594 us; speedup vs baseline: 1.0979x; 1.0035x over previous
//
#include <hip/hip_runtime.h>
#include <hip/hip_bf16.h>
#include <math.h>

#define T_ 2048
#define H_ 1024
#define HQ_ 16
#define HK_ 4
#define D_ 64
#define NE_ 8
#define II_ 2048

typedef __attribute__((ext_vector_type(8))) short bf16x8;
typedef __attribute__((ext_vector_type(8))) unsigned short u16x8;
typedef __attribute__((ext_vector_type(4))) float f32x4;

// async global->LDS DMA: 16B per lane, dest = wave-uniform base + lane*16
#define GLOAD16(g, l)                                                                   \
  __builtin_amdgcn_global_load_lds((const __attribute__((address_space(1))) unsigned int*)(g), \
                                   (__attribute__((address_space(3))) unsigned int*)(l), 16, 0, 0)

__device__ __forceinline__ unsigned short f2bf(float f) {
  unsigned int u = __float_as_uint(f);
  return (unsigned short)((u + 0x7fffu + ((u >> 16) & 1u)) >> 16);
}
__device__ __forceinline__ float bf2f(unsigned short h) {
  return __uint_as_float((unsigned int)h << 16);
}

__device__ __forceinline__ void wsplit_body(const float* __restrict__ in, unsigned short* __restrict__ out,
                                            int K, int n8total, int vbid, int nblocks) {
  int stride = nblocks * 256;
  int kc8 = K >> 3;
  for (int i = vbid * 256 + (int)threadIdx.x; i < n8total; i += stride) {
    int n = i / kc8, kc = (i - n * kc8) * 8;
    const float4* p = (const float4*)(in + (size_t)n * K + kc);
    float4 a = p[0], b = p[1];
    u16x8 hi, lo;
    hi[0] = f2bf(a.x); hi[1] = f2bf(a.y); hi[2] = f2bf(a.z); hi[3] = f2bf(a.w);
    hi[4] = f2bf(b.x); hi[5] = f2bf(b.y); hi[6] = f2bf(b.z); hi[7] = f2bf(b.w);
    lo[0] = f2bf(a.x - bf2f(hi[0])); lo[1] = f2bf(a.y - bf2f(hi[1]));
    lo[2] = f2bf(a.z - bf2f(hi[2])); lo[3] = f2bf(a.w - bf2f(hi[3]));
    lo[4] = f2bf(b.x - bf2f(hi[4])); lo[5] = f2bf(b.y - bf2f(hi[5]));
    lo[6] = f2bf(b.z - bf2f(hi[6])); lo[7] = f2bf(b.w - bf2f(hi[7]));
    size_t ob = (size_t)n * 3 * K + kc;
    *(u16x8*)(out + ob) = hi;
    *(u16x8*)(out + ob + K) = lo;
    *(u16x8*)(out + ob + 2 * K) = hi;
  }
}

// ---------------- fused prep: rmsnorm_split (blocks 0..T-1) + wsplit qkv_w + wsplit o_w ----------------
__global__ __launch_bounds__(256) void k_prep(const float* __restrict__ x, const float* __restrict__ nin_w,
                                              unsigned short* __restrict__ Aq, const float* __restrict__ qkv_w,
                                              unsigned short* __restrict__ Bq, const float* __restrict__ o_w,
                                              unsigned short* __restrict__ Bo) {
  int bid = blockIdx.x;
  if (bid < T_) {
    int row = bid;
    int tid = threadIdx.x;
    float4 v = ((const float4*)(x + (size_t)row * H_))[tid];
    float ss = v.x * v.x + v.y * v.y + v.z * v.z + v.w * v.w;
#pragma unroll
    for (int off = 32; off; off >>= 1) ss += __shfl_xor(ss, off, 64);
    __shared__ float red[4];
    int lane = tid & 63, wid = tid >> 6;
    if (lane == 0) red[wid] = ss;
    __syncthreads();
    float tot = red[0] + red[1] + red[2] + red[3];
    float inv = rsqrtf(tot * (1.0f / H_) + 1e-5f);
    float4 wv = ((const float4*)nin_w)[tid];
    float4 o;
    o.x = v.x * inv * wv.x; o.y = v.y * inv * wv.y; o.z = v.z * inv * wv.z; o.w = v.w * inv * wv.w;
    ushort4 hi, lo;
    hi.x = f2bf(o.x); hi.y = f2bf(o.y); hi.z = f2bf(o.z); hi.w = f2bf(o.w);
    lo.x = f2bf(o.x - bf2f(hi.x)); lo.y = f2bf(o.y - bf2f(hi.y));
    lo.z = f2bf(o.z - bf2f(hi.z)); lo.w = f2bf(o.w - bf2f(hi.w));
    size_t base = (size_t)row * (3 * H_) + tid * 4;
    *(ushort4*)(Aq + base) = hi;
    *(ushort4*)(Aq + base + H_) = hi;
    *(ushort4*)(Aq + base + 2 * H_) = lo;
  } else if (bid < T_ + 2048) {
    wsplit_body(qkv_w, Bq, H_, 1536 * H_ / 8, bid - T_, 2048);
  } else {
    wsplit_body(o_w, Bo, HQ_ * D_, H_ * HQ_ * D_ / 8, bid - T_ - 2048, 2048);
  }
}

// ---------------- bf16 GEMM (expanded-K bf16x3), m97-style gload_lds + dbuf ----------------
template <int ADD>
__global__ __launch_bounds__(256) void k_hgemm(const unsigned short* __restrict__ A, const unsigned short* __restrict__ B,
                                               float* __restrict__ C, const float* __restrict__ addsrc,
                                               int N, int K3) {
  int m0 = blockIdx.y * 128, n0 = blockIdx.x * 64;
  __shared__ unsigned short As[2][128 * 32];
  __shared__ unsigned short Bs[2][64 * 32];
  int tid = threadIdx.x, lane = tid & 63, w = tid >> 6;
  int wr = w >> 1, wc = w & 1;
  int l15 = lane & 15, lg = lane >> 4;
  int srow = lane >> 2, schunk = lane & 3;

  const unsigned short* ga0 = A + (size_t)(m0 + w * 32 + srow) * K3 + schunk * 8;
  const unsigned short* ga1 = A + (size_t)(m0 + w * 32 + 16 + srow) * K3 + schunk * 8;
  const unsigned short* gb = B + (size_t)(n0 + w * 16 + srow) * K3 + schunk * 8;

  f32x4 acc[4][2];
  f32x4 z = {0.f, 0.f, 0.f, 0.f};
#pragma unroll
  for (int a = 0; a < 4; a++)
#pragma unroll
    for (int b = 0; b < 2; b++) acc[a][b] = z;

  GLOAD16(ga0, &As[0][(w * 32) * 32]);
  GLOAD16(ga1, &As[0][(w * 32 + 16) * 32]);
  GLOAD16(gb, &Bs[0][(w * 16) * 32]);
  __syncthreads();

  int nt = K3 / 32;
  for (int t = 0; t < nt; ++t) {
    int cur = t & 1;
    if (t + 1 < nt) {
      int ko = (t + 1) * 32;
      GLOAD16(ga0 + ko, &As[cur ^ 1][(w * 32) * 32]);
      GLOAD16(ga1 + ko, &As[cur ^ 1][(w * 32 + 16) * 32]);
      GLOAD16(gb + ko, &Bs[cur ^ 1][(w * 16) * 32]);
    }
    bf16x8 af[4], bw2[2];
#pragma unroll
    for (int fa = 0; fa < 4; fa++)
      af[fa] = *(const bf16x8*)&As[cur][(wr * 64 + fa * 16 + l15) * 32 + lg * 8];
#pragma unroll
    for (int fb = 0; fb < 2; fb++)
      bw2[fb] = *(const bf16x8*)&Bs[cur][(wc * 32 + fb * 16 + l15) * 32 + lg * 8];
#pragma unroll
    for (int fa = 0; fa < 4; fa++)
#pragma unroll
      for (int fb = 0; fb < 2; fb++)
        acc[fa][fb] = __builtin_amdgcn_mfma_f32_16x16x32_bf16(af[fa], bw2[fb], acc[fa][fb], 0, 0, 0);
    __syncthreads();
  }
#pragma unroll
  for (int fa = 0; fa < 4; fa++)
#pragma unroll
    for (int r = 0; r < 4; r++) {
      int row = m0 + wr * 64 + fa * 16 + lg * 4 + r;
#pragma unroll
      for (int fb = 0; fb < 2; fb++) {
        int col = n0 + wc * 32 + fb * 16 + l15;
        float v = acc[fa][fb][r];
        if (ADD) v += addsrc[(size_t)row * N + col];
        C[(size_t)row * N + col] = v;
      }
    }
}

// ---------------- fused RoPE (blocks 0..T-1) + V transpose (blocks T..T+127) ----------------
__global__ __launch_bounds__(256) void k_rope_vtrans(const float* __restrict__ qkv, const int* __restrict__ pos,
                                                     unsigned short* __restrict__ Qhi, unsigned short* __restrict__ Qlo,
                                                     unsigned short* __restrict__ Khi, unsigned short* __restrict__ Klo,
                                                     unsigned short* __restrict__ Vthi, unsigned short* __restrict__ Vtlo) {
  int bid = blockIdx.x;
  int tid = threadIdx.x;
  if (bid < T_) {
    int t = bid;
    __shared__ float cs[32], sn[32];
    if (tid < 32) {
      float p = (float)pow(10000.0, (double)tid / 32.0);
      float freq = 1.0f / p;
      float ang = (float)pos[t] * freq;
      cs[tid] = cosf(ang);
      sn[tid] = sinf(ang);
    }
    __syncthreads();
    const float* row = qkv + (size_t)t * 1536;
#pragma unroll 2
    for (int it = tid; it < 512; it += 256) {
      int h = it >> 5, i = it & 31;
      float c = cs[i], s = sn[i];
      float x1 = row[h * 64 + i], x2 = row[h * 64 + i + 32];
      float a = (x1 * c - x2 * s) * 0.125f;
      float b = (x2 * c + x1 * s) * 0.125f;
      size_t base = ((size_t)h * T_ + t) * 64 + i;
      unsigned short ah = f2bf(a), bh = f2bf(b);
      Qhi[base] = ah; Qhi[base + 32] = bh;
      Qlo[base] = f2bf(a - bf2f(ah));
      Qlo[base + 32] = f2bf(b - bf2f(bh));
    }
    if (tid < 128) {
      int h = tid >> 5, i = tid & 31;
      float c = cs[i], s = sn[i];
      float x1 = row[1024 + h * 64 + i], x2 = row[1024 + h * 64 + i + 32];
      float a = x1 * c - x2 * s;
      float b = x2 * c + x1 * s;
      size_t base = ((size_t)h * T_ + t) * 64 + i;
      unsigned short ah = f2bf(a), bh = f2bf(b);
      Khi[base] = ah; Khi[base + 32] = bh;
      Klo[base] = f2bf(a - bf2f(ah));
      Klo[base + 32] = f2bf(b - bf2f(bh));
    }
  } else {
    int vb = bid - T_;          // 0..127
    int h = vb >> 5;            // 0..3
    int t0 = (vb & 31) * 64;    // 0..1984
    __shared__ float tile[64][65];
    int c = tid & 63, w = tid >> 6;
    for (int r = w; r < 64; r += 4)
      tile[r][c] = qkv[(size_t)(t0 + r) * 1536 + 1280 + h * 64 + c];
    __syncthreads();
    for (int d = w; d < 64; d += 4) {
      float v = tile[c][d];
      unsigned short hi = f2bf(v);
      size_t idx = ((size_t)h * 64 + d) * T_ + t0 + c;
      Vthi[idx] = hi;
      Vtlo[idx] = f2bf(v - bf2f(hi));
    }
  }
}

// ---------------- flash attention, bf16x3; Ps aliases Ks (36.9KB LDS -> 4 blk/CU), direct staging ----------------
__global__ __launch_bounds__(256) void k_attn_mfma(const unsigned short* __restrict__ Qhi,
                                                   const unsigned short* __restrict__ Qlo,
                                                   const unsigned short* __restrict__ Khi,
                                                   const unsigned short* __restrict__ Klo,
                                                   const unsigned short* __restrict__ Vthi,
                                                   const unsigned short* __restrict__ Vtlo,
                                                   unsigned short* __restrict__ Ao) {
  int bid = blockIdx.x;
  int kk = bid >> 4;
  int head = bid & 15;
  // heavy-first: qidx 31..16 dispatch first, then 0..15
  int qidx = (kk < 16) ? (31 - kk) : (kk - 16);
  int qb = qidx * 64;
  int kvh = head >> 2;
  int tid = threadIdx.x, lane = tid & 63, w = tid >> 6;
  int l15 = lane & 15, lg = lane >> 4;

  // 4 x (64*72) shorts = 36.9 KB. Ps aliases Ks (Ks dead after QK^T; barrier-protected).
  __shared__ unsigned short S[4 * 64 * 72];
  unsigned short* KsH = S;
  unsigned short* KsL = S + 4608;
  unsigned short* VsH = S + 9216;
  unsigned short* VsL = S + 13824;
  unsigned short* PsH = KsH;
  unsigned short* PsL = KsL;

  bf16x8 qh[2], ql[2];
  {
    size_t qbase = ((size_t)head * T_ + qb + w * 16 + l15) * 64 + lg * 8;
    qh[0] = *(const bf16x8*)(Qhi + qbase);
    qh[1] = *(const bf16x8*)(Qhi + qbase + 32);
    ql[0] = *(const bf16x8*)(Qlo + qbase);
    ql[1] = *(const bf16x8*)(Qlo + qbase + 32);
  }
  f32x4 z = {0.f, 0.f, 0.f, 0.f};
  f32x4 Oa[4];
  float mrow[4], lrow[4];
#pragma unroll
  for (int r = 0; r < 4; r++) { mrow[r] = -1e30f; lrow[r] = 0.f; }
#pragma unroll
  for (int dg = 0; dg < 4; dg++) Oa[dg] = z;

  for (int jb = 0; jb <= qb; jb += 64) {
    // direct staging (short register liveness; previous tile's LDS reads protected by tile-end barrier)
    for (int c = tid; c < 512; c += 256) {
      int r = c >> 3, g = (c & 7) * 8;
      size_t kgl = ((size_t)kvh * T_ + jb + r) * 64 + g;
      size_t vgl = ((size_t)kvh * 64 + r) * T_ + jb + g;
      *(uint4*)&KsH[r * 72 + g] = *(const uint4*)(Khi + kgl);
      *(uint4*)&KsL[r * 72 + g] = *(const uint4*)(Klo + kgl);
      *(uint4*)&VsH[r * 72 + g] = *(const uint4*)(Vthi + vgl);
      *(uint4*)&VsL[r * 72 + g] = *(const uint4*)(Vtlo + vgl);
    }
    __syncthreads();

    f32x4 sc[4];
    sc[0] = z; sc[1] = z; sc[2] = z; sc[3] = z;
#pragma unroll
    for (int kg = 0; kg < 4; kg++) {
      int ba = (kg * 16 + l15) * 72 + lg * 8;
      bf16x8 bh0 = *(const bf16x8*)&KsH[ba];
      bf16x8 bh1 = *(const bf16x8*)&KsH[ba + 32];
      bf16x8 bl0 = *(const bf16x8*)&KsL[ba];
      bf16x8 bl1 = *(const bf16x8*)&KsL[ba + 32];
      sc[kg] = __builtin_amdgcn_mfma_f32_16x16x32_bf16(qh[0], bh0, sc[kg], 0, 0, 0);
      sc[kg] = __builtin_amdgcn_mfma_f32_16x16x32_bf16(qh[1], bh1, sc[kg], 0, 0, 0);
      sc[kg] = __builtin_amdgcn_mfma_f32_16x16x32_bf16(qh[0], bl0, sc[kg], 0, 0, 0);
      sc[kg] = __builtin_amdgcn_mfma_f32_16x16x32_bf16(qh[1], bl1, sc[kg], 0, 0, 0);
      sc[kg] = __builtin_amdgcn_mfma_f32_16x16x32_bf16(ql[0], bh0, sc[kg], 0, 0, 0);
      sc[kg] = __builtin_amdgcn_mfma_f32_16x16x32_bf16(ql[1], bh1, sc[kg], 0, 0, 0);
    }
    if (jb == qb) {
      int rb = w * 16 + lg * 4;
#pragma unroll
      for (int kg = 0; kg < 4; kg++) {
        int col = kg * 16 + l15;
#pragma unroll
        for (int r = 0; r < 4; r++)
          if (col > rb + r) sc[kg][r] = -1e30f;
      }
    }
#pragma unroll
    for (int r = 0; r < 4; r++) {
      float mt = fmaxf(fmaxf(sc[0][r], sc[1][r]), fmaxf(sc[2][r], sc[3][r]));
      mt = fmaxf(mt, __shfl_xor(mt, 1, 64));
      mt = fmaxf(mt, __shfl_xor(mt, 2, 64));
      mt = fmaxf(mt, __shfl_xor(mt, 4, 64));
      mt = fmaxf(mt, __shfl_xor(mt, 8, 64));
      float mnew = fmaxf(mrow[r], mt);
      float corr = __expf(mrow[r] - mnew);
      mrow[r] = mnew;
      float s = 0.f;
#pragma unroll
      for (int kg = 0; kg < 4; kg++) {
        float p = __expf(sc[kg][r] - mnew);
        sc[kg][r] = p;
        s += p;
      }
      s += __shfl_xor(s, 1, 64);
      s += __shfl_xor(s, 2, 64);
      s += __shfl_xor(s, 4, 64);
      s += __shfl_xor(s, 8, 64);
      lrow[r] = lrow[r] * corr + s;
      // per-ROW rescale (Oa[dg] components are 4 different rows)
#pragma unroll
      for (int dg = 0; dg < 4; dg++) Oa[dg][r] *= corr;
    }
    __syncthreads();  // all waves' QK reads of Ks done before Ps (alias) overwrite
    {
      int rb = w * 16 + lg * 4;
#pragma unroll
      for (int kg = 0; kg < 4; kg++) {
        int col = kg * 16 + l15;
#pragma unroll
        for (int r = 0; r < 4; r++) {
          float p = sc[kg][r];
          unsigned short ph = f2bf(p);
          PsH[(rb + r) * 72 + col] = ph;
          PsL[(rb + r) * 72 + col] = f2bf(p - bf2f(ph));
        }
      }
    }
    {
      // PV: A-frag rows w*16..w*16+15 == rows this wave just wrote (same-wave, no barrier)
      int ab = (w * 16 + l15) * 72 + lg * 8;
      bf16x8 ph0 = *(const bf16x8*)&PsH[ab];
      bf16x8 ph1 = *(const bf16x8*)&PsH[ab + 32];
      bf16x8 pl0 = *(const bf16x8*)&PsL[ab];
      bf16x8 pl1 = *(const bf16x8*)&PsL[ab + 32];
#pragma unroll
      for (int dg = 0; dg < 4; dg++) {
        int vb = (dg * 16 + l15) * 72 + lg * 8;
        bf16x8 vh0 = *(const bf16x8*)&VsH[vb];
        bf16x8 vh1 = *(const bf16x8*)&VsH[vb + 32];
        bf16x8 vl0 = *(const bf16x8*)&VsL[vb];
        bf16x8 vl1 = *(const bf16x8*)&VsL[vb + 32];
        Oa[dg] = __builtin_amdgcn_mfma_f32_16x16x32_bf16(ph0, vh0, Oa[dg], 0, 0, 0);
        Oa[dg] = __builtin_amdgcn_mfma_f32_16x16x32_bf16(ph1, vh1, Oa[dg], 0, 0, 0);
        Oa[dg] = __builtin_amdgcn_mfma_f32_16x16x32_bf16(ph0, vl0, Oa[dg], 0, 0, 0);
        Oa[dg] = __builtin_amdgcn_mfma_f32_16x16x32_bf16(ph1, vl1, Oa[dg], 0, 0, 0);
        Oa[dg] = __builtin_amdgcn_mfma_f32_16x16x32_bf16(pl0, vh0, Oa[dg], 0, 0, 0);
        Oa[dg] = __builtin_amdgcn_mfma_f32_16x16x32_bf16(pl1, vh1, Oa[dg], 0, 0, 0);
      }
    }
    __syncthreads();  // Ps/Vs reads done before next tile's staging writes
  }
#pragma unroll
  for (int r = 0; r < 4; r++) {
    float inv = 1.0f / lrow[r];
    size_t rb2 = (size_t)(qb + w * 16 + lg * 4 + r) * 3072 + head * 64;
#pragma unroll
    for (int dg = 0; dg < 4; dg++) {
      float v = Oa[dg][r] * inv;
      unsigned short hi2 = f2bf(v);
      unsigned short lo2 = f2bf(v - bf2f(hi2));
      Ao[rb2 + dg * 16 + l15] = hi2;
      Ao[rb2 + 1024 + dg * 16 + l15] = hi2;
      Ao[rb2 + 2048 + dg * 16 + l15] = lo2;
    }
  }
}

// ---------------- fused rmsnorm(post) + router: one wave per token ----------------
__global__ __launch_bounds__(256) void k_rmsrouter(const float* __restrict__ resid, const float* __restrict__ w,
                                                   const float* __restrict__ gw, unsigned short* __restrict__ h2b,
                                                   int* __restrict__ topi, float* __restrict__ topw,
                                                   int* __restrict__ counts) {
  int wid = threadIdx.x >> 6, lane = threadIdx.x & 63;
  int t = blockIdx.x * 4 + wid;
  const float* hr = resid + (size_t)t * H_;
  float hv[16];
#pragma unroll
  for (int i = 0; i < 16; i++) hv[i] = hr[lane + 64 * i];
  float ss = 0.f;
#pragma unroll
  for (int i = 0; i < 16; i++) ss += hv[i] * hv[i];
#pragma unroll
  for (int off = 32; off; off >>= 1) ss += __shfl_xor(ss, off, 64);
  float inv = rsqrtf(ss * (1.0f / H_) + 1e-5f);
#pragma unroll
  for (int i = 0; i < 16; i++) {
    hv[i] = hv[i] * inv * w[lane + 64 * i];
    h2b[(size_t)t * H_ + lane + 64 * i] = f2bf(hv[i]);
  }
  float le[8];
#pragma unroll
  for (int e = 0; e < 8; e++) {
    const float* g = gw + (size_t)e * H_;
    float acc = 0.f;
#pragma unroll
    for (int i = 0; i < 16; i++) acc += hv[i] * g[lane + 64 * i];
#pragma unroll
    for (int off = 32; off; off >>= 1) acc += __shfl_xor(acc, off, 64);
    le[e] = acc;
  }
  if (lane == 0) {
    int i0 = 0;
#pragma unroll
    for (int e = 1; e < 8; e++)
      if (le[e] > le[i0]) i0 = e;
    int i1 = (i0 == 0) ? 1 : 0;
#pragma unroll
    for (int e = 0; e < 8; e++) {
      if (e == i0) continue;
      if (le[e] > le[i1]) i1 = e;
    }
    float w1r = expf(le[i1] - le[i0]);
    float denom = 1.0f + w1r;
    topi[t * 2 + 0] = i0;
    topi[t * 2 + 1] = i1;
    topw[t * 2 + 0] = 1.0f / denom;
    topw[t * 2 + 1] = w1r / denom;
    atomicAdd(&counts[i0], 1);
    atomicAdd(&counts[i1], 1);
  }
}

// ---------------- fused scan + build: one block, LDS offsets + LDS slot counters ----------------
__global__ __launch_bounds__(256) void k_scanbuild(const int* __restrict__ counts, int* __restrict__ offsets,
                                                   const int* __restrict__ topi, const float* __restrict__ topw,
                                                   int* __restrict__ pairs_ts, float* __restrict__ pairs_w) {
  __shared__ int offs[NE_];
  __shared__ int cnt2[NE_];
  int tid = threadIdx.x;
  if (tid == 0) {
    int off = 0;
    for (int e = 0; e < NE_; e++) { offs[e] = off; offsets[e] = off; off += counts[e]; }
  }
  if (tid < NE_) cnt2[tid] = 0;
  __syncthreads();
  for (int t = tid; t < T_; t += 256) {
#pragma unroll
    for (int s = 0; s < 2; s++) {
      int e = topi[t * 2 + s];
      int slot = atomicAdd(&cnt2[e], 1);
      int p = offs[e] + slot;
      pairs_ts[p] = t * 2 + s;
      pairs_w[p] = topw[t * 2 + s];
    }
  }
}

// ---------------- fp32 -> bf16 bulk convert, all three MoE weights in one launch ----------------
__global__ __launch_bounds__(256) void k_conv3(const float* __restrict__ w1, const float* __restrict__ w3,
                                               const float* __restrict__ w2, unsigned short* __restrict__ W1b,
                                               unsigned short* __restrict__ W3b, unsigned short* __restrict__ W2b,
                                               int n8each) {
  int stride = gridDim.x * 256;
  int total = 3 * n8each;
  for (int i = blockIdx.x * 256 + threadIdx.x; i < total; i += stride) {
    int sel = i / n8each;
    int j = i - sel * n8each;
    const float* in = (sel == 0) ? w1 : (sel == 1) ? w3 : w2;
    unsigned short* out = (sel == 0) ? W1b : (sel == 1) ? W3b : W2b;
    const float4* p = (const float4*)in + (size_t)j * 2;
    float4 a = p[0], b = p[1];
    u16x8 t;
    t[0] = f2bf(a.x); t[1] = f2bf(a.y); t[2] = f2bf(a.z); t[3] = f2bf(a.w);
    t[4] = f2bf(b.x); t[5] = f2bf(b.y); t[6] = f2bf(b.z); t[7] = f2bf(b.w);
    *((u16x8*)out + j) = t;
  }
}

// ---------------- MoE up: 128x64 tile, BK=32, gload_lds dbuf, silu epilogue ----------------
__global__ __launch_bounds__(256) void k_moe_up(const unsigned short* __restrict__ h2b, const unsigned short* __restrict__ W1b,
                                                const unsigned short* __restrict__ W3b, const int* __restrict__ pairs_ts,
                                                const int* __restrict__ offsets, const int* __restrict__ counts,
                                                unsigned short* __restrict__ G) {
  int e = blockIdx.z;
  int ne = counts[e];
  int row0 = blockIdx.y * 128;
  if (row0 >= ne) return;
  int col0 = blockIdx.x * 64;
  int pbase = offsets[e];
  __shared__ unsigned short As[2][128 * 32];
  __shared__ unsigned short B1s[2][64 * 32];
  __shared__ unsigned short B2s[2][64 * 32];
  int tid = threadIdx.x, lane = tid & 63, w = tid >> 6;
  int wr = w >> 1, wc = w & 1;
  int l15 = lane & 15, lg = lane >> 4;
  int srow = lane >> 2, schunk = lane & 3;

  int gr0 = row0 + w * 32 + srow, gr1 = gr0 + 16;
  int tok0 = (gr0 < ne) ? (pairs_ts[pbase + gr0] >> 1) : 0;
  int tok1 = (gr1 < ne) ? (pairs_ts[pbase + gr1] >> 1) : 0;
  const unsigned short* ga0 = h2b + (size_t)tok0 * H_ + schunk * 8;
  const unsigned short* ga1 = h2b + (size_t)tok1 * H_ + schunk * 8;
  const unsigned short* gb1 = W1b + ((size_t)e * II_ + col0 + w * 16 + srow) * H_ + schunk * 8;
  const unsigned short* gb3 = W3b + ((size_t)e * II_ + col0 + w * 16 + srow) * H_ + schunk * 8;

  f32x4 acc1[4][2], acc2[4][2];
  f32x4 z = {0.f, 0.f, 0.f, 0.f};
#pragma unroll
  for (int a = 0; a < 4; a++)
#pragma unroll
    for (int b = 0; b < 2; b++) { acc1[a][b] = z; acc2[a][b] = z; }

  GLOAD16(ga0, &As[0][(w * 32) * 32]);
  GLOAD16(ga1, &As[0][(w * 32 + 16) * 32]);
  GLOAD16(gb1, &B1s[0][(w * 16) * 32]);
  GLOAD16(gb3, &B2s[0][(w * 16) * 32]);
  __syncthreads();

  for (int t = 0; t < H_ / 32; ++t) {
    int cur = t & 1;
    if (t + 1 < H_ / 32) {
      int ko = (t + 1) * 32;
      GLOAD16(ga0 + ko, &As[cur ^ 1][(w * 32) * 32]);
      GLOAD16(ga1 + ko, &As[cur ^ 1][(w * 32 + 16) * 32]);
      GLOAD16(gb1 + ko, &B1s[cur ^ 1][(w * 16) * 32]);
      GLOAD16(gb3 + ko, &B2s[cur ^ 1][(w * 16) * 32]);
    }
    bf16x8 af[4], b1f[2], b2f[2];
#pragma unroll
    for (int fa = 0; fa < 4; fa++)
      af[fa] = *(const bf16x8*)&As[cur][(wr * 64 + fa * 16 + l15) * 32 + lg * 8];
#pragma unroll
    for (int fb = 0; fb < 2; fb++) {
      b1f[fb] = *(const bf16x8*)&B1s[cur][(wc * 32 + fb * 16 + l15) * 32 + lg * 8];
      b2f[fb] = *(const bf16x8*)&B2s[cur][(wc * 32 + fb * 16 + l15) * 32 + lg * 8];
    }
#pragma unroll
    for (int fa = 0; fa < 4; fa++)
#pragma unroll
      for (int fb = 0; fb < 2; fb++) {
        acc1[fa][fb] = __builtin_amdgcn_mfma_f32_16x16x32_bf16(af[fa], b1f[fb], acc1[fa][fb], 0, 0, 0);
        acc2[fa][fb] = __builtin_amdgcn_mfma_f32_16x16x32_bf16(af[fa], b2f[fb], acc2[fa][fb], 0, 0, 0);
      }
    __syncthreads();
  }
#pragma unroll
  for (int fa = 0; fa < 4; fa++)
#pragma unroll
    for (int r = 0; r < 4; r++) {
      int prow = row0 + wr * 64 + fa * 16 + lg * 4 + r;
      if (prow < ne) {
#pragma unroll
        for (int fb = 0; fb < 2; fb++) {
          int icol = col0 + wc * 32 + fb * 16 + l15;
          float h1 = acc1[fa][fb][r], h3 = acc2[fa][fb][r];
          float g = h1 / (1.0f + __expf(-h1)) * h3;
          G[(size_t)(pbase + prow) * II_ + icol] = f2bf(g);
        }
      }
    }
}

// ---------------- MoE down: 128x64 tile, BK=32, gload_lds dbuf, weighted store ----------------
__global__ __launch_bounds__(256) void k_moe_down(const unsigned short* __restrict__ G, const unsigned short* __restrict__ W2b,
                                                  const int* __restrict__ pairs_ts, const float* __restrict__ pairs_w,
                                                  const int* __restrict__ offsets, const int* __restrict__ counts,
                                                  float* __restrict__ Pbuf) {
  int e = blockIdx.z;
  int ne = counts[e];
  int row0 = blockIdx.y * 128;
  if (row0 >= ne) return;
  int col0 = blockIdx.x * 64;
  int pbase = offsets[e];
  __shared__ unsigned short As[2][128 * 32];
  __shared__ unsigned short Bs[2][64 * 32];
  int tid = threadIdx.x, lane = tid & 63, w = tid >> 6;
  int wr = w >> 1, wc = w & 1;
  int l15 = lane & 15, lg = lane >> 4;
  int srow = lane >> 2, schunk = lane & 3;

  int gr0 = row0 + w * 32 + srow, gr1 = gr0 + 16;
  int p0 = pbase + ((gr0 < ne) ? gr0 : 0);
  int p1 = pbase + ((gr1 < ne) ? gr1 : 0);
  const unsigned short* ga0 = G + (size_t)p0 * II_ + schunk * 8;
  const unsigned short* ga1 = G + (size_t)p1 * II_ + schunk * 8;
  const unsigned short* gb = W2b + ((size_t)e * H_ + col0 + w * 16 + srow) * II_ + schunk * 8;

  f32x4 acc[4][2];
  f32x4 z = {0.f, 0.f, 0.f, 0.f};
#pragma unroll
  for (int a = 0; a < 4; a++)
#pragma unroll
    for (int b = 0; b < 2; b++) acc[a][b] = z;

  GLOAD16(ga0, &As[0][(w * 32) * 32]);
  GLOAD16(ga1, &As[0][(w * 32 + 16) * 32]);
  GLOAD16(gb, &Bs[0][(w * 16) * 32]);
  __syncthreads();

  for (int t = 0; t < II_ / 32; ++t) {
    int cur = t & 1;
    if (t + 1 < II_ / 32) {
      int ko = (t + 1) * 32;
      GLOAD16(ga0 + ko, &As[cur ^ 1][(w * 32) * 32]);
      GLOAD16(ga1 + ko, &As[cur ^ 1][(w * 32 + 16) * 32]);
      GLOAD16(gb + ko, &Bs[cur ^ 1][(w * 16) * 32]);
    }
    bf16x8 af[4], bw2[2];
#pragma unroll
    for (int fa = 0; fa < 4; fa++)
      af[fa] = *(const bf16x8*)&As[cur][(wr * 64 + fa * 16 + l15) * 32 + lg * 8];
#pragma unroll
    for (int fb = 0; fb < 2; fb++)
      bw2[fb] = *(const bf16x8*)&Bs[cur][(wc * 32 + fb * 16 + l15) * 32 + lg * 8];
#pragma unroll
    for (int fa = 0; fa < 4; fa++)
#pragma unroll
      for (int fb = 0; fb < 2; fb++)
        acc[fa][fb] = __builtin_amdgcn_mfma_f32_16x16x32_bf16(af[fa], bw2[fb], acc[fa][fb], 0, 0, 0);
    __syncthreads();
  }
#pragma unroll
  for (int fa = 0; fa < 4; fa++)
#pragma unroll
    for (int r = 0; r < 4; r++) {
      int prow = row0 + wr * 64 + fa * 16 + lg * 4 + r;
      if (prow < ne) {
        int p = pbase + prow;
        int ts = pairs_ts[p];
        float wgt = pairs_w[p];
#pragma unroll
        for (int fb = 0; fb < 2; fb++) {
          int col = col0 + wc * 32 + fb * 16 + l15;
          Pbuf[(size_t)ts * H_ + col] = wgt * acc[fa][fb][r];
        }
      }
    }
}

// ---------------- final: out = rmsnorm(resid + P0 + P1) ----------------
__global__ __launch_bounds__(256) void k_final(const float* __restrict__ resid, const float* __restrict__ Pbuf,
                                               const float* __restrict__ w, float* __restrict__ out) {
  int row = blockIdx.x;
  int tid = threadIdx.x;
  float4 a = ((const float4*)(resid + (size_t)row * H_))[tid];
  float4 p0 = ((const float4*)(Pbuf + (size_t)(2 * row) * H_))[tid];
  float4 p1 = ((const float4*)(Pbuf + (size_t)(2 * row + 1) * H_))[tid];
  float4 v;
  v.x = a.x + p0.x + p1.x; v.y = a.y + p0.y + p1.y; v.z = a.z + p0.z + p1.z; v.w = a.w + p0.w + p1.w;
  float ss = v.x * v.x + v.y * v.y + v.z * v.z + v.w * v.w;
#pragma unroll
  for (int off = 32; off; off >>= 1) ss += __shfl_xor(ss, off, 64);
  __shared__ float red[4];
  int lane = tid & 63, wid = tid >> 6;
  if (lane == 0) red[wid] = ss;
  __syncthreads();
  float tot = red[0] + red[1] + red[2] + red[3];
  float inv = rsqrtf(tot * (1.0f / H_) + 1e-5f);
  float4 wv = ((const float4*)w)[tid];
  float4 o;
  o.x = v.x * inv * wv.x; o.y = v.y * inv * wv.y; o.z = v.z * inv * wv.z; o.w = v.w * inv * wv.w;
  ((float4*)(out + (size_t)row * H_))[tid] = o;
}

extern "C" void kernel_launch(void* const* d_in, const int* in_sizes, int n_in,
                              void* d_out, int out_size, void* d_ws, size_t ws_size,
                              hipStream_t stream) {
  const float* x = (const float*)d_in[0];
  const int* pos = (const int*)d_in[1];
  const float* qkv_w = (const float*)d_in[2];
  const float* o_w = (const float*)d_in[3];
  const float* nin_w = (const float*)d_in[4];
  const float* npost_w = (const float*)d_in[5];
  const float* nnext_w = (const float*)d_in[6];
  const float* gate_w = (const float*)d_in[7];
  const float* w1 = (const float*)d_in[8];
  const float* w3 = (const float*)d_in[9];
  const float* w2 = (const float*)d_in[10];
  float* out = (float*)d_out;

  // ---- persistent region (layout unchanged from the verified config; unused slots retained) ----
  float* resid = (float*)d_ws;                       // T*H
  float* h2 = resid + (size_t)T_ * H_;               // T*H (unused; slot retained)
  float* Pbuf = h2 + (size_t)T_ * H_;                // 2*T*H
  float* topw = Pbuf + (size_t)2 * T_ * H_;          // 2T
  float* pairsw = topw + T_ * 2;                     // 4096
  unsigned short* h2b = (unsigned short*)(pairsw + 4096);  // T*H
  unsigned short* G = h2b + (size_t)T_ * H_;         // 2*T*II
  int* topi = (int*)(G + (size_t)2 * T_ * II_);      // 2T
  int* ctrl = topi + T_ * 2;
  int* counts = ctrl;
  int* counts2 = ctrl + 8;                           // (unused; slot retained)
  int* offsets = ctrl + 16;
  int* pairs_ts = ctrl + 24;                         // 4096
  char* trans = (char*)(pairs_ts + 4096);
  trans = (char*)(((uintptr_t)trans + 255) & ~(uintptr_t)255);

  // ---- transient: attention phase ----
  unsigned short* Aq = (unsigned short*)trans;       // T*3072
  unsigned short* Bq = Aq + (size_t)T_ * 3072;       // 1536*3072
  unsigned short* Bo = Bq + (size_t)1536 * 3072;     // 1024*3072
  unsigned short* Ao = Bo + (size_t)1024 * 3072;     // T*3072
  float* qkvb = (float*)(Ao + (size_t)T_ * 3072);    // T*1536
  float* ct = qkvb + (size_t)T_ * 1536;              // T*32 (unused; slot retained)
  float* st = ct + (size_t)T_ * 32;                  // T*32 (unused; slot retained)
  unsigned short* uu = (unsigned short*)(st + (size_t)T_ * 32);
  unsigned short* Qhi = uu;  uu += (size_t)HQ_ * T_ * D_;
  unsigned short* Qlo = uu;  uu += (size_t)HQ_ * T_ * D_;
  unsigned short* Khi = uu;  uu += (size_t)HK_ * T_ * D_;
  unsigned short* Klo = uu;  uu += (size_t)HK_ * T_ * D_;
  unsigned short* Vthi = uu; uu += (size_t)HK_ * D_ * T_;
  unsigned short* Vtlo = uu; uu += (size_t)HK_ * D_ * T_;

  // ---- transient: MoE phase (aliases attention transients; conv runs after router) ----
  unsigned short* W1b = (unsigned short*)trans;      // E*I*H
  unsigned short* W3b = W1b + (size_t)NE_ * II_ * H_;
  unsigned short* W2b = W3b + (size_t)NE_ * II_ * H_;

  const int WCNT8 = (NE_ * II_ * H_) / 8;

  hipMemsetAsync(ctrl, 0, 64, stream);  // counts (+ retained counts2 slot)
  k_prep<<<dim3(T_ + 4096), 256, 0, stream>>>(x, nin_w, Aq, qkv_w, Bq, o_w, Bo);
  k_hgemm<0><<<dim3(1536 / 64, T_ / 128), 256, 0, stream>>>(Aq, Bq, qkvb, nullptr, 1536, 3 * H_);
  k_rope_vtrans<<<dim3(T_ + 128), 256, 0, stream>>>(qkvb, pos, Qhi, Qlo, Khi, Klo, Vthi, Vtlo);
  k_attn_mfma<<<dim3(512), 256, 0, stream>>>(Qhi, Qlo, Khi, Klo, Vthi, Vtlo, Ao);
  k_hgemm<1><<<dim3(H_ / 64, T_ / 128), 256, 0, stream>>>(Ao, Bo, resid, x, H_, 3 * HQ_ * D_);
  k_rmsrouter<<<T_ / 4, 256, 0, stream>>>(resid, npost_w, gate_w, h2b, topi, topw, counts);
  k_scanbuild<<<1, 256, 0, stream>>>(counts, offsets, topi, topw, pairs_ts, pairsw);
  // weight pre-conversion (attention transients are dead now) — single fused launch
  k_conv3<<<4096, 256, 0, stream>>>(w1, w3, w2, W1b, W3b, W2b, WCNT8);
  k_moe_up<<<dim3(II_ / 64, T_ / 128, NE_), 256, 0, stream>>>(h2b, W1b, W3b, pairs_ts, offsets, counts, G);
  k_moe_down<<<dim3(H_ / 64, T_ / 128, NE_), 256, 0, stream>>>(G, W2b, pairs_ts, pairsw, offsets, counts, Pbuf);
  k_final<<<T_, 256, 0, stream>>>(resid, Pbuf, nnext_w, out);
}